// Round 4
// baseline (27786.682 us; speedup 1.0000x reference)
//
#include <hip/hip_runtime.h>
#include <hip/hip_bf16.h>
#include <math.h>

#define SEQ 2048
#define HID 1024
#define NHEAD 16
#define HDIM 64
#define IDIM 2816
#define NEXP 8
#define VOCAB 32000

typedef float f32x4v __attribute__((ext_vector_type(4)));
typedef __bf16 bf16x8v __attribute__((ext_vector_type(8)));

__device__ __forceinline__ bf16x8v cvt8(const float4& a, const float4& b) {
  bf16x8v r;
  r[0] = (__bf16)a.x; r[1] = (__bf16)a.y; r[2] = (__bf16)a.z; r[3] = (__bf16)a.w;
  r[4] = (__bf16)b.x; r[5] = (__bf16)b.y; r[6] = (__bf16)b.z; r[7] = (__bf16)b.w;
  return r;
}

__device__ __forceinline__ void split8(const float4& a, const float4& b,
                                       bf16x8v& h, bf16x8v& l) {
  float f[8] = {a.x, a.y, a.z, a.w, b.x, b.y, b.z, b.w};
#pragma unroll
  for (int i = 0; i < 8; ++i) {
    __bf16 hb = (__bf16)f[i];
    h[i] = hb;
    l[i] = (__bf16)(f[i] - (float)hb);
  }
}

// ---------------------------------------------------------------------------
// Plain bf16 GEMM (unchanged; used post-router: MoE experts, L3, logits)
// ---------------------------------------------------------------------------
template<bool BT, bool ACCUM>
__global__ __launch_bounds__(256) void gemm_kernel(
    const float* __restrict__ A,
    const float* __restrict__ B0, const float* __restrict__ B1, const float* __restrict__ B2,
    float* __restrict__ C0, float* __restrict__ C1, float* __restrict__ C2,
    int M, int N, int Kd)
{
  const float* __restrict__ B = (blockIdx.z == 0) ? B0 : (blockIdx.z == 1 ? B1 : B2);
  float* __restrict__ C       = (blockIdx.z == 0) ? C0 : (blockIdx.z == 1 ? C1 : C2);
  __shared__ __align__(16) char AsB[128 * 32 * 2];
  __shared__ __align__(16) char BsB[128 * 32 * 2];
  const int tid = threadIdx.x;
  const int bm = blockIdx.y, bn = blockIdx.x;
  const int wid = tid >> 6, lane = tid & 63;
  const int wm = (wid >> 1) << 6, wn = (wid & 1) << 6;
  const int lr = lane & 15, kh = lane >> 4;

  f32x4v acc[4][4];
  const f32x4v z4 = {0.f, 0.f, 0.f, 0.f};
#pragma unroll
  for (int i = 0; i < 4; ++i)
#pragma unroll
    for (int j = 0; j < 4; ++j) acc[i][j] = z4;

  for (int k0 = 0; k0 < Kd; k0 += 32) {
    __syncthreads();
#pragma unroll
    for (int p = 0; p < 2; ++p) {
      int g = tid + (p << 8);
      int r = g >> 2;
      int kk = (g & 3) << 3;
      const float* src = A + (size_t)(bm * 128 + r) * Kd + k0 + kk;
      float4 f0 = *(const float4*)src;
      float4 f1 = *(const float4*)(src + 4);
      *(bf16x8v*)(AsB + (r << 6) + ((kk << 1) ^ ((r & 3) << 4))) = cvt8(f0, f1);
    }
    if (BT) {
#pragma unroll
      for (int p = 0; p < 2; ++p) {
        int g = tid + (p << 8);
        int r = g >> 2;
        int kk = (g & 3) << 3;
        const float* src = B + (size_t)(bn * 128 + r) * Kd + k0 + kk;
        float4 f0 = *(const float4*)src;
        float4 f1 = *(const float4*)(src + 4);
        *(bf16x8v*)(BsB + (r << 6) + ((kk << 1) ^ ((r & 3) << 4))) = cvt8(f0, f1);
      }
    } else {
#pragma unroll
      for (int p = 0; p < 2; ++p) {
        int g = tid + (p << 8);
        int k = g >> 4;
        int n8 = (g & 15) << 3;
        const float* src = B + (size_t)(k0 + k) * N + bn * 128 + n8;
        float4 f0 = *(const float4*)src;
        float4 f1 = *(const float4*)(src + 4);
        float fv[8] = {f0.x, f0.y, f0.z, f0.w, f1.x, f1.y, f1.z, f1.w};
#pragma unroll
        for (int i = 0; i < 8; ++i) {
          int r = n8 + i;
          *(__bf16*)(BsB + (r << 6) + (((k << 1)) ^ ((r & 3) << 4))) = (__bf16)fv[i];
        }
      }
    }
    __syncthreads();

    bf16x8v af[4], bfv[4];
#pragma unroll
    for (int i = 0; i < 4; ++i) {
      int r = wm + (i << 4) + lr;
      af[i] = *(const bf16x8v*)(AsB + (r << 6) + ((kh << 4) ^ ((r & 3) << 4)));
    }
#pragma unroll
    for (int i = 0; i < 4; ++i) {
      int r = wn + (i << 4) + lr;
      bfv[i] = *(const bf16x8v*)(BsB + (r << 6) + ((kh << 4) ^ ((r & 3) << 4)));
    }
#pragma unroll
    for (int mi = 0; mi < 4; ++mi)
#pragma unroll
      for (int ni = 0; ni < 4; ++ni)
        acc[mi][ni] = __builtin_amdgcn_mfma_f32_16x16x32_bf16(af[mi], bfv[ni], acc[mi][ni], 0, 0, 0);
  }

  const int cr0 = kh << 2;
#pragma unroll
  for (int mi = 0; mi < 4; ++mi)
#pragma unroll
    for (int ni = 0; ni < 4; ++ni)
#pragma unroll
      for (int r = 0; r < 4; ++r) {
        int row = bm * 128 + wm + (mi << 4) + cr0 + r;
        int col = bn * 128 + wn + (ni << 4) + lr;
        size_t idx = (size_t)row * N + col;
        if (ACCUM) C[idx] += acc[mi][ni][r];
        else       C[idx] = acc[mi][ni][r];
      }
}

// ---------------------------------------------------------------------------
// Compensated bf16 GEMM: A,B split hi/lo; acc += Ah*Bh + Ah*Bl + Al*Bh.
// Relative error ~1e-5 (vs 4e-3 plain). Used pre-router.
// ---------------------------------------------------------------------------
template<bool BT, bool ACCUM>
__global__ __launch_bounds__(256) void gemmc_kernel(
    const float* __restrict__ A,
    const float* __restrict__ B0, const float* __restrict__ B1, const float* __restrict__ B2,
    float* __restrict__ C0, float* __restrict__ C1, float* __restrict__ C2,
    int M, int N, int Kd)
{
  const float* __restrict__ B = (blockIdx.z == 0) ? B0 : (blockIdx.z == 1 ? B1 : B2);
  float* __restrict__ C       = (blockIdx.z == 0) ? C0 : (blockIdx.z == 1 ? C1 : C2);
  __shared__ __align__(16) char AsH[8192], AsL[8192], BsH[8192], BsL[8192];
  const int tid = threadIdx.x;
  const int bm = blockIdx.y, bn = blockIdx.x;
  const int wid = tid >> 6, lane = tid & 63;
  const int wm = (wid >> 1) << 6, wn = (wid & 1) << 6;
  const int lr = lane & 15, kh = lane >> 4;

  f32x4v acc[4][4];
  const f32x4v z4 = {0.f, 0.f, 0.f, 0.f};
#pragma unroll
  for (int i = 0; i < 4; ++i)
#pragma unroll
    for (int j = 0; j < 4; ++j) acc[i][j] = z4;

  for (int k0 = 0; k0 < Kd; k0 += 32) {
    __syncthreads();
#pragma unroll
    for (int p = 0; p < 2; ++p) {
      int g = tid + (p << 8);
      int r = g >> 2;
      int kk = (g & 3) << 3;
      const float* src = A + (size_t)(bm * 128 + r) * Kd + k0 + kk;
      float4 f0 = *(const float4*)src;
      float4 f1 = *(const float4*)(src + 4);
      bf16x8v hv, lv;
      split8(f0, f1, hv, lv);
      int off = (r << 6) + ((kk << 1) ^ ((r & 3) << 4));
      *(bf16x8v*)(AsH + off) = hv;
      *(bf16x8v*)(AsL + off) = lv;
    }
    if (BT) {
#pragma unroll
      for (int p = 0; p < 2; ++p) {
        int g = tid + (p << 8);
        int r = g >> 2;
        int kk = (g & 3) << 3;
        const float* src = B + (size_t)(bn * 128 + r) * Kd + k0 + kk;
        float4 f0 = *(const float4*)src;
        float4 f1 = *(const float4*)(src + 4);
        bf16x8v hv, lv;
        split8(f0, f1, hv, lv);
        int off = (r << 6) + ((kk << 1) ^ ((r & 3) << 4));
        *(bf16x8v*)(BsH + off) = hv;
        *(bf16x8v*)(BsL + off) = lv;
      }
    } else {
#pragma unroll
      for (int p = 0; p < 2; ++p) {
        int g = tid + (p << 8);
        int k = g >> 4;
        int n8 = (g & 15) << 3;
        const float* src = B + (size_t)(k0 + k) * N + bn * 128 + n8;
        float4 f0 = *(const float4*)src;
        float4 f1 = *(const float4*)(src + 4);
        float fv[8] = {f0.x, f0.y, f0.z, f0.w, f1.x, f1.y, f1.z, f1.w};
#pragma unroll
        for (int i = 0; i < 8; ++i) {
          int r = n8 + i;
          int off = (r << 6) + (((k << 1)) ^ ((r & 3) << 4));
          __bf16 hb = (__bf16)fv[i];
          *(__bf16*)(BsH + off) = hb;
          *(__bf16*)(BsL + off) = (__bf16)(fv[i] - (float)hb);
        }
      }
    }
    __syncthreads();

    bf16x8v ah[4], al[4], bh[4], bl[4];
#pragma unroll
    for (int i = 0; i < 4; ++i) {
      int r = wm + (i << 4) + lr;
      int off = (r << 6) + ((kh << 4) ^ ((r & 3) << 4));
      ah[i] = *(const bf16x8v*)(AsH + off);
      al[i] = *(const bf16x8v*)(AsL + off);
    }
#pragma unroll
    for (int i = 0; i < 4; ++i) {
      int r = wn + (i << 4) + lr;
      int off = (r << 6) + ((kh << 4) ^ ((r & 3) << 4));
      bh[i] = *(const bf16x8v*)(BsH + off);
      bl[i] = *(const bf16x8v*)(BsL + off);
    }
#pragma unroll
    for (int mi = 0; mi < 4; ++mi)
#pragma unroll
      for (int ni = 0; ni < 4; ++ni) {
        acc[mi][ni] = __builtin_amdgcn_mfma_f32_16x16x32_bf16(al[mi], bh[ni], acc[mi][ni], 0, 0, 0);
        acc[mi][ni] = __builtin_amdgcn_mfma_f32_16x16x32_bf16(ah[mi], bl[ni], acc[mi][ni], 0, 0, 0);
        acc[mi][ni] = __builtin_amdgcn_mfma_f32_16x16x32_bf16(ah[mi], bh[ni], acc[mi][ni], 0, 0, 0);
      }
  }

  const int cr0 = kh << 2;
#pragma unroll
  for (int mi = 0; mi < 4; ++mi)
#pragma unroll
    for (int ni = 0; ni < 4; ++ni)
#pragma unroll
      for (int r = 0; r < 4; ++r) {
        int row = bm * 128 + wm + (mi << 4) + cr0 + r;
        int col = bn * 128 + wn + (ni << 4) + lr;
        size_t idx = (size_t)row * N + col;
        if (ACCUM) C[idx] += acc[mi][ni][r];
        else       C[idx] = acc[mi][ni][r];
      }
}

// ---------------------------------------------------------------------------
// Plain strided GEMM for L3 attention (unchanged from round 2/3)
// ---------------------------------------------------------------------------
template<bool BT, bool ABF16, bool NGUARD>
__global__ __launch_bounds__(256) void gemm2_kernel(
    const void* __restrict__ Av, int lda,
    const float* __restrict__ B, int ldb,
    float* __restrict__ C, int ldc,
    int M, int N, int Kd)
{
  __shared__ __align__(16) char AsB[128 * 32 * 2];
  __shared__ __align__(16) char BsB[128 * 32 * 2];
  const int tid = threadIdx.x;
  const int bm = blockIdx.y, bn = blockIdx.x;
  const int wid = tid >> 6, lane = tid & 63;
  const int wm = (wid >> 1) << 6, wn = (wid & 1) << 6;
  const int lr = lane & 15, kh = lane >> 4;

  f32x4v acc[4][4];
  const f32x4v z4 = {0.f, 0.f, 0.f, 0.f};
#pragma unroll
  for (int i = 0; i < 4; ++i)
#pragma unroll
    for (int j = 0; j < 4; ++j) acc[i][j] = z4;

  for (int k0 = 0; k0 < Kd; k0 += 32) {
    __syncthreads();
#pragma unroll
    for (int p = 0; p < 2; ++p) {
      int g = tid + (p << 8);
      int r = g >> 2;
      int kk = (g & 3) << 3;
      if (ABF16) {
        const __bf16* src = (const __bf16*)Av + (size_t)(bm * 128 + r) * lda + k0 + kk;
        *(bf16x8v*)(AsB + (r << 6) + ((kk << 1) ^ ((r & 3) << 4))) = *(const bf16x8v*)src;
      } else {
        const float* src = (const float*)Av + (size_t)(bm * 128 + r) * lda + k0 + kk;
        float4 f0 = *(const float4*)src;
        float4 f1 = *(const float4*)(src + 4);
        *(bf16x8v*)(AsB + (r << 6) + ((kk << 1) ^ ((r & 3) << 4))) = cvt8(f0, f1);
      }
    }
    if (BT) {
#pragma unroll
      for (int p = 0; p < 2; ++p) {
        int g = tid + (p << 8);
        int r = g >> 2;
        int kk = (g & 3) << 3;
        const float* src = B + (size_t)(bn * 128 + r) * ldb + k0 + kk;
        float4 f0 = *(const float4*)src;
        float4 f1 = *(const float4*)(src + 4);
        *(bf16x8v*)(BsB + (r << 6) + ((kk << 1) ^ ((r & 3) << 4))) = cvt8(f0, f1);
      }
    } else {
#pragma unroll
      for (int p = 0; p < 2; ++p) {
        int g = tid + (p << 8);
        int k = g >> 4;
        int n8 = (g & 15) << 3;
        int colb = bn * 128 + n8;
        float fv[8] = {0.f, 0.f, 0.f, 0.f, 0.f, 0.f, 0.f, 0.f};
        if (!NGUARD || colb + 7 < N) {
          const float* src = B + (size_t)(k0 + k) * ldb + colb;
          float4 f0 = *(const float4*)src;
          float4 f1 = *(const float4*)(src + 4);
          fv[0] = f0.x; fv[1] = f0.y; fv[2] = f0.z; fv[3] = f0.w;
          fv[4] = f1.x; fv[5] = f1.y; fv[6] = f1.z; fv[7] = f1.w;
        }
#pragma unroll
        for (int i = 0; i < 8; ++i) {
          int r = n8 + i;
          *(__bf16*)(BsB + (r << 6) + (((k << 1)) ^ ((r & 3) << 4))) = (__bf16)fv[i];
        }
      }
    }
    __syncthreads();

    bf16x8v af[4], bfv[4];
#pragma unroll
    for (int i = 0; i < 4; ++i) {
      int r = wm + (i << 4) + lr;
      af[i] = *(const bf16x8v*)(AsB + (r << 6) + ((kh << 4) ^ ((r & 3) << 4)));
    }
#pragma unroll
    for (int i = 0; i < 4; ++i) {
      int r = wn + (i << 4) + lr;
      bfv[i] = *(const bf16x8v*)(BsB + (r << 6) + ((kh << 4) ^ ((r & 3) << 4)));
    }
#pragma unroll
    for (int mi = 0; mi < 4; ++mi)
#pragma unroll
      for (int ni = 0; ni < 4; ++ni)
        acc[mi][ni] = __builtin_amdgcn_mfma_f32_16x16x32_bf16(af[mi], bfv[ni], acc[mi][ni], 0, 0, 0);
  }

  const int cr0 = kh << 2;
#pragma unroll
  for (int mi = 0; mi < 4; ++mi)
#pragma unroll
    for (int ni = 0; ni < 4; ++ni)
#pragma unroll
      for (int r = 0; r < 4; ++r) {
        int row = bm * 128 + wm + (mi << 4) + cr0 + r;
        int col = bn * 128 + wn + (ni << 4) + lr;
        if (!NGUARD || col < N)
          C[(size_t)row * ldc + col] = acc[mi][ni][r];
      }
}

// ---------------------------------------------------------------------------
// Compensated strided GEMM (attention L0-2): A f32 (lda), B f32 (ldb)
// ---------------------------------------------------------------------------
template<bool BT, bool NGUARD>
__global__ __launch_bounds__(256) void gemm2c_kernel(
    const float* __restrict__ A, int lda,
    const float* __restrict__ B, int ldb,
    float* __restrict__ C, int ldc,
    int M, int N, int Kd)
{
  __shared__ __align__(16) char AsH[8192], AsL[8192], BsH[8192], BsL[8192];
  const int tid = threadIdx.x;
  const int bm = blockIdx.y, bn = blockIdx.x;
  const int wid = tid >> 6, lane = tid & 63;
  const int wm = (wid >> 1) << 6, wn = (wid & 1) << 6;
  const int lr = lane & 15, kh = lane >> 4;

  f32x4v acc[4][4];
  const f32x4v z4 = {0.f, 0.f, 0.f, 0.f};
#pragma unroll
  for (int i = 0; i < 4; ++i)
#pragma unroll
    for (int j = 0; j < 4; ++j) acc[i][j] = z4;

  for (int k0 = 0; k0 < Kd; k0 += 32) {
    __syncthreads();
#pragma unroll
    for (int p = 0; p < 2; ++p) {
      int g = tid + (p << 8);
      int r = g >> 2;
      int kk = (g & 3) << 3;
      const float* src = A + (size_t)(bm * 128 + r) * lda + k0 + kk;
      float4 f0 = *(const float4*)src;
      float4 f1 = *(const float4*)(src + 4);
      bf16x8v hv, lv;
      split8(f0, f1, hv, lv);
      int off = (r << 6) + ((kk << 1) ^ ((r & 3) << 4));
      *(bf16x8v*)(AsH + off) = hv;
      *(bf16x8v*)(AsL + off) = lv;
    }
    if (BT) {
#pragma unroll
      for (int p = 0; p < 2; ++p) {
        int g = tid + (p << 8);
        int r = g >> 2;
        int kk = (g & 3) << 3;
        const float* src = B + (size_t)(bn * 128 + r) * ldb + k0 + kk;
        float4 f0 = *(const float4*)src;
        float4 f1 = *(const float4*)(src + 4);
        bf16x8v hv, lv;
        split8(f0, f1, hv, lv);
        int off = (r << 6) + ((kk << 1) ^ ((r & 3) << 4));
        *(bf16x8v*)(BsH + off) = hv;
        *(bf16x8v*)(BsL + off) = lv;
      }
    } else {
#pragma unroll
      for (int p = 0; p < 2; ++p) {
        int g = tid + (p << 8);
        int k = g >> 4;
        int n8 = (g & 15) << 3;
        int colb = bn * 128 + n8;
        float fv[8] = {0.f, 0.f, 0.f, 0.f, 0.f, 0.f, 0.f, 0.f};
        if (!NGUARD || colb + 7 < N) {
          const float* src = B + (size_t)(k0 + k) * ldb + colb;
          float4 f0 = *(const float4*)src;
          float4 f1 = *(const float4*)(src + 4);
          fv[0] = f0.x; fv[1] = f0.y; fv[2] = f0.z; fv[3] = f0.w;
          fv[4] = f1.x; fv[5] = f1.y; fv[6] = f1.z; fv[7] = f1.w;
        }
#pragma unroll
        for (int i = 0; i < 8; ++i) {
          int r = n8 + i;
          int off = (r << 6) + (((k << 1)) ^ ((r & 3) << 4));
          __bf16 hb = (__bf16)fv[i];
          *(__bf16*)(BsH + off) = hb;
          *(__bf16*)(BsL + off) = (__bf16)(fv[i] - (float)hb);
        }
      }
    }
    __syncthreads();

    bf16x8v ah[4], al[4], bh[4], bl[4];
#pragma unroll
    for (int i = 0; i < 4; ++i) {
      int r = wm + (i << 4) + lr;
      int off = (r << 6) + ((kh << 4) ^ ((r & 3) << 4));
      ah[i] = *(const bf16x8v*)(AsH + off);
      al[i] = *(const bf16x8v*)(AsL + off);
    }
#pragma unroll
    for (int i = 0; i < 4; ++i) {
      int r = wn + (i << 4) + lr;
      int off = (r << 6) + ((kh << 4) ^ ((r & 3) << 4));
      bh[i] = *(const bf16x8v*)(BsH + off);
      bl[i] = *(const bf16x8v*)(BsL + off);
    }
#pragma unroll
    for (int mi = 0; mi < 4; ++mi)
#pragma unroll
      for (int ni = 0; ni < 4; ++ni) {
        acc[mi][ni] = __builtin_amdgcn_mfma_f32_16x16x32_bf16(al[mi], bh[ni], acc[mi][ni], 0, 0, 0);
        acc[mi][ni] = __builtin_amdgcn_mfma_f32_16x16x32_bf16(ah[mi], bl[ni], acc[mi][ni], 0, 0, 0);
        acc[mi][ni] = __builtin_amdgcn_mfma_f32_16x16x32_bf16(ah[mi], bh[ni], acc[mi][ni], 0, 0, 0);
      }
  }

  const int cr0 = kh << 2;
#pragma unroll
  for (int mi = 0; mi < 4; ++mi)
#pragma unroll
    for (int ni = 0; ni < 4; ++ni)
#pragma unroll
      for (int r = 0; r < 4; ++r) {
        int row = bm * 128 + wm + (mi << 4) + cr0 + r;
        int col = bn * 128 + wn + (ni << 4) + lr;
        if (!NGUARD || col < N)
          C[(size_t)row * ldc + col] = acc[mi][ni][r];
      }
}

// ---------------------------------------------------------------------------
// Row softmax with causal mask. PF variant writes f32 P (comp path).
// ---------------------------------------------------------------------------
template<bool PF>
__global__ __launch_bounds__(256) void smax_kernel(
    const float* __restrict__ SC, void* __restrict__ P)
{
  const int r = blockIdx.x;
  const int tid = threadIdx.x;
  const int wid = tid >> 6, lane = tid & 63;
  const int c0 = tid << 3;
  const float* row = SC + (size_t)r * SEQ;
  float4 a = ((const float4*)row)[tid * 2];
  float4 b = ((const float4*)row)[tid * 2 + 1];
  float v[8] = {a.x, a.y, a.z, a.w, b.x, b.y, b.z, b.w};

  __shared__ float redA[4], redB[4];
  float mx = -1e30f;
#pragma unroll
  for (int i = 0; i < 8; ++i)
    if (c0 + i <= r) mx = fmaxf(mx, v[i]);
#pragma unroll
  for (int d = 1; d < 64; d <<= 1) mx = fmaxf(mx, __shfl_xor(mx, d));
  if (lane == 0) redA[wid] = mx;
  __syncthreads();
  mx = fmaxf(fmaxf(redA[0], redA[1]), fmaxf(redA[2], redA[3]));

  float p8[8];
  float se = 0.f;
#pragma unroll
  for (int i = 0; i < 8; ++i) {
    p8[i] = (c0 + i <= r) ? __expf(v[i] - mx) : 0.f;
    se += p8[i];
  }
#pragma unroll
  for (int d = 1; d < 64; d <<= 1) se += __shfl_xor(se, d);
  if (lane == 0) redB[wid] = se;
  __syncthreads();
  se = redB[0] + redB[1] + redB[2] + redB[3];
  float inv = 1.f / se;

  if (PF) {
    float4 o0, o1;
    o0.x = p8[0] * inv; o0.y = p8[1] * inv; o0.z = p8[2] * inv; o0.w = p8[3] * inv;
    o1.x = p8[4] * inv; o1.y = p8[5] * inv; o1.z = p8[6] * inv; o1.w = p8[7] * inv;
    float* dst = (float*)P + (size_t)r * SEQ + c0;
    *(float4*)dst = o0;
    *(float4*)(dst + 4) = o1;
  } else {
    bf16x8v o8;
#pragma unroll
    for (int i = 0; i < 8; ++i) o8[i] = (__bf16)(p8[i] * inv);
    *(bf16x8v*)((__bf16*)P + (size_t)r * SEQ + c0) = o8;
  }
}

// ---------------------------------------------------------------------------
// Small kernels
// ---------------------------------------------------------------------------
__global__ void tables_kernel(float* __restrict__ CT, float* __restrict__ ST)
{
  int idx = blockIdx.x * 256 + threadIdx.x;
  int s = idx >> 5, i = idx & 31;
  double inv = exp(-log(10000.0) * (double)i / 32.0);
  double ang = (double)s * inv;
  CT[idx] = (float)cos(ang);
  ST[idx] = (float)sin(ang);
}

__global__ __launch_bounds__(256) void embed_kernel(
    const int* __restrict__ ids, const float* __restrict__ E, float* __restrict__ H)
{
  int t = blockIdx.x;
  int id = ids[t];
  ((float4*)(H + (size_t)t * HID))[threadIdx.x] =
      ((const float4*)(E + (size_t)id * HID))[threadIdx.x];
}

__global__ __launch_bounds__(256) void rmsnorm_kernel(
    const float* __restrict__ X, const float* __restrict__ W, float* __restrict__ O)
{
  int t = blockIdx.x;
  int tid = threadIdx.x;
  float4 v = ((const float4*)(X + (size_t)t * HID))[tid];
  float ss = v.x * v.x + v.y * v.y + v.z * v.z + v.w * v.w;
#pragma unroll
  for (int d = 1; d < 64; d <<= 1) ss += __shfl_xor(ss, d);
  __shared__ float red[4];
  if ((tid & 63) == 0) red[tid >> 6] = ss;
  __syncthreads();
  float tot = red[0] + red[1] + red[2] + red[3];
  float inv = 1.0f / sqrtf(tot * (1.0f / 1024.0f) + 1e-6f);
  float4 w = ((const float4*)W)[tid];
  float4 r;
  r.x = v.x * inv * w.x; r.y = v.y * inv * w.y;
  r.z = v.z * inv * w.z; r.w = v.w * inv * w.w;
  ((float4*)(O + (size_t)t * HID))[tid] = r;
}

__global__ __launch_bounds__(256) void rope_kernel(
    const float* __restrict__ X, float* __restrict__ O,
    const float* __restrict__ CT, const float* __restrict__ ST, float scale)
{
  int idx = blockIdx.x * 256 + threadIdx.x;
  int s = idx >> 9;
  int rr = idx & 511;
  int hd = rr >> 5;
  int i = rr & 31;
  float c = CT[(s << 5) + i], sn = ST[(s << 5) + i];
  size_t base = (size_t)s * HID + hd * 64 + i;
  float x1 = X[base], x2 = X[base + 32];
  O[base]      = (x1 * c - x2 * sn) * scale;
  O[base + 32] = (x2 * c + x1 * sn) * scale;
}

__global__ __launch_bounds__(256) void silu_kernel(
    const float* __restrict__ G, const float* __restrict__ U, float* __restrict__ A,
    const float* __restrict__ W, int e)
{
  int t = blockIdx.y;
  int i = blockIdx.x * 256 + threadIdx.x;
  size_t idx = (size_t)t * IDIM + i;
  float gv = G[idx], uv = U[idx];
  float s = gv / (1.f + __expf(-gv));
  float sc = W ? W[t * 8 + e] : 1.f;
  A[idx] = s * uv * sc;
}

__global__ __launch_bounds__(256) void router_kernel(
    const float* __restrict__ X, const float* __restrict__ RW, float* __restrict__ RL)
{
  int wid = threadIdx.x >> 6, lane = threadIdx.x & 63;
  int t = blockIdx.x * 4 + wid;
  const float* x = X + (size_t)t * HID;
  float a0 = 0, a1 = 0, a2 = 0, a3 = 0, a4 = 0, a5 = 0, a6 = 0, a7 = 0;
  for (int hh = lane; hh < HID; hh += 64) {
    float xv = x[hh];
    float4 f0 = *(const float4*)(RW + hh * 8);
    float4 f1 = *(const float4*)(RW + hh * 8 + 4);
    a0 += xv * f0.x; a1 += xv * f0.y; a2 += xv * f0.z; a3 += xv * f0.w;
    a4 += xv * f1.x; a5 += xv * f1.y; a6 += xv * f1.z; a7 += xv * f1.w;
  }
#pragma unroll
  for (int d = 1; d < 64; d <<= 1) {
    a0 += __shfl_xor(a0, d); a1 += __shfl_xor(a1, d);
    a2 += __shfl_xor(a2, d); a3 += __shfl_xor(a3, d);
    a4 += __shfl_xor(a4, d); a5 += __shfl_xor(a5, d);
    a6 += __shfl_xor(a6, d); a7 += __shfl_xor(a7, d);
  }
  if (lane == 0) {
    float* dst = RL + (size_t)t * 8;
    dst[0] = a0; dst[1] = a1; dst[2] = a2; dst[3] = a3;
    dst[4] = a4; dst[5] = a5; dst[6] = a6; dst[7] = a7;
  }
}

__global__ void zero_kernel(float* __restrict__ p, int n)
{
  int i = threadIdx.x;
  if (i < n) p[i] = 0.f;
}

__global__ __launch_bounds__(256) void topk_kernel(
    const float* __restrict__ RL, float* __restrict__ W, float* __restrict__ AUX)
{
  int t = blockIdx.x * 256 + threadIdx.x;
  int lane = threadIdx.x & 63;
  float r[8];
#pragma unroll
  for (int e = 0; e < 8; ++e) r[e] = RL[t * 8 + e];
  float mx = r[0];
#pragma unroll
  for (int e = 1; e < 8; ++e) mx = fmaxf(mx, r[e]);
  float p[8];
  float se = 0.f;
#pragma unroll
  for (int e = 0; e < 8; ++e) { p[e] = __expf(r[e] - mx); se += p[e]; }
  float inv = 1.f / se;
#pragma unroll
  for (int e = 0; e < 8; ++e) p[e] *= inv;
  float lse = logf(se) + mx;
  int i1 = 0; float v1 = p[0];
#pragma unroll
  for (int e = 1; e < 8; ++e) if (p[e] > v1) { v1 = p[e]; i1 = e; }
  int i2 = -1; float v2 = -1.f;
#pragma unroll
  for (int e = 0; e < 8; ++e) if (e != i1 && p[e] > v2) { v2 = p[e]; i2 = e; }
  float s12 = v1 + v2;
#pragma unroll
  for (int e = 0; e < 8; ++e)
    W[t * 8 + e] = (e == i1) ? v1 / s12 : ((e == i2) ? v2 / s12 : 0.f);
#pragma unroll
  for (int e = 0; e < 8; ++e) {
    float fe = ((i1 == e) ? 1.f : 0.f) + ((i2 == e) ? 1.f : 0.f);
    float pe = p[e];
#pragma unroll
    for (int d = 1; d < 64; d <<= 1) { fe += __shfl_xor(fe, d); pe += __shfl_xor(pe, d); }
    if (lane == 0) { atomicAdd(&AUX[e], fe); atomicAdd(&AUX[8 + e], pe); }
  }
  float zz = lse * lse;
#pragma unroll
  for (int d = 1; d < 64; d <<= 1) zz += __shfl_xor(zz, d);
  if (lane == 0) atomicAdd(&AUX[16], zz);
}

__global__ void aux_kernel(const float* __restrict__ AUX, float* __restrict__ OUT)
{
  float s = 0.f;
#pragma unroll
  for (int e = 0; e < 8; ++e)
    s += (AUX[e] * (1.f / 2048.f)) * (AUX[8 + e] * (1.f / 2048.f));
  float auxv = 0.01f * 8.f * s;
  float z = 0.001f * (AUX[16] * (1.f / 2048.f));
  OUT[(size_t)SEQ * VOCAB] = auxv + z;
}

__global__ __launch_bounds__(256) void copy_row_kernel(
    const float* __restrict__ src, float* __restrict__ dst)
{
  ((float4*)dst)[threadIdx.x] = ((const float4*)src)[threadIdx.x];
}

// ---------------------------------------------------------------------------
// Token-0 oracle: independent f32 recompute of token-0's whole chain,
// verified per stage against snapshots. Flags (bits added to out[0]):
//   A_l = 8<<(2l)  (attn residual stage, layer l)
//   F_l = 16<<(2l) (mlp/moe stage, layer l)
//   SEL = 2048 (main top-2 != oracle top-2), GAP = 4096 (token-0 gap < 2e-3)
//   LG  = 8192 (logits row 0 mismatch)
// ---------------------------------------------------------------------------
__device__ float block_sum256(float v, float* red) {
  int lane = threadIdx.x & 63, w = threadIdx.x >> 6;
#pragma unroll
  for (int d = 1; d < 64; d <<= 1) v += __shfl_xor(v, d);
  if (lane == 0) red[w] = v;
  __syncthreads();
  float s = red[0] + red[1] + red[2] + red[3];
  __syncthreads();
  return s;
}

__global__ __launch_bounds__(256) void oracle_kernel(
    const int* __restrict__ ids, const float* __restrict__ embed,
    const float* __restrict__ ln1, const float* __restrict__ ln2,
    const float* __restrict__ wv, const float* __restrict__ wo,
    const float* __restrict__ dg, const float* __restrict__ du, const float* __restrict__ dd,
    const float* __restrict__ rw,
    const float* __restrict__ mg, const float* __restrict__ mu, const float* __restrict__ md,
    const float* __restrict__ fin,
    const float* __restrict__ ha, const float* __restrict__ hf,
    const float* __restrict__ wmoe, float* __restrict__ out,
    float* __restrict__ flags)
{
  __shared__ float x[HID], hn[HID], t1[IDIM], t2[IDIM];
  __shared__ float red[4];
  __shared__ int cnt;
  __shared__ int si1, si2;
  __shared__ float sw1, sw2;
  const int tid = threadIdx.x;

  if (tid < 12) flags[tid] = 0.f;
  for (int i = tid; i < HID; i += 256) x[i] = embed[(size_t)ids[0] * HID + i];
  __syncthreads();

  for (int l = 0; l < 4; ++l) {
    // ---- attention stage: h2 = x + (rms(x)*ln1 @ wv) @ wo ----
    float ss = 0.f;
    for (int i = tid; i < HID; i += 256) ss += x[i] * x[i];
    ss = block_sum256(ss, red);
    float inv = 1.f / sqrtf(ss * (1.f / 1024.f) + 1e-6f);
    for (int i = tid; i < HID; i += 256) hn[i] = x[i] * inv * ln1[l * HID + i];
    __syncthreads();
    for (int c = tid; c < HID; c += 256) {
      float s = 0.f;
      const float* wc = wv + (size_t)l * HID * HID + c;
      for (int i = 0; i < HID; ++i) s += hn[i] * wc[(size_t)i * HID];
      t2[c] = s;
    }
    __syncthreads();
    if (tid == 0) cnt = 0;
    __syncthreads();
    int bad = 0;
    for (int c = tid; c < HID; c += 256) {
      float s = 0.f;
      const float* wc = wo + (size_t)l * HID * HID + c;
      for (int i = 0; i < HID; ++i) s += t2[i] * wc[(size_t)i * HID];
      if (fabsf(x[c] + s - ha[l * HID + c]) > 0.02f) bad++;
    }
    atomicAdd(&cnt, bad);
    __syncthreads();
    if (tid == 0) flags[l] = cnt > 8 ? (float)(8 << (2 * l)) : 0.f;
    __syncthreads();

    // ---- mlp/moe stage from snapshot ha[l] ----
    for (int i = tid; i < HID; i += 256) x[i] = ha[l * HID + i];
    __syncthreads();
    ss = 0.f;
    for (int i = tid; i < HID; i += 256) ss += x[i] * x[i];
    ss = block_sum256(ss, red);
    inv = 1.f / sqrtf(ss * (1.f / 1024.f) + 1e-6f);
    for (int i = tid; i < HID; i += 256) hn[i] = x[i] * inv * ln2[l * HID + i];
    __syncthreads();

    float yacc[4] = {0.f, 0.f, 0.f, 0.f};
    if (l != 2) {
      int d = (l < 2) ? l : l - 1;
      for (int c = tid; c < IDIM; c += 256) {
        float sg = 0.f, su = 0.f;
        const float* wg = dg + (size_t)d * HID * IDIM + c;
        const float* wu = du + (size_t)d * HID * IDIM + c;
        for (int i = 0; i < HID; ++i) {
          float hv = hn[i];
          sg += hv * wg[(size_t)i * IDIM];
          su += hv * wu[(size_t)i * IDIM];
        }
        t1[c] = sg / (1.f + __expf(-sg)) * su;
      }
      __syncthreads();
#pragma unroll
      for (int j = 0; j < 4; ++j) {
        int c = tid + j * 256;
        float s = 0.f;
        const float* wc = dd + (size_t)d * IDIM * HID + c;
        for (int i = 0; i < IDIM; ++i) s += t1[i] * wc[(size_t)i * HID];
        yacc[j] = s;
      }
    } else {
      // router + top-2 (oracle's own selection)
      __shared__ float rl8[8];
      if (tid < 8) {
        float s = 0.f;
        for (int i = 0; i < HID; ++i) s += hn[i] * rw[(size_t)i * 8 + tid];
        rl8[tid] = s;
      }
      __syncthreads();
      if (tid == 0) {
        float mx = rl8[0];
        for (int e = 1; e < 8; ++e) mx = fmaxf(mx, rl8[e]);
        float p[8], se = 0.f;
        for (int e = 0; e < 8; ++e) { p[e] = __expf(rl8[e] - mx); se += p[e]; }
        for (int e = 0; e < 8; ++e) p[e] /= se;
        int i1 = 0; float v1 = p[0];
        for (int e = 1; e < 8; ++e) if (p[e] > v1) { v1 = p[e]; i1 = e; }
        int i2 = -1; float v2 = -2.f;
        for (int e = 0; e < 8; ++e) if (e != i1 && p[e] > v2) { v2 = p[e]; i2 = e; }
        int i3 = -1; float v3 = -2.f;
        for (int e = 0; e < 8; ++e) if (e != i1 && e != i2 && p[e] > v3) { v3 = p[e]; i3 = e; }
        float w1 = v1 / (v1 + v2), w2 = v2 / (v1 + v2);
        bool selbad = (fabsf(wmoe[i1] - w1) > 1e-3f) || (fabsf(wmoe[i2] - w2) > 1e-3f);
        for (int e = 0; e < 8; ++e)
          if (e != i1 && e != i2 && wmoe[e] != 0.f) selbad = true;
        flags[8] = selbad ? 2048.f : 0.f;
        flags[9] = ((v2 - v3) < 0.002f) ? 4096.f : 0.f;
        si1 = i1; si2 = i2; sw1 = w1; sw2 = w2;
      }
      __syncthreads();
      for (int t = 0; t < 2; ++t) {
        int e = t ? si2 : si1;
        float wgt = t ? sw2 : sw1;
        for (int c = tid; c < IDIM; c += 256) {
          float sg = 0.f, su = 0.f;
          const float* wg = mg + (size_t)e * HID * IDIM + c;
          const float* wu = mu + (size_t)e * HID * IDIM + c;
          for (int i = 0; i < HID; ++i) {
            float hv = hn[i];
            sg += hv * wg[(size_t)i * IDIM];
            su += hv * wu[(size_t)i * IDIM];
          }
          t1[c] = sg / (1.f + __expf(-sg)) * su;
        }
        __syncthreads();
#pragma unroll
        for (int j = 0; j < 4; ++j) {
          int c = tid + j * 256;
          float s = 0.f;
          const float* wc = md + (size_t)e * IDIM * HID + c;
          for (int i = 0; i < IDIM; ++i) s += t1[i] * wc[(size_t)i * HID];
          yacc[j] += wgt * s;
        }
        __syncthreads();
      }
    }
    __syncthreads();
    if (tid == 0) cnt = 0;
    __syncthreads();
    int badf = 0;
#pragma unroll
    for (int j = 0; j < 4; ++j) {
      int c = tid + j * 256;
      if (fabsf(x[c] + yacc[j] - hf[l * HID + c]) > 0.02f) badf++;
    }
    atomicAdd(&cnt, badf);
    __syncthreads();
    if (tid == 0) flags[4 + l] = cnt > 8 ? (float)(16 << (2 * l)) : 0.f;
    __syncthreads();

    // next layer input = snapshot hf[l]
    for (int i = tid; i < HID; i += 256) x[i] = hf[l * HID + i];
    __syncthreads();
  }

  // ---- logits row 0 sample (every 4th col) ----
  float ss = 0.f;
  for (int i = tid; i < HID; i += 256) ss += x[i] * x[i];
  ss = block_sum256(ss, red);
  float inv = 1.f / sqrtf(ss * (1.f / 1024.f) + 1e-6f);
  for (int i = tid; i < HID; i += 256) hn[i] = x[i] * inv * fin[i];
  __syncthreads();
  if (tid == 0) cnt = 0;
  __syncthreads();
  int bad = 0;
  for (int c = tid * 4; c < VOCAB; c += 1024) {
    float s = 0.f;
    const float* er = embed + (size_t)c * HID;
    for (int i = 0; i < HID; ++i) s += hn[i] * er[i];
    if (fabsf(s - out[c]) > 0.06f) bad++;
  }
  atomicAdd(&cnt, bad);
  __syncthreads();
  if (tid == 0) {
    flags[10] = cnt > 2 ? 8192.f : 0.f;
    float fs = 0.f;
    for (int i = 0; i < 11; ++i) fs += flags[i];
    out[0] += fs;
  }
}

// ---------------------------------------------------------------------------
extern "C" void kernel_launch(void* const* d_in, const int* in_sizes, int n_in,
                              void* d_out, int out_size, void* d_ws, size_t ws_size,
                              hipStream_t stream)
{
  const int*   ids   = (const int*)d_in[0];
  const float* embed = (const float*)d_in[1];
  const float* ln1   = (const float*)d_in[2];
  const float* ln2   = (const float*)d_in[3];
  const float* wq    = (const float*)d_in[4];
  const float* wk    = (const float*)d_in[5];
  const float* wv    = (const float*)d_in[6];
  const float* wo    = (const float*)d_in[7];
  const float* dg    = (const float*)d_in[8];
  const float* du    = (const float*)d_in[9];
  const float* dd    = (const float*)d_in[10];
  const float* rw    = (const float*)d_in[11];
  const float* mg    = (const float*)d_in[12];
  const float* mu    = (const float*)d_in[13];
  const float* md    = (const float*)d_in[14];
  const float* fin   = (const float*)d_in[15];
  float* out = (float*)d_out;

  char* ws = (char*)d_ws;
  float*  h    = (float*) (ws + 0);
  float*  hn   = (float*) (ws + 8388608);
  float*  q    = (float*) (ws + 16777216);
  float*  k    = (float*) (ws + 25165824);
  float*  v    = (float*) (ws + 33554432);
  float*  o    = (float*) (ws + 41943040);
  float*  g    = (float*) (ws + 50331648);     // 23 MB (sc aliases)
  float*  u    = (float*) (ws + 73400320);     // 23 MB (P aliases)
  float*  qr   = (float*) (ws + 96468992);     // roped q f32
  float*  ct   = (float*) (ws + 104857600);
  float*  st   = (float*) (ws + 105119744);
  float*  rl   = (float*) (ws + 105381888);
  float*  wmoe = (float*) (ws + 105447424);
  float*  aux  = (float*) (ws + 105512960);    // 17 f
  float*  flags= (float*) (ws + 105513088);    // 12 f
  float*  ha   = (float*) (ws + 105513216);    // 4x1024 f
  float*  hf   = (float*) (ws + 105529600);    // 4x1024 f

  float*  sc   = g;                 // scores f32 16.8MB
  float*  pf   = u;                 // P f32 16.8MB (comp path)
  __bf16* pbuf = (__bf16*)u;        // P bf16 (plain path, L3)

  tables_kernel<<<256, 256, 0, stream>>>(ct, st);
  embed_kernel<<<SEQ, 256, 0, stream>>>(ids, embed, h);

  for (int li = 0; li < 4; ++li) {
    const bool comp = (li <= 2);   // selection-grade precision pre-router
    rmsnorm_kernel<<<SEQ, 256, 0, stream>>>(h, ln1 + li * HID, hn);
    size_t wofs = (size_t)li * HID * HID;
    if (comp)
      gemmc_kernel<false, false><<<dim3(8, 16, 3), 256, 0, stream>>>(
          hn, wq + wofs, wk + wofs, wv + wofs, q, k, v, SEQ, HID, HID);
    else
      gemm_kernel<false, false><<<dim3(8, 16, 3), 256, 0, stream>>>(
          hn, wq + wofs, wk + wofs, wv + wofs, q, k, v, SEQ, HID, HID);
    rope_kernel<<<4096, 256, 0, stream>>>(q, qr, ct, st, 0.125f);
    rope_kernel<<<4096, 256, 0, stream>>>(k, k, ct, st, 1.0f);

    for (int hh = 0; hh < NHEAD; ++hh) {
      if (comp) {
        gemm2c_kernel<true, false><<<dim3(16, 16), 256, 0, stream>>>(
            qr + hh * HDIM, HID, k + hh * HDIM, HID, sc, SEQ, SEQ, SEQ, HDIM);
        smax_kernel<true><<<SEQ, 256, 0, stream>>>(sc, pf);
        gemm2c_kernel<false, true><<<dim3(1, 16), 256, 0, stream>>>(
            pf, SEQ, v + hh * HDIM, HID, o + hh * HDIM, HID, SEQ, HDIM, SEQ);
      } else {
        gemm2_kernel<true, false, false><<<dim3(16, 16), 256, 0, stream>>>(
            (const void*)(qr + hh * HDIM), HID, k + hh * HDIM, HID,
            sc, SEQ, SEQ, SEQ, HDIM);
        smax_kernel<false><<<SEQ, 256, 0, stream>>>(sc, pbuf);
        gemm2_kernel<false, true, true><<<dim3(1, 16), 256, 0, stream>>>(
            (const void*)pbuf, SEQ, v + hh * HDIM, HID,
            o + hh * HDIM, HID, SEQ, HDIM, SEQ);
      }
    }

    if (comp)
      gemmc_kernel<false, true><<<dim3(8, 16, 1), 256, 0, stream>>>(
          o, wo + wofs, wo + wofs, wo + wofs, h, h, h, SEQ, HID, HID);
    else
      gemm_kernel<false, true><<<dim3(8, 16, 1), 256, 0, stream>>>(
          o, wo + wofs, wo + wofs, wo + wofs, h, h, h, SEQ, HID, HID);
    copy_row_kernel<<<1, 256, 0, stream>>>(h, ha + li * HID);

    rmsnorm_kernel<<<SEQ, 256, 0, stream>>>(h, ln2 + li * HID, hn);
    if (li == 2) {
      router_kernel<<<512, 256, 0, stream>>>(hn, rw, rl);
      zero_kernel<<<1, 32, 0, stream>>>(aux, 17);
      topk_kernel<<<8, 256, 0, stream>>>(rl, wmoe, aux);
      aux_kernel<<<1, 1, 0, stream>>>(aux, out);
      for (int e = 0; e < 8; ++e) {
        size_t go = (size_t)e * HID * IDIM;
        gemm_kernel<false, false><<<dim3(22, 16, 2), 256, 0, stream>>>(
            hn, mg + go, mu + go, mu + go, g, u, u, SEQ, IDIM, HID);
        silu_kernel<<<dim3(11, SEQ), 256, 0, stream>>>(g, u, g, wmoe, e);
        gemm_kernel<false, true><<<dim3(8, 16, 1), 256, 0, stream>>>(
            g, md + (size_t)e * IDIM * HID, md, md, h, h, h, SEQ, HID, IDIM);
      }
    } else {
      int d = (li < 2) ? li : li - 1;
      size_t go = (size_t)d * HID * IDIM;
      if (comp) {
        gemmc_kernel<false, false><<<dim3(22, 16, 2), 256, 0, stream>>>(
            hn, dg + go, du + go, du + go, g, u, u, SEQ, IDIM, HID);
        silu_kernel<<<dim3(11, SEQ), 256, 0, stream>>>(g, u, g, nullptr, 0);
        gemmc_kernel<false, true><<<dim3(8, 16, 1), 256, 0, stream>>>(
            g, dd + (size_t)d * IDIM * HID, dd, dd, h, h, h, SEQ, HID, IDIM);
      } else {
        gemm_kernel<false, false><<<dim3(22, 16, 2), 256, 0, stream>>>(
            hn, dg + go, du + go, du + go, g, u, u, SEQ, IDIM, HID);
        silu_kernel<<<dim3(11, SEQ), 256, 0, stream>>>(g, u, g, nullptr, 0);
        gemm_kernel<false, true><<<dim3(8, 16, 1), 256, 0, stream>>>(
            g, dd + (size_t)d * IDIM * HID, dd, dd, h, h, h, SEQ, HID, IDIM);
      }
    }
    copy_row_kernel<<<1, 256, 0, stream>>>(h, hf + li * HID);
  }
  rmsnorm_kernel<<<SEQ, 256, 0, stream>>>(h, fin, hn);
  gemm_kernel<true, false><<<dim3(250, 16, 1), 256, 0, stream>>>(
      hn, embed, embed, embed, out, out, out, SEQ, VOCAB, HID);

  oracle_kernel<<<1, 256, 0, stream>>>(
      ids, embed, ln1, ln2, wv, wo, dg, du, dd, rw, mg, mu, md, fin,
      ha, hf, wmoe, out, flags);
}

// Round 5
// 5931.991 us; speedup vs baseline: 4.6842x; 4.6842x over previous
//
#include <hip/hip_runtime.h>
#include <hip/hip_bf16.h>
#include <math.h>

#define SEQ 2048
#define HID 1024
#define NHEAD 16
#define HDIM 64
#define IDIM 2816
#define NEXP 8
#define VOCAB 32000

typedef float f32x4v __attribute__((ext_vector_type(4)));
typedef __bf16 bf16x8v __attribute__((ext_vector_type(8)));

__device__ __forceinline__ bf16x8v cvt8(const float4& a, const float4& b) {
  bf16x8v r;
  r[0] = (__bf16)a.x; r[1] = (__bf16)a.y; r[2] = (__bf16)a.z; r[3] = (__bf16)a.w;
  r[4] = (__bf16)b.x; r[5] = (__bf16)b.y; r[6] = (__bf16)b.z; r[7] = (__bf16)b.w;
  return r;
}

__device__ __forceinline__ void split8(const float4& a, const float4& b,
                                       bf16x8v& h, bf16x8v& l) {
  float f[8] = {a.x, a.y, a.z, a.w, b.x, b.y, b.z, b.w};
#pragma unroll
  for (int i = 0; i < 8; ++i) {
    __bf16 hb = (__bf16)f[i];
    h[i] = hb;
    l[i] = (__bf16)(f[i] - (float)hb);
  }
}

#define MFMA(a, b, c) __builtin_amdgcn_mfma_f32_16x16x32_bf16(a, b, c, 0, 0, 0)

// ---------------------------------------------------------------------------
// Plain bf16 GEMM (post-router: MoE handled by gather variants, L3 MLP, logits)
// ---------------------------------------------------------------------------
template<bool BT, bool ACCUM>
__global__ __launch_bounds__(256) void gemm_kernel(
    const float* __restrict__ A,
    const float* __restrict__ B0, const float* __restrict__ B1, const float* __restrict__ B2,
    float* __restrict__ C0, float* __restrict__ C1, float* __restrict__ C2,
    int M, int N, int Kd)
{
  const float* __restrict__ B = (blockIdx.z == 0) ? B0 : (blockIdx.z == 1 ? B1 : B2);
  float* __restrict__ C       = (blockIdx.z == 0) ? C0 : (blockIdx.z == 1 ? C1 : C2);
  __shared__ __align__(16) char AsB[8192];
  __shared__ __align__(16) char BsB[8192];
  const int tid = threadIdx.x;
  const int bm = blockIdx.y, bn = blockIdx.x;
  const int wid = tid >> 6, lane = tid & 63;
  const int wm = (wid >> 1) << 6, wn = (wid & 1) << 6;
  const int lr = lane & 15, kh = lane >> 4;

  f32x4v acc[4][4];
  const f32x4v z4 = {0.f, 0.f, 0.f, 0.f};
#pragma unroll
  for (int i = 0; i < 4; ++i)
#pragma unroll
    for (int j = 0; j < 4; ++j) acc[i][j] = z4;

  for (int k0 = 0; k0 < Kd; k0 += 32) {
    __syncthreads();
#pragma unroll
    for (int p = 0; p < 2; ++p) {
      int g = tid + (p << 8);
      int r = g >> 2;
      int kk = (g & 3) << 3;
      const float* src = A + (size_t)(bm * 128 + r) * Kd + k0 + kk;
      float4 f0 = *(const float4*)src;
      float4 f1 = *(const float4*)(src + 4);
      *(bf16x8v*)(AsB + (r << 6) + ((kk << 1) ^ ((r & 3) << 4))) = cvt8(f0, f1);
    }
    if (BT) {
#pragma unroll
      for (int p = 0; p < 2; ++p) {
        int g = tid + (p << 8);
        int r = g >> 2;
        int kk = (g & 3) << 3;
        const float* src = B + (size_t)(bn * 128 + r) * Kd + k0 + kk;
        float4 f0 = *(const float4*)src;
        float4 f1 = *(const float4*)(src + 4);
        *(bf16x8v*)(BsB + (r << 6) + ((kk << 1) ^ ((r & 3) << 4))) = cvt8(f0, f1);
      }
    } else {
#pragma unroll
      for (int p = 0; p < 2; ++p) {
        int g = tid + (p << 8);
        int k = g >> 4;
        int n8 = (g & 15) << 3;
        const float* src = B + (size_t)(k0 + k) * N + bn * 128 + n8;
        float4 f0 = *(const float4*)src;
        float4 f1 = *(const float4*)(src + 4);
        float fv[8] = {f0.x, f0.y, f0.z, f0.w, f1.x, f1.y, f1.z, f1.w};
#pragma unroll
        for (int i = 0; i < 8; ++i) {
          int r = n8 + i;
          *(__bf16*)(BsB + (r << 6) + (((k << 1)) ^ ((r & 3) << 4))) = (__bf16)fv[i];
        }
      }
    }
    __syncthreads();

    bf16x8v af[4], bfv[4];
#pragma unroll
    for (int i = 0; i < 4; ++i) {
      int r = wm + (i << 4) + lr;
      af[i] = *(const bf16x8v*)(AsB + (r << 6) + ((kh << 4) ^ ((r & 3) << 4)));
    }
#pragma unroll
    for (int i = 0; i < 4; ++i) {
      int r = wn + (i << 4) + lr;
      bfv[i] = *(const bf16x8v*)(BsB + (r << 6) + ((kh << 4) ^ ((r & 3) << 4)));
    }
#pragma unroll
    for (int mi = 0; mi < 4; ++mi)
#pragma unroll
      for (int ni = 0; ni < 4; ++ni)
        acc[mi][ni] = MFMA(af[mi], bfv[ni], acc[mi][ni]);
  }

  const int cr0 = kh << 2;
#pragma unroll
  for (int mi = 0; mi < 4; ++mi)
#pragma unroll
    for (int ni = 0; ni < 4; ++ni)
#pragma unroll
      for (int r = 0; r < 4; ++r) {
        int row = bm * 128 + wm + (mi << 4) + cr0 + r;
        int col = bn * 128 + wn + (ni << 4) + lr;
        size_t idx = (size_t)row * N + col;
        if (ACCUM) C[idx] += acc[mi][ni][r];
        else       C[idx] = acc[mi][ni][r];
      }
}

// ---------------------------------------------------------------------------
// Compensated bf16 GEMM (pre-router): acc += Al*Bh + Ah*Bl + Ah*Bh
// ---------------------------------------------------------------------------
template<bool BT, bool ACCUM>
__global__ __launch_bounds__(256) void gemmc_kernel(
    const float* __restrict__ A,
    const float* __restrict__ B0, const float* __restrict__ B1, const float* __restrict__ B2,
    float* __restrict__ C0, float* __restrict__ C1, float* __restrict__ C2,
    int M, int N, int Kd)
{
  const float* __restrict__ B = (blockIdx.z == 0) ? B0 : (blockIdx.z == 1 ? B1 : B2);
  float* __restrict__ C       = (blockIdx.z == 0) ? C0 : (blockIdx.z == 1 ? C1 : C2);
  __shared__ __align__(16) char AsH[8192], AsL[8192], BsH[8192], BsL[8192];
  const int tid = threadIdx.x;
  const int bm = blockIdx.y, bn = blockIdx.x;
  const int wid = tid >> 6, lane = tid & 63;
  const int wm = (wid >> 1) << 6, wn = (wid & 1) << 6;
  const int lr = lane & 15, kh = lane >> 4;

  f32x4v acc[4][4];
  const f32x4v z4 = {0.f, 0.f, 0.f, 0.f};
#pragma unroll
  for (int i = 0; i < 4; ++i)
#pragma unroll
    for (int j = 0; j < 4; ++j) acc[i][j] = z4;

  for (int k0 = 0; k0 < Kd; k0 += 32) {
    __syncthreads();
#pragma unroll
    for (int p = 0; p < 2; ++p) {
      int g = tid + (p << 8);
      int r = g >> 2;
      int kk = (g & 3) << 3;
      const float* src = A + (size_t)(bm * 128 + r) * Kd + k0 + kk;
      float4 f0 = *(const float4*)src;
      float4 f1 = *(const float4*)(src + 4);
      bf16x8v hv, lv;
      split8(f0, f1, hv, lv);
      int off = (r << 6) + ((kk << 1) ^ ((r & 3) << 4));
      *(bf16x8v*)(AsH + off) = hv;
      *(bf16x8v*)(AsL + off) = lv;
    }
    if (BT) {
#pragma unroll
      for (int p = 0; p < 2; ++p) {
        int g = tid + (p << 8);
        int r = g >> 2;
        int kk = (g & 3) << 3;
        const float* src = B + (size_t)(bn * 128 + r) * Kd + k0 + kk;
        float4 f0 = *(const float4*)src;
        float4 f1 = *(const float4*)(src + 4);
        bf16x8v hv, lv;
        split8(f0, f1, hv, lv);
        int off = (r << 6) + ((kk << 1) ^ ((r & 3) << 4));
        *(bf16x8v*)(BsH + off) = hv;
        *(bf16x8v*)(BsL + off) = lv;
      }
    } else {
#pragma unroll
      for (int p = 0; p < 2; ++p) {
        int g = tid + (p << 8);
        int k = g >> 4;
        int n8 = (g & 15) << 3;
        const float* src = B + (size_t)(k0 + k) * N + bn * 128 + n8;
        float4 f0 = *(const float4*)src;
        float4 f1 = *(const float4*)(src + 4);
        float fv[8] = {f0.x, f0.y, f0.z, f0.w, f1.x, f1.y, f1.z, f1.w};
#pragma unroll
        for (int i = 0; i < 8; ++i) {
          int r = n8 + i;
          int off = (r << 6) + (((k << 1)) ^ ((r & 3) << 4));
          __bf16 hb = (__bf16)fv[i];
          *(__bf16*)(BsH + off) = hb;
          *(__bf16*)(BsL + off) = (__bf16)(fv[i] - (float)hb);
        }
      }
    }
    __syncthreads();

    bf16x8v ah[4], al[4], bh[4], bl[4];
#pragma unroll
    for (int i = 0; i < 4; ++i) {
      int r = wm + (i << 4) + lr;
      int off = (r << 6) + ((kh << 4) ^ ((r & 3) << 4));
      ah[i] = *(const bf16x8v*)(AsH + off);
      al[i] = *(const bf16x8v*)(AsL + off);
    }
#pragma unroll
    for (int i = 0; i < 4; ++i) {
      int r = wn + (i << 4) + lr;
      int off = (r << 6) + ((kh << 4) ^ ((r & 3) << 4));
      bh[i] = *(const bf16x8v*)(BsH + off);
      bl[i] = *(const bf16x8v*)(BsL + off);
    }
#pragma unroll
    for (int mi = 0; mi < 4; ++mi)
#pragma unroll
      for (int ni = 0; ni < 4; ++ni) {
        acc[mi][ni] = MFMA(al[mi], bh[ni], acc[mi][ni]);
        acc[mi][ni] = MFMA(ah[mi], bl[ni], acc[mi][ni]);
        acc[mi][ni] = MFMA(ah[mi], bh[ni], acc[mi][ni]);
      }
  }

  const int cr0 = kh << 2;
#pragma unroll
  for (int mi = 0; mi < 4; ++mi)
#pragma unroll
    for (int ni = 0; ni < 4; ++ni)
#pragma unroll
      for (int r = 0; r < 4; ++r) {
        int row = bm * 128 + wm + (mi << 4) + cr0 + r;
        int col = bn * 128 + wn + (ni << 4) + lr;
        size_t idx = (size_t)row * N + col;
        if (ACCUM) C[idx] += acc[mi][ni][r];
        else       C[idx] = acc[mi][ni][r];
      }
}

// ---------------------------------------------------------------------------
// Compensated flash attention (causal). Grid (S/64, NH), 4 waves x 16 q-rows.
// Q pre-scaled f32 (rope folded 1/8); K roped f32; V f32. O f32.
// QK^T and PV each use 3-term hi/lo compensation (6 MFMA per 32-K slice pair).
// ---------------------------------------------------------------------------
__global__ __launch_bounds__(256) void attn_flash_kernel(
    const float* __restrict__ Q, const float* __restrict__ K,
    const float* __restrict__ V, float* __restrict__ O)
{
  const int qt = blockIdx.x;
  const int head = blockIdx.y;
  const int tid = threadIdx.x, wid = tid >> 6, lane = tid & 63;
  const int lr = lane & 15, kh = lane >> 4;
  __shared__ __align__(16) char KsH[8192], KsL[8192];   // [key 64][hd 64] bf16, swz
  __shared__ __align__(16) char VtH[8192], VtL[8192];   // [hd 64][key 64] bf16, swz
  __shared__ __align__(16) char PsH[4][2048], PsL[4][2048]; // per-wave [qrow 16][key 64]

  // Q fragments hi/lo, two 32-k halves
  const float* qrow = Q + (size_t)(qt * 64 + wid * 16 + lr) * HID + head * HDIM;
  bf16x8v qfh[2], qfl[2];
  {
    float4 a0 = *(const float4*)(qrow + (kh << 3));
    float4 b0 = *(const float4*)(qrow + (kh << 3) + 4);
    split8(a0, b0, qfh[0], qfl[0]);
    float4 a1 = *(const float4*)(qrow + 32 + (kh << 3));
    float4 b1 = *(const float4*)(qrow + 32 + (kh << 3) + 4);
    split8(a1, b1, qfh[1], qfl[1]);
  }

  float m_run[4], l_run[4];
  f32x4v oacc[4];
  const f32x4v z4 = {0.f, 0.f, 0.f, 0.f};
#pragma unroll
  for (int i = 0; i < 4; ++i) { m_run[i] = -1e30f; l_run[i] = 0.f; oacc[i] = z4; }

  for (int kt = 0; kt <= qt; ++kt) {
    __syncthreads();
#pragma unroll
    for (int p = 0; p < 2; ++p) {
      int g = tid + (p << 8);
      int r = g >> 3;                 // key 0..63
      int c8 = (g & 7) << 3;          // hd col
      const size_t gofs = (size_t)(kt * 64 + r) * HID + head * HDIM + c8;
      float4 f0 = *(const float4*)(K + gofs);
      float4 f1 = *(const float4*)(K + gofs + 4);
      bf16x8v hv, lv; split8(f0, f1, hv, lv);
      int koff = (r << 7) + ((c8 << 1) ^ ((r & 7) << 4));
      *(bf16x8v*)(KsH + koff) = hv;
      *(bf16x8v*)(KsL + koff) = lv;
      float4 g0 = *(const float4*)(V + gofs);
      float4 g1 = *(const float4*)(V + gofs + 4);
      bf16x8v wh, wl; split8(g0, g1, wh, wl);
#pragma unroll
      for (int j = 0; j < 8; ++j) {
        int vr = c8 + j;
        int voff = (vr << 7) + ((r << 1) ^ ((vr & 7) << 4));
        *(__bf16*)(VtH + voff) = wh[j];
        *(__bf16*)(VtL + voff) = wl[j];
      }
    }
    __syncthreads();

    // S = Q K^T (comp), 16 q-rows x 64 keys per wave
    float sv[4][4];
#pragma unroll
    for (int stt = 0; stt < 4; ++stt) {
      int r = (stt << 4) + lr;
      int off0 = (r << 7) + ((kh << 4) ^ ((r & 7) << 4));
      int off1 = (r << 7) + ((64 + (kh << 4)) ^ ((r & 7) << 4));
      bf16x8v kfh0 = *(const bf16x8v*)(KsH + off0);
      bf16x8v kfl0 = *(const bf16x8v*)(KsL + off0);
      bf16x8v kfh1 = *(const bf16x8v*)(KsH + off1);
      bf16x8v kfl1 = *(const bf16x8v*)(KsL + off1);
      f32x4v s = z4;
      s = MFMA(qfl[0], kfh0, s);
      s = MFMA(qfh[0], kfl0, s);
      s = MFMA(qfh[0], kfh0, s);
      s = MFMA(qfl[1], kfh1, s);
      s = MFMA(qfh[1], kfl1, s);
      s = MFMA(qfh[1], kfh1, s);
      int key = kt * 64 + (stt << 4) + lr;
#pragma unroll
      for (int rr = 0; rr < 4; ++rr) {
        int qr = qt * 64 + wid * 16 + (kh << 2) + rr;
        sv[stt][rr] = (key <= qr) ? s[rr] : -1e30f;
      }
    }

    // online softmax; P stored hi/lo bf16 in per-wave LDS
#pragma unroll
    for (int rr = 0; rr < 4; ++rr) {
      float mx = fmaxf(fmaxf(sv[0][rr], sv[1][rr]), fmaxf(sv[2][rr], sv[3][rr]));
#pragma unroll
      for (int d = 1; d < 16; d <<= 1) mx = fmaxf(mx, __shfl_xor(mx, d));
      float mnew = fmaxf(m_run[rr], mx);
      float scl = __expf(m_run[rr] - mnew);
      float pv[4];
#pragma unroll
      for (int stt = 0; stt < 4; ++stt) pv[stt] = __expf(sv[stt][rr] - mnew);
      float rs = pv[0] + pv[1] + pv[2] + pv[3];
#pragma unroll
      for (int d = 1; d < 16; d <<= 1) rs += __shfl_xor(rs, d);
      l_run[rr] = l_run[rr] * scl + rs;
      m_run[rr] = mnew;
#pragma unroll
      for (int n = 0; n < 4; ++n) oacc[n][rr] *= scl;
      int qlr = (kh << 2) + rr;
#pragma unroll
      for (int stt = 0; stt < 4; ++stt) {
        __bf16 hb = (__bf16)pv[stt];
        __bf16 lb = (__bf16)(pv[stt] - (float)hb);
        int off = (qlr << 7) + ((((stt << 4) + lr) << 1) ^ ((qlr & 7) << 4));
        *(__bf16*)(PsH[wid] + off) = hb;
        *(__bf16*)(PsL[wid] + off) = lb;
      }
    }

    // O += P V (comp)
    int poff0 = (lr << 7) + ((kh << 4) ^ ((lr & 7) << 4));
    int poff1 = (lr << 7) + ((64 + (kh << 4)) ^ ((lr & 7) << 4));
    bf16x8v pah0 = *(const bf16x8v*)(PsH[wid] + poff0);
    bf16x8v pal0 = *(const bf16x8v*)(PsL[wid] + poff0);
    bf16x8v pah1 = *(const bf16x8v*)(PsH[wid] + poff1);
    bf16x8v pal1 = *(const bf16x8v*)(PsL[wid] + poff1);
#pragma unroll
    for (int n = 0; n < 4; ++n) {
      int vr = (n << 4) + lr;
      int voff0 = (vr << 7) + ((kh << 4) ^ ((vr & 7) << 4));
      int voff1 = (vr << 7) + ((64 + (kh << 4)) ^ ((vr & 7) << 4));
      bf16x8v vfh0 = *(const bf16x8v*)(VtH + voff0);
      bf16x8v vfl0 = *(const bf16x8v*)(VtL + voff0);
      bf16x8v vfh1 = *(const bf16x8v*)(VtH + voff1);
      bf16x8v vfl1 = *(const bf16x8v*)(VtL + voff1);
      oacc[n] = MFMA(pal0, vfh0, oacc[n]);
      oacc[n] = MFMA(pah0, vfl0, oacc[n]);
      oacc[n] = MFMA(pah0, vfh0, oacc[n]);
      oacc[n] = MFMA(pal1, vfh1, oacc[n]);
      oacc[n] = MFMA(pah1, vfl1, oacc[n]);
      oacc[n] = MFMA(pah1, vfh1, oacc[n]);
    }
  }

#pragma unroll
  for (int n = 0; n < 4; ++n)
#pragma unroll
    for (int rr = 0; rr < 4; ++rr) {
      int qr = qt * 64 + wid * 16 + (kh << 2) + rr;
      O[(size_t)qr * HID + head * HDIM + (n << 4) + lr] = oacc[n][rr] / l_run[rr];
    }
}

// ---------------------------------------------------------------------------
// MoE gathered GEMMs (plain bf16; identical per-row numerics to dense pass)
// ---------------------------------------------------------------------------
// gate/up: A rows gathered from X via list; z: 0->B0/C0 (gate), 1->B1/C1 (up)
__global__ __launch_bounds__(256) void gemm_moe_gu_kernel(
    const float* __restrict__ X,
    const float* __restrict__ B0, const float* __restrict__ B1,
    float* __restrict__ C0, float* __restrict__ C1,
    const int* __restrict__ list, const int* __restrict__ cntp)
{
  const int cnt = cntp[0];
  const int bm = blockIdx.y, bn = blockIdx.x;
  if (bm * 128 >= cnt) return;
  const float* __restrict__ B = blockIdx.z ? B1 : B0;
  float* __restrict__ C       = blockIdx.z ? C1 : C0;
  __shared__ __align__(16) char AsB[8192];
  __shared__ __align__(16) char BsB[8192];
  const int tid = threadIdx.x;
  const int wid = tid >> 6, lane = tid & 63;
  const int wm = (wid >> 1) << 6, wn = (wid & 1) << 6;
  const int lr = lane & 15, kh = lane >> 4;

  f32x4v acc[4][4];
  const f32x4v z4 = {0.f, 0.f, 0.f, 0.f};
#pragma unroll
  for (int i = 0; i < 4; ++i)
#pragma unroll
    for (int j = 0; j < 4; ++j) acc[i][j] = z4;

  for (int k0 = 0; k0 < HID; k0 += 32) {
    __syncthreads();
#pragma unroll
    for (int p = 0; p < 2; ++p) {
      int g = tid + (p << 8);
      int r = g >> 2;
      int kk = (g & 3) << 3;
      int rg = bm * 128 + r;
      int tok = list[rg < cnt ? rg : cnt - 1];
      const float* src = X + (size_t)tok * HID + k0 + kk;
      float4 f0 = *(const float4*)src;
      float4 f1 = *(const float4*)(src + 4);
      *(bf16x8v*)(AsB + (r << 6) + ((kk << 1) ^ ((r & 3) << 4))) = cvt8(f0, f1);
    }
#pragma unroll
    for (int p = 0; p < 2; ++p) {
      int g = tid + (p << 8);
      int k = g >> 4;
      int n8 = (g & 15) << 3;
      const float* src = B + (size_t)(k0 + k) * IDIM + bn * 128 + n8;
      float4 f0 = *(const float4*)src;
      float4 f1 = *(const float4*)(src + 4);
      float fv[8] = {f0.x, f0.y, f0.z, f0.w, f1.x, f1.y, f1.z, f1.w};
#pragma unroll
      for (int i = 0; i < 8; ++i) {
        int r = n8 + i;
        *(__bf16*)(BsB + (r << 6) + (((k << 1)) ^ ((r & 3) << 4))) = (__bf16)fv[i];
      }
    }
    __syncthreads();

    bf16x8v af[4], bfv[4];
#pragma unroll
    for (int i = 0; i < 4; ++i) {
      int r = wm + (i << 4) + lr;
      af[i] = *(const bf16x8v*)(AsB + (r << 6) + ((kh << 4) ^ ((r & 3) << 4)));
    }
#pragma unroll
    for (int i = 0; i < 4; ++i) {
      int r = wn + (i << 4) + lr;
      bfv[i] = *(const bf16x8v*)(BsB + (r << 6) + ((kh << 4) ^ ((r & 3) << 4)));
    }
#pragma unroll
    for (int mi = 0; mi < 4; ++mi)
#pragma unroll
      for (int ni = 0; ni < 4; ++ni)
        acc[mi][ni] = MFMA(af[mi], bfv[ni], acc[mi][ni]);
  }

  const int cr0 = kh << 2;
#pragma unroll
  for (int mi = 0; mi < 4; ++mi)
#pragma unroll
    for (int ni = 0; ni < 4; ++ni)
#pragma unroll
      for (int r = 0; r < 4; ++r) {
        int row = bm * 128 + wm + (mi << 4) + cr0 + r;
        if (row < cnt) {
          int col = bn * 128 + wn + (ni << 4) + lr;
          C[(size_t)row * IDIM + col] = acc[mi][ni][r];
        }
      }
}

// down: A compact rows (G), C scatter-accumulate into H[list[row]]
__global__ __launch_bounds__(256) void gemm_moe_down_kernel(
    const float* __restrict__ G, const float* __restrict__ MD,
    float* __restrict__ H,
    const int* __restrict__ list, const int* __restrict__ cntp)
{
  const int cnt = cntp[0];
  const int bm = blockIdx.y, bn = blockIdx.x;
  if (bm * 128 >= cnt) return;
  __shared__ __align__(16) char AsB[8192];
  __shared__ __align__(16) char BsB[8192];
  const int tid = threadIdx.x;
  const int wid = tid >> 6, lane = tid & 63;
  const int wm = (wid >> 1) << 6, wn = (wid & 1) << 6;
  const int lr = lane & 15, kh = lane >> 4;

  f32x4v acc[4][4];
  const f32x4v z4 = {0.f, 0.f, 0.f, 0.f};
#pragma unroll
  for (int i = 0; i < 4; ++i)
#pragma unroll
    for (int j = 0; j < 4; ++j) acc[i][j] = z4;

  for (int k0 = 0; k0 < IDIM; k0 += 32) {
    __syncthreads();
#pragma unroll
    for (int p = 0; p < 2; ++p) {
      int g = tid + (p << 8);
      int r = g >> 2;
      int kk = (g & 3) << 3;
      int rg = bm * 128 + r;
      const float* src = G + (size_t)(rg < cnt ? rg : cnt - 1) * IDIM + k0 + kk;
      float4 f0 = *(const float4*)src;
      float4 f1 = *(const float4*)(src + 4);
      *(bf16x8v*)(AsB + (r << 6) + ((kk << 1) ^ ((r & 3) << 4))) = cvt8(f0, f1);
    }
#pragma unroll
    for (int p = 0; p < 2; ++p) {
      int g = tid + (p << 8);
      int k = g >> 4;
      int n8 = (g & 15) << 3;
      const float* src = MD + (size_t)(k0 + k) * HID + bn * 128 + n8;
      float4 f0 = *(const float4*)src;
      float4 f1 = *(const float4*)(src + 4);
      float fv[8] = {f0.x, f0.y, f0.z, f0.w, f1.x, f1.y, f1.z, f1.w};
#pragma unroll
      for (int i = 0; i < 8; ++i) {
        int r = n8 + i;
        *(__bf16*)(BsB + (r << 6) + (((k << 1)) ^ ((r & 3) << 4))) = (__bf16)fv[i];
      }
    }
    __syncthreads();

    bf16x8v af[4], bfv[4];
#pragma unroll
    for (int i = 0; i < 4; ++i) {
      int r = wm + (i << 4) + lr;
      af[i] = *(const bf16x8v*)(AsB + (r << 6) + ((kh << 4) ^ ((r & 3) << 4)));
    }
#pragma unroll
    for (int i = 0; i < 4; ++i) {
      int r = wn + (i << 4) + lr;
      bfv[i] = *(const bf16x8v*)(BsB + (r << 6) + ((kh << 4) ^ ((r & 3) << 4)));
    }
#pragma unroll
    for (int mi = 0; mi < 4; ++mi)
#pragma unroll
      for (int ni = 0; ni < 4; ++ni)
        acc[mi][ni] = MFMA(af[mi], bfv[ni], acc[mi][ni]);
  }

  const int cr0 = kh << 2;
#pragma unroll
  for (int mi = 0; mi < 4; ++mi)
#pragma unroll
    for (int ni = 0; ni < 4; ++ni)
#pragma unroll
      for (int r = 0; r < 4; ++r) {
        int row = bm * 128 + wm + (mi << 4) + cr0 + r;
        if (row < cnt) {
          int col = bn * 128 + wn + (ni << 4) + lr;
          H[(size_t)list[row] * HID + col] += acc[mi][ni][r];
        }
      }
}

// ---------------------------------------------------------------------------
// Small kernels
// ---------------------------------------------------------------------------
__global__ void tables_kernel(float* __restrict__ CT, float* __restrict__ ST)
{
  int idx = blockIdx.x * 256 + threadIdx.x;
  int s = idx >> 5, i = idx & 31;
  double inv = exp(-log(10000.0) * (double)i / 32.0);
  double ang = (double)s * inv;
  CT[idx] = (float)cos(ang);
  ST[idx] = (float)sin(ang);
}

__global__ __launch_bounds__(256) void embed_kernel(
    const int* __restrict__ ids, const float* __restrict__ E, float* __restrict__ H)
{
  int t = blockIdx.x;
  int id = ids[t];
  ((float4*)(H + (size_t)t * HID))[threadIdx.x] =
      ((const float4*)(E + (size_t)id * HID))[threadIdx.x];
}

__global__ __launch_bounds__(256) void rmsnorm_kernel(
    const float* __restrict__ X, const float* __restrict__ W, float* __restrict__ O)
{
  int t = blockIdx.x;
  int tid = threadIdx.x;
  float4 v = ((const float4*)(X + (size_t)t * HID))[tid];
  float ss = v.x * v.x + v.y * v.y + v.z * v.z + v.w * v.w;
#pragma unroll
  for (int d = 1; d < 64; d <<= 1) ss += __shfl_xor(ss, d);
  __shared__ float red[4];
  if ((tid & 63) == 0) red[tid >> 6] = ss;
  __syncthreads();
  float tot = red[0] + red[1] + red[2] + red[3];
  float inv = 1.0f / sqrtf(tot * (1.0f / 1024.0f) + 1e-6f);
  float4 w = ((const float4*)W)[tid];
  float4 r;
  r.x = v.x * inv * w.x; r.y = v.y * inv * w.y;
  r.z = v.z * inv * w.z; r.w = v.w * inv * w.w;
  ((float4*)(O + (size_t)t * HID))[tid] = r;
}

// rope in-place (per-thread read-before-write, disjoint pairs)
__global__ __launch_bounds__(256) void rope_kernel(
    float* __restrict__ X,
    const float* __restrict__ CT, const float* __restrict__ ST, float scale)
{
  int idx = blockIdx.x * 256 + threadIdx.x;
  int s = idx >> 9;
  int rr = idx & 511;
  int hd = rr >> 5;
  int i = rr & 31;
  float c = CT[(s << 5) + i], sn = ST[(s << 5) + i];
  size_t base = (size_t)s * HID + hd * 64 + i;
  float x1 = X[base], x2 = X[base + 32];
  X[base]      = (x1 * c - x2 * sn) * scale;
  X[base + 32] = (x2 * c + x1 * sn) * scale;
}

__global__ __launch_bounds__(256) void silu_kernel(
    const float* __restrict__ G, const float* __restrict__ U, float* __restrict__ A)
{
  int t = blockIdx.y;
  int i = blockIdx.x * 256 + threadIdx.x;
  size_t idx = (size_t)t * IDIM + i;
  float gv = G[idx], uv = U[idx];
  A[idx] = gv / (1.f + __expf(-gv)) * uv;
}

// compacted silu with router weight folded in
__global__ __launch_bounds__(256) void silu_moe_kernel(
    const float* __restrict__ G, const float* __restrict__ U, float* __restrict__ A,
    const float* __restrict__ W, const int* __restrict__ list,
    const int* __restrict__ cntp, int e)
{
  int t = blockIdx.y;
  if (t >= cntp[0]) return;
  int i = blockIdx.x * 256 + threadIdx.x;
  size_t idx = (size_t)t * IDIM + i;
  float gv = G[idx], uv = U[idx];
  A[idx] = gv / (1.f + __expf(-gv)) * uv * W[list[t] * 8 + e];
}

__global__ __launch_bounds__(256) void router_kernel(
    const float* __restrict__ X, const float* __restrict__ RW, float* __restrict__ RL)
{
  int wid = threadIdx.x >> 6, lane = threadIdx.x & 63;
  int t = blockIdx.x * 4 + wid;
  const float* x = X + (size_t)t * HID;
  float a0 = 0, a1 = 0, a2 = 0, a3 = 0, a4 = 0, a5 = 0, a6 = 0, a7 = 0;
  for (int hh = lane; hh < HID; hh += 64) {
    float xv = x[hh];
    float4 f0 = *(const float4*)(RW + hh * 8);
    float4 f1 = *(const float4*)(RW + hh * 8 + 4);
    a0 += xv * f0.x; a1 += xv * f0.y; a2 += xv * f0.z; a3 += xv * f0.w;
    a4 += xv * f1.x; a5 += xv * f1.y; a6 += xv * f1.z; a7 += xv * f1.w;
  }
#pragma unroll
  for (int d = 1; d < 64; d <<= 1) {
    a0 += __shfl_xor(a0, d); a1 += __shfl_xor(a1, d);
    a2 += __shfl_xor(a2, d); a3 += __shfl_xor(a3, d);
    a4 += __shfl_xor(a4, d); a5 += __shfl_xor(a5, d);
    a6 += __shfl_xor(a6, d); a7 += __shfl_xor(a7, d);
  }
  if (lane == 0) {
    float* dst = RL + (size_t)t * 8;
    dst[0] = a0; dst[1] = a1; dst[2] = a2; dst[3] = a3;
    dst[4] = a4; dst[5] = a5; dst[6] = a6; dst[7] = a7;
  }
}

__global__ void zero_kernel(float* __restrict__ p, int n)
{
  int i = threadIdx.x;
  if (i < n) p[i] = 0.f;
}

__global__ void zeroi_kernel(int* __restrict__ p, int n)
{
  int i = threadIdx.x;
  if (i < n) p[i] = 0;
}

__global__ __launch_bounds__(256) void topk_kernel(
    const float* __restrict__ RL, float* __restrict__ W, float* __restrict__ AUX)
{
  int t = blockIdx.x * 256 + threadIdx.x;
  int lane = threadIdx.x & 63;
  float r[8];
#pragma unroll
  for (int e = 0; e < 8; ++e) r[e] = RL[t * 8 + e];
  float mx = r[0];
#pragma unroll
  for (int e = 1; e < 8; ++e) mx = fmaxf(mx, r[e]);
  float p[8];
  float se = 0.f;
#pragma unroll
  for (int e = 0; e < 8; ++e) { p[e] = __expf(r[e] - mx); se += p[e]; }
  float inv = 1.f / se;
#pragma unroll
  for (int e = 0; e < 8; ++e) p[e] *= inv;
  float lse = logf(se) + mx;
  int i1 = 0; float v1 = p[0];
#pragma unroll
  for (int e = 1; e < 8; ++e) if (p[e] > v1) { v1 = p[e]; i1 = e; }
  int i2 = -1; float v2 = -1.f;
#pragma unroll
  for (int e = 0; e < 8; ++e) if (e != i1 && p[e] > v2) { v2 = p[e]; i2 = e; }
  float s12 = v1 + v2;
#pragma unroll
  for (int e = 0; e < 8; ++e)
    W[t * 8 + e] = (e == i1) ? v1 / s12 : ((e == i2) ? v2 / s12 : 0.f);
#pragma unroll
  for (int e = 0; e < 8; ++e) {
    float fe = ((i1 == e) ? 1.f : 0.f) + ((i2 == e) ? 1.f : 0.f);
    float pe = p[e];
#pragma unroll
    for (int d = 1; d < 64; d <<= 1) { fe += __shfl_xor(fe, d); pe += __shfl_xor(pe, d); }
    if (lane == 0) { atomicAdd(&AUX[e], fe); atomicAdd(&AUX[8 + e], pe); }
  }
  float zz = lse * lse;
#pragma unroll
  for (int d = 1; d < 64; d <<= 1) zz += __shfl_xor(zz, d);
  if (lane == 0) atomicAdd(&AUX[16], zz);
}

__global__ void aux_kernel(const float* __restrict__ AUX, float* __restrict__ OUT)
{
  float s = 0.f;
#pragma unroll
  for (int e = 0; e < 8; ++e)
    s += (AUX[e] * (1.f / 2048.f)) * (AUX[8 + e] * (1.f / 2048.f));
  float auxv = 0.01f * 8.f * s;
  float z = 0.001f * (AUX[16] * (1.f / 2048.f));
  OUT[(size_t)SEQ * VOCAB] = auxv + z;
}

// per-expert token lists (list order nondeterministic; outputs order-invariant)
__global__ __launch_bounds__(256) void build_list_kernel(
    const float* __restrict__ W, int* __restrict__ cnt, int* __restrict__ list)
{
  int t = blockIdx.x * 256 + threadIdx.x;
#pragma unroll
  for (int e = 0; e < 8; ++e) {
    if (W[t * 8 + e] > 0.f) {
      int p = atomicAdd(&cnt[e], 1);
      list[e * SEQ + p] = t;
    }
  }
}

// ---------------------------------------------------------------------------
extern "C" void kernel_launch(void* const* d_in, const int* in_sizes, int n_in,
                              void* d_out, int out_size, void* d_ws, size_t ws_size,
                              hipStream_t stream)
{
  const int*   ids   = (const int*)d_in[0];
  const float* embed = (const float*)d_in[1];
  const float* ln1   = (const float*)d_in[2];
  const float* ln2   = (const float*)d_in[3];
  const float* wq    = (const float*)d_in[4];
  const float* wk    = (const float*)d_in[5];
  const float* wv    = (const float*)d_in[6];
  const float* wo    = (const float*)d_in[7];
  const float* dg    = (const float*)d_in[8];
  const float* du    = (const float*)d_in[9];
  const float* dd    = (const float*)d_in[10];
  const float* rw    = (const float*)d_in[11];
  const float* mg    = (const float*)d_in[12];
  const float* mu    = (const float*)d_in[13];
  const float* md    = (const float*)d_in[14];
  const float* fin   = (const float*)d_in[15];
  float* out = (float*)d_out;

  char* ws = (char*)d_ws;
  float* h    = (float*)(ws + 0);            // 2048x1024 f32
  float* hn   = (float*)(ws + 8388608);
  float* q    = (float*)(ws + 16777216);
  float* k    = (float*)(ws + 25165824);
  float* v    = (float*)(ws + 33554432);
  float* o    = (float*)(ws + 41943040);
  float* g    = (float*)(ws + 50331648);     // 2048x2816 f32
  float* u    = (float*)(ws + 73400320);
  float* ct   = (float*)(ws + 96468992);     // 2048x32
  float* st   = (float*)(ws + 96731136);
  float* rl   = (float*)(ws + 96993280);     // 2048x8
  float* wmoe = (float*)(ws + 97058816);
  float* aux  = (float*)(ws + 97124352);     // 17 f
  int*   cnt  = (int*)  (ws + 97124608);     // 8 i
  int*   list = (int*)  (ws + 97124864);     // 8x2048 i

  tables_kernel<<<256, 256, 0, stream>>>(ct, st);
  embed_kernel<<<SEQ, 256, 0, stream>>>(ids, embed, h);

  for (int li = 0; li < 4; ++li) {
    const bool comp = (li <= 2);   // selection-grade precision pre-router
    rmsnorm_kernel<<<SEQ, 256, 0, stream>>>(h, ln1 + li * HID, hn);
    size_t wofs = (size_t)li * HID * HID;
    if (comp)
      gemmc_kernel<false, false><<<dim3(8, 16, 3), 256, 0, stream>>>(
          hn, wq + wofs, wk + wofs, wv + wofs, q, k, v, SEQ, HID, HID);
    else
      gemm_kernel<false, false><<<dim3(8, 16, 3), 256, 0, stream>>>(
          hn, wq + wofs, wk + wofs, wv + wofs, q, k, v, SEQ, HID, HID);
    rope_kernel<<<4096, 256, 0, stream>>>(q, ct, st, 0.125f);
    rope_kernel<<<4096, 256, 0, stream>>>(k, ct, st, 1.0f);

    attn_flash_kernel<<<dim3(32, 16), 256, 0, stream>>>(q, k, v, o);

    if (comp)
      gemmc_kernel<false, true><<<dim3(8, 16, 1), 256, 0, stream>>>(
          o, wo + wofs, wo + wofs, wo + wofs, h, h, h, SEQ, HID, HID);
    else
      gemm_kernel<false, true><<<dim3(8, 16, 1), 256, 0, stream>>>(
          o, wo + wofs, wo + wofs, wo + wofs, h, h, h, SEQ, HID, HID);

    rmsnorm_kernel<<<SEQ, 256, 0, stream>>>(h, ln2 + li * HID, hn);
    if (li == 2) {
      router_kernel<<<512, 256, 0, stream>>>(hn, rw, rl);
      zero_kernel<<<1, 32, 0, stream>>>(aux, 17);
      topk_kernel<<<8, 256, 0, stream>>>(rl, wmoe, aux);
      aux_kernel<<<1, 1, 0, stream>>>(aux, out);
      zeroi_kernel<<<1, 32, 0, stream>>>(cnt, 8);
      build_list_kernel<<<8, 256, 0, stream>>>(wmoe, cnt, list);
      for (int e = 0; e < 8; ++e) {
        size_t go = (size_t)e * HID * IDIM;
        gemm_moe_gu_kernel<<<dim3(22, 16, 2), 256, 0, stream>>>(
            hn, mg + go, mu + go, g, u, list + e * SEQ, cnt + e);
        silu_moe_kernel<<<dim3(11, SEQ), 256, 0, stream>>>(
            g, u, g, wmoe, list + e * SEQ, cnt + e, e);
        gemm_moe_down_kernel<<<dim3(8, 16), 256, 0, stream>>>(
            g, md + (size_t)e * IDIM * HID, h, list + e * SEQ, cnt + e);
      }
    } else {
      int d = (li < 2) ? li : li - 1;
      size_t go = (size_t)d * HID * IDIM;
      if (comp) {
        gemmc_kernel<false, false><<<dim3(22, 16, 2), 256, 0, stream>>>(
            hn, dg + go, du + go, du + go, g, u, u, SEQ, IDIM, HID);
        silu_kernel<<<dim3(11, SEQ), 256, 0, stream>>>(g, u, g);
        gemmc_kernel<false, true><<<dim3(8, 16, 1), 256, 0, stream>>>(
            g, dd + (size_t)d * IDIM * HID, dd, dd, h, h, h, SEQ, HID, IDIM);
      } else {
        gemm_kernel<false, false><<<dim3(22, 16, 2), 256, 0, stream>>>(
            hn, dg + go, du + go, du + go, g, u, u, SEQ, IDIM, HID);
        silu_kernel<<<dim3(11, SEQ), 256, 0, stream>>>(g, u, g);
        gemm_kernel<false, true><<<dim3(8, 16, 1), 256, 0, stream>>>(
            g, dd + (size_t)d * IDIM * HID, dd, dd, h, h, h, SEQ, HID, IDIM);
      }
    }
  }
  rmsnorm_kernel<<<SEQ, 256, 0, stream>>>(h, fin, hn);
  gemm_kernel<true, false><<<dim3(250, 16, 1), 256, 0, stream>>>(
      hn, embed, embed, embed, out, out, out, SEQ, VOCAB, HID);
}

// Round 6
// 4684.019 us; speedup vs baseline: 5.9322x; 1.2664x over previous
//
#include <hip/hip_runtime.h>
#include <hip/hip_bf16.h>
#include <math.h>

#define SEQ 2048
#define HID 1024
#define NHEAD 16
#define HDIM 64
#define IDIM 2816
#define NEXP 8
#define VOCAB 32000

typedef float f32x4v __attribute__((ext_vector_type(4)));
typedef __bf16 bf16x8v __attribute__((ext_vector_type(8)));

__device__ __forceinline__ bf16x8v cvt8(const float4& a, const float4& b) {
  bf16x8v r;
  r[0] = (__bf16)a.x; r[1] = (__bf16)a.y; r[2] = (__bf16)a.z; r[3] = (__bf16)a.w;
  r[4] = (__bf16)b.x; r[5] = (__bf16)b.y; r[6] = (__bf16)b.z; r[7] = (__bf16)b.w;
  return r;
}

__device__ __forceinline__ void split8(const float4& a, const float4& b,
                                       bf16x8v& h, bf16x8v& l) {
  float f[8] = {a.x, a.y, a.z, a.w, b.x, b.y, b.z, b.w};
#pragma unroll
  for (int i = 0; i < 8; ++i) {
    __bf16 hb = (__bf16)f[i];
    h[i] = hb;
    l[i] = (__bf16)(f[i] - (float)hb);
  }
}

#define MFMA(a, b, c) __builtin_amdgcn_mfma_f32_16x16x32_bf16(a, b, c, 0, 0, 0)

// ---------------------------------------------------------------------------
// Weight preprocessing: W[K,N] f32 -> WH,WL [N,K] bf16 (transposed hi/lo).
// Grid (N/64, K/64, nz). Values identical to inline split8 (numerics-neutral).
// ---------------------------------------------------------------------------
__global__ __launch_bounds__(256) void wsplit_t_kernel(
    const float* __restrict__ W, __bf16* __restrict__ WH, __bf16* __restrict__ WL,
    int K, int N)
{
  __shared__ float tile[64][65];
  const int tid = threadIdx.x;
  const size_t zofs = (size_t)blockIdx.z * K * N;
  const int n0 = blockIdx.x * 64, k0 = blockIdx.y * 64;
#pragma unroll
  for (int r = 0; r < 4; ++r) {
    int kk = (tid >> 4) + r * 16;
    int nn = (tid & 15) * 4;
    float4 v = *(const float4*)(W + zofs + (size_t)(k0 + kk) * N + n0 + nn);
    tile[kk][nn] = v.x; tile[kk][nn + 1] = v.y;
    tile[kk][nn + 2] = v.z; tile[kk][nn + 3] = v.w;
  }
  __syncthreads();
  const int nn = tid >> 2;
  const int kk = (tid & 3) * 16;
  __bf16* dh = WH + zofs + (size_t)(n0 + nn) * K + k0 + kk;
  __bf16* dl = WL + zofs + (size_t)(n0 + nn) * K + k0 + kk;
  bf16x8v h0, l0, h1, l1;
#pragma unroll
  for (int j = 0; j < 8; ++j) {
    float f = tile[kk + j][nn];
    __bf16 hb = (__bf16)f; h0[j] = hb; l0[j] = (__bf16)(f - (float)hb);
    f = tile[kk + 8 + j][nn];
    hb = (__bf16)f; h1[j] = hb; l1[j] = (__bf16)(f - (float)hb);
  }
  *(bf16x8v*)dh = h0; *(bf16x8v*)(dh + 8) = h1;
  *(bf16x8v*)dl = l0; *(bf16x8v*)(dl + 8) = l1;
}

// embed f32 -> bf16 hi (no transpose; logits B is already [N,K])
__global__ __launch_bounds__(256) void esplit_kernel(
    const float* __restrict__ E, __bf16* __restrict__ EH)
{
  size_t i = ((size_t)blockIdx.x * 256 + threadIdx.x) * 8;
  float4 a = *(const float4*)(E + i);
  float4 b = *(const float4*)(E + i + 4);
  *(bf16x8v*)(EH + i) = cvt8(a, b);
}

// ---------------------------------------------------------------------------
// Unified BT GEMM: C[M,N] (+)= A[M,K] * B^T, B pre-split bf16 [N,K].
// COMP: acc += Al*Bh + Ah*Bl + Ah*Bh (A split in-kernel). 128x128 tile, BK=32.
// SWAP: bm from blockIdx.x (B-panel reuse for wide-N GEMMs, e.g. logits).
// blockIdx.z selects (B,C) set for batched launches.
// ---------------------------------------------------------------------------
template<bool COMP, bool ACCUM, bool SWAP>
__global__ __launch_bounds__(256) void gemm_bt_kernel(
    const float* __restrict__ A,
    const __bf16* __restrict__ B0h, const __bf16* __restrict__ B0l,
    const __bf16* __restrict__ B1h, const __bf16* __restrict__ B1l,
    const __bf16* __restrict__ B2h, const __bf16* __restrict__ B2l,
    float* __restrict__ C0, float* __restrict__ C1, float* __restrict__ C2,
    int M, int N, int Kd)
{
  const __bf16* __restrict__ Bh = (blockIdx.z == 0) ? B0h : (blockIdx.z == 1 ? B1h : B2h);
  const __bf16* __restrict__ Bl = (blockIdx.z == 0) ? B0l : (blockIdx.z == 1 ? B1l : B2l);
  float* __restrict__ C         = (blockIdx.z == 0) ? C0 : (blockIdx.z == 1 ? C1 : C2);
  __shared__ __align__(16) char smem[COMP ? 32768 : 16384];
  char* AsH = smem;
  char* BsH = smem + 8192;
  char* AsL = COMP ? smem + 16384 : smem;
  char* BsL = COMP ? smem + 24576 : smem + 8192;
  const int tid = threadIdx.x;
  const int bm = SWAP ? blockIdx.x : blockIdx.y;
  const int bn = SWAP ? blockIdx.y : blockIdx.x;
  const int wid = tid >> 6, lane = tid & 63;
  const int wm = (wid >> 1) << 6, wn = (wid & 1) << 6;
  const int lr = lane & 15, kh = lane >> 4;

  f32x4v acc[4][4];
  const f32x4v z4 = {0.f, 0.f, 0.f, 0.f};
#pragma unroll
  for (int i = 0; i < 4; ++i)
#pragma unroll
    for (int j = 0; j < 4; ++j) acc[i][j] = z4;

  for (int k0 = 0; k0 < Kd; k0 += 32) {
    __syncthreads();
#pragma unroll
    for (int p = 0; p < 2; ++p) {
      int g = tid + (p << 8);
      int r = g >> 2;
      int kk = (g & 3) << 3;
      int off = (r << 6) + ((kk << 1) ^ ((r & 3) << 4));
      const float* src = A + (size_t)(bm * 128 + r) * Kd + k0 + kk;
      float4 f0 = *(const float4*)src;
      float4 f1 = *(const float4*)(src + 4);
      if (COMP) {
        bf16x8v hv, lv;
        split8(f0, f1, hv, lv);
        *(bf16x8v*)(AsH + off) = hv;
        *(bf16x8v*)(AsL + off) = lv;
      } else {
        *(bf16x8v*)(AsH + off) = cvt8(f0, f1);
      }
      *(bf16x8v*)(BsH + off) =
          *(const bf16x8v*)(Bh + (size_t)(bn * 128 + r) * Kd + k0 + kk);
      if (COMP)
        *(bf16x8v*)(BsL + off) =
            *(const bf16x8v*)(Bl + (size_t)(bn * 128 + r) * Kd + k0 + kk);
    }
    __syncthreads();

    bf16x8v ah[4], al[4], bh4[4], bl4[4];
#pragma unroll
    for (int i = 0; i < 4; ++i) {
      int r = wm + (i << 4) + lr;
      int off = (r << 6) + ((kh << 4) ^ ((r & 3) << 4));
      ah[i] = *(const bf16x8v*)(AsH + off);
      if (COMP) al[i] = *(const bf16x8v*)(AsL + off);
    }
#pragma unroll
    for (int i = 0; i < 4; ++i) {
      int r = wn + (i << 4) + lr;
      int off = (r << 6) + ((kh << 4) ^ ((r & 3) << 4));
      bh4[i] = *(const bf16x8v*)(BsH + off);
      if (COMP) bl4[i] = *(const bf16x8v*)(BsL + off);
    }
#pragma unroll
    for (int mi = 0; mi < 4; ++mi)
#pragma unroll
      for (int ni = 0; ni < 4; ++ni) {
        if (COMP) {
          acc[mi][ni] = MFMA(al[mi], bh4[ni], acc[mi][ni]);
          acc[mi][ni] = MFMA(ah[mi], bl4[ni], acc[mi][ni]);
        }
        acc[mi][ni] = MFMA(ah[mi], bh4[ni], acc[mi][ni]);
      }
  }

  const int cr0 = kh << 2;
#pragma unroll
  for (int mi = 0; mi < 4; ++mi)
#pragma unroll
    for (int ni = 0; ni < 4; ++ni)
#pragma unroll
      for (int r = 0; r < 4; ++r) {
        int row = bm * 128 + wm + (mi << 4) + cr0 + r;
        int col = bn * 128 + wn + (ni << 4) + lr;
        size_t idx = (size_t)row * N + col;
        if (ACCUM) C[idx] += acc[mi][ni][r];
        else       C[idx] = acc[mi][ni][r];
      }
}

// ---------------------------------------------------------------------------
// Compensated flash attention (unchanged from round 5; verified)
// ---------------------------------------------------------------------------
__global__ __launch_bounds__(256) void attn_flash_kernel(
    const float* __restrict__ Q, const float* __restrict__ K,
    const float* __restrict__ V, float* __restrict__ O)
{
  const int qt = blockIdx.x;
  const int head = blockIdx.y;
  const int tid = threadIdx.x, wid = tid >> 6, lane = tid & 63;
  const int lr = lane & 15, kh = lane >> 4;
  __shared__ __align__(16) char KsH[8192], KsL[8192];
  __shared__ __align__(16) char VtH[8192], VtL[8192];
  __shared__ __align__(16) char PsH[4][2048], PsL[4][2048];

  const float* qrow = Q + (size_t)(qt * 64 + wid * 16 + lr) * HID + head * HDIM;
  bf16x8v qfh[2], qfl[2];
  {
    float4 a0 = *(const float4*)(qrow + (kh << 3));
    float4 b0 = *(const float4*)(qrow + (kh << 3) + 4);
    split8(a0, b0, qfh[0], qfl[0]);
    float4 a1 = *(const float4*)(qrow + 32 + (kh << 3));
    float4 b1 = *(const float4*)(qrow + 32 + (kh << 3) + 4);
    split8(a1, b1, qfh[1], qfl[1]);
  }

  float m_run[4], l_run[4];
  f32x4v oacc[4];
  const f32x4v z4 = {0.f, 0.f, 0.f, 0.f};
#pragma unroll
  for (int i = 0; i < 4; ++i) { m_run[i] = -1e30f; l_run[i] = 0.f; oacc[i] = z4; }

  for (int kt = 0; kt <= qt; ++kt) {
    __syncthreads();
#pragma unroll
    for (int p = 0; p < 2; ++p) {
      int g = tid + (p << 8);
      int r = g >> 3;
      int c8 = (g & 7) << 3;
      const size_t gofs = (size_t)(kt * 64 + r) * HID + head * HDIM + c8;
      float4 f0 = *(const float4*)(K + gofs);
      float4 f1 = *(const float4*)(K + gofs + 4);
      bf16x8v hv, lv; split8(f0, f1, hv, lv);
      int koff = (r << 7) + ((c8 << 1) ^ ((r & 7) << 4));
      *(bf16x8v*)(KsH + koff) = hv;
      *(bf16x8v*)(KsL + koff) = lv;
      float4 g0 = *(const float4*)(V + gofs);
      float4 g1 = *(const float4*)(V + gofs + 4);
      bf16x8v wh, wl; split8(g0, g1, wh, wl);
#pragma unroll
      for (int j = 0; j < 8; ++j) {
        int vr = c8 + j;
        int voff = (vr << 7) + ((r << 1) ^ ((vr & 7) << 4));
        *(__bf16*)(VtH + voff) = wh[j];
        *(__bf16*)(VtL + voff) = wl[j];
      }
    }
    __syncthreads();

    float sv[4][4];
#pragma unroll
    for (int stt = 0; stt < 4; ++stt) {
      int r = (stt << 4) + lr;
      int off0 = (r << 7) + ((kh << 4) ^ ((r & 7) << 4));
      int off1 = (r << 7) + ((64 + (kh << 4)) ^ ((r & 7) << 4));
      bf16x8v kfh0 = *(const bf16x8v*)(KsH + off0);
      bf16x8v kfl0 = *(const bf16x8v*)(KsL + off0);
      bf16x8v kfh1 = *(const bf16x8v*)(KsH + off1);
      bf16x8v kfl1 = *(const bf16x8v*)(KsL + off1);
      f32x4v s = z4;
      s = MFMA(qfl[0], kfh0, s);
      s = MFMA(qfh[0], kfl0, s);
      s = MFMA(qfh[0], kfh0, s);
      s = MFMA(qfl[1], kfh1, s);
      s = MFMA(qfh[1], kfl1, s);
      s = MFMA(qfh[1], kfh1, s);
      int key = kt * 64 + (stt << 4) + lr;
#pragma unroll
      for (int rr = 0; rr < 4; ++rr) {
        int qr = qt * 64 + wid * 16 + (kh << 2) + rr;
        sv[stt][rr] = (key <= qr) ? s[rr] : -1e30f;
      }
    }

#pragma unroll
    for (int rr = 0; rr < 4; ++rr) {
      float mx = fmaxf(fmaxf(sv[0][rr], sv[1][rr]), fmaxf(sv[2][rr], sv[3][rr]));
#pragma unroll
      for (int d = 1; d < 16; d <<= 1) mx = fmaxf(mx, __shfl_xor(mx, d));
      float mnew = fmaxf(m_run[rr], mx);
      float scl = __expf(m_run[rr] - mnew);
      float pv[4];
#pragma unroll
      for (int stt = 0; stt < 4; ++stt) pv[stt] = __expf(sv[stt][rr] - mnew);
      float rs = pv[0] + pv[1] + pv[2] + pv[3];
#pragma unroll
      for (int d = 1; d < 16; d <<= 1) rs += __shfl_xor(rs, d);
      l_run[rr] = l_run[rr] * scl + rs;
      m_run[rr] = mnew;
#pragma unroll
      for (int n = 0; n < 4; ++n) oacc[n][rr] *= scl;
      int qlr = (kh << 2) + rr;
#pragma unroll
      for (int stt = 0; stt < 4; ++stt) {
        __bf16 hb = (__bf16)pv[stt];
        __bf16 lb = (__bf16)(pv[stt] - (float)hb);
        int off = (qlr << 7) + ((((stt << 4) + lr) << 1) ^ ((qlr & 7) << 4));
        *(__bf16*)(PsH[wid] + off) = hb;
        *(__bf16*)(PsL[wid] + off) = lb;
      }
    }

    int poff0 = (lr << 7) + ((kh << 4) ^ ((lr & 7) << 4));
    int poff1 = (lr << 7) + ((64 + (kh << 4)) ^ ((lr & 7) << 4));
    bf16x8v pah0 = *(const bf16x8v*)(PsH[wid] + poff0);
    bf16x8v pal0 = *(const bf16x8v*)(PsL[wid] + poff0);
    bf16x8v pah1 = *(const bf16x8v*)(PsH[wid] + poff1);
    bf16x8v pal1 = *(const bf16x8v*)(PsL[wid] + poff1);
#pragma unroll
    for (int n = 0; n < 4; ++n) {
      int vr = (n << 4) + lr;
      int voff0 = (vr << 7) + ((kh << 4) ^ ((vr & 7) << 4));
      int voff1 = (vr << 7) + ((64 + (kh << 4)) ^ ((vr & 7) << 4));
      bf16x8v vfh0 = *(const bf16x8v*)(VtH + voff0);
      bf16x8v vfl0 = *(const bf16x8v*)(VtL + voff0);
      bf16x8v vfh1 = *(const bf16x8v*)(VtH + voff1);
      bf16x8v vfl1 = *(const bf16x8v*)(VtL + voff1);
      oacc[n] = MFMA(pal0, vfh0, oacc[n]);
      oacc[n] = MFMA(pah0, vfl0, oacc[n]);
      oacc[n] = MFMA(pah0, vfh0, oacc[n]);
      oacc[n] = MFMA(pal1, vfh1, oacc[n]);
      oacc[n] = MFMA(pah1, vfl1, oacc[n]);
      oacc[n] = MFMA(pah1, vfh1, oacc[n]);
    }
  }

#pragma unroll
  for (int n = 0; n < 4; ++n)
#pragma unroll
    for (int rr = 0; rr < 4; ++rr) {
      int qr = qt * 64 + wid * 16 + (kh << 2) + rr;
      O[(size_t)qr * HID + head * HDIM + (n << 4) + lr] = oacc[n][rr] / l_run[rr];
    }
}

// ---------------------------------------------------------------------------
// MoE gathered GEMMs (unchanged from round 5; f32 weights, plain bf16)
// ---------------------------------------------------------------------------
__global__ __launch_bounds__(256) void gemm_moe_gu_kernel(
    const float* __restrict__ X,
    const float* __restrict__ B0, const float* __restrict__ B1,
    float* __restrict__ C0, float* __restrict__ C1,
    const int* __restrict__ list, const int* __restrict__ cntp)
{
  const int cnt = cntp[0];
  const int bm = blockIdx.y, bn = blockIdx.x;
  if (bm * 128 >= cnt) return;
  const float* __restrict__ B = blockIdx.z ? B1 : B0;
  float* __restrict__ C       = blockIdx.z ? C1 : C0;
  __shared__ __align__(16) char AsB[8192];
  __shared__ __align__(16) char BsB[8192];
  const int tid = threadIdx.x;
  const int wid = tid >> 6, lane = tid & 63;
  const int wm = (wid >> 1) << 6, wn = (wid & 1) << 6;
  const int lr = lane & 15, kh = lane >> 4;

  f32x4v acc[4][4];
  const f32x4v z4 = {0.f, 0.f, 0.f, 0.f};
#pragma unroll
  for (int i = 0; i < 4; ++i)
#pragma unroll
    for (int j = 0; j < 4; ++j) acc[i][j] = z4;

  for (int k0 = 0; k0 < HID; k0 += 32) {
    __syncthreads();
#pragma unroll
    for (int p = 0; p < 2; ++p) {
      int g = tid + (p << 8);
      int r = g >> 2;
      int kk = (g & 3) << 3;
      int rg = bm * 128 + r;
      int tok = list[rg < cnt ? rg : cnt - 1];
      const float* src = X + (size_t)tok * HID + k0 + kk;
      float4 f0 = *(const float4*)src;
      float4 f1 = *(const float4*)(src + 4);
      *(bf16x8v*)(AsB + (r << 6) + ((kk << 1) ^ ((r & 3) << 4))) = cvt8(f0, f1);
    }
#pragma unroll
    for (int p = 0; p < 2; ++p) {
      int g = tid + (p << 8);
      int k = g >> 4;
      int n8 = (g & 15) << 3;
      const float* src = B + (size_t)(k0 + k) * IDIM + bn * 128 + n8;
      float4 f0 = *(const float4*)src;
      float4 f1 = *(const float4*)(src + 4);
      float fv[8] = {f0.x, f0.y, f0.z, f0.w, f1.x, f1.y, f1.z, f1.w};
#pragma unroll
      for (int i = 0; i < 8; ++i) {
        int r = n8 + i;
        *(__bf16*)(BsB + (r << 6) + (((k << 1)) ^ ((r & 3) << 4))) = (__bf16)fv[i];
      }
    }
    __syncthreads();

    bf16x8v af[4], bfv[4];
#pragma unroll
    for (int i = 0; i < 4; ++i) {
      int r = wm + (i << 4) + lr;
      af[i] = *(const bf16x8v*)(AsB + (r << 6) + ((kh << 4) ^ ((r & 3) << 4)));
    }
#pragma unroll
    for (int i = 0; i < 4; ++i) {
      int r = wn + (i << 4) + lr;
      bfv[i] = *(const bf16x8v*)(BsB + (r << 6) + ((kh << 4) ^ ((r & 3) << 4)));
    }
#pragma unroll
    for (int mi = 0; mi < 4; ++mi)
#pragma unroll
      for (int ni = 0; ni < 4; ++ni)
        acc[mi][ni] = MFMA(af[mi], bfv[ni], acc[mi][ni]);
  }

  const int cr0 = kh << 2;
#pragma unroll
  for (int mi = 0; mi < 4; ++mi)
#pragma unroll
    for (int ni = 0; ni < 4; ++ni)
#pragma unroll
      for (int r = 0; r < 4; ++r) {
        int row = bm * 128 + wm + (mi << 4) + cr0 + r;
        if (row < cnt) {
          int col = bn * 128 + wn + (ni << 4) + lr;
          C[(size_t)row * IDIM + col] = acc[mi][ni][r];
        }
      }
}

__global__ __launch_bounds__(256) void gemm_moe_down_kernel(
    const float* __restrict__ G, const float* __restrict__ MD,
    float* __restrict__ H,
    const int* __restrict__ list, const int* __restrict__ cntp)
{
  const int cnt = cntp[0];
  const int bm = blockIdx.y, bn = blockIdx.x;
  if (bm * 128 >= cnt) return;
  __shared__ __align__(16) char AsB[8192];
  __shared__ __align__(16) char BsB[8192];
  const int tid = threadIdx.x;
  const int wid = tid >> 6, lane = tid & 63;
  const int wm = (wid >> 1) << 6, wn = (wid & 1) << 6;
  const int lr = lane & 15, kh = lane >> 4;

  f32x4v acc[4][4];
  const f32x4v z4 = {0.f, 0.f, 0.f, 0.f};
#pragma unroll
  for (int i = 0; i < 4; ++i)
#pragma unroll
    for (int j = 0; j < 4; ++j) acc[i][j] = z4;

  for (int k0 = 0; k0 < IDIM; k0 += 32) {
    __syncthreads();
#pragma unroll
    for (int p = 0; p < 2; ++p) {
      int g = tid + (p << 8);
      int r = g >> 2;
      int kk = (g & 3) << 3;
      int rg = bm * 128 + r;
      const float* src = G + (size_t)(rg < cnt ? rg : cnt - 1) * IDIM + k0 + kk;
      float4 f0 = *(const float4*)src;
      float4 f1 = *(const float4*)(src + 4);
      *(bf16x8v*)(AsB + (r << 6) + ((kk << 1) ^ ((r & 3) << 4))) = cvt8(f0, f1);
    }
#pragma unroll
    for (int p = 0; p < 2; ++p) {
      int g = tid + (p << 8);
      int k = g >> 4;
      int n8 = (g & 15) << 3;
      const float* src = MD + (size_t)(k0 + k) * HID + bn * 128 + n8;
      float4 f0 = *(const float4*)src;
      float4 f1 = *(const float4*)(src + 4);
      float fv[8] = {f0.x, f0.y, f0.z, f0.w, f1.x, f1.y, f1.z, f1.w};
#pragma unroll
      for (int i = 0; i < 8; ++i) {
        int r = n8 + i;
        *(__bf16*)(BsB + (r << 6) + (((k << 1)) ^ ((r & 3) << 4))) = (__bf16)fv[i];
      }
    }
    __syncthreads();

    bf16x8v af[4], bfv[4];
#pragma unroll
    for (int i = 0; i < 4; ++i) {
      int r = wm + (i << 4) + lr;
      af[i] = *(const bf16x8v*)(AsB + (r << 6) + ((kh << 4) ^ ((r & 3) << 4)));
    }
#pragma unroll
    for (int i = 0; i < 4; ++i) {
      int r = wn + (i << 4) + lr;
      bfv[i] = *(const bf16x8v*)(BsB + (r << 6) + ((kh << 4) ^ ((r & 3) << 4)));
    }
#pragma unroll
    for (int mi = 0; mi < 4; ++mi)
#pragma unroll
      for (int ni = 0; ni < 4; ++ni)
        acc[mi][ni] = MFMA(af[mi], bfv[ni], acc[mi][ni]);
  }

  const int cr0 = kh << 2;
#pragma unroll
  for (int mi = 0; mi < 4; ++mi)
#pragma unroll
    for (int ni = 0; ni < 4; ++ni)
#pragma unroll
      for (int r = 0; r < 4; ++r) {
        int row = bm * 128 + wm + (mi << 4) + cr0 + r;
        if (row < cnt) {
          int col = bn * 128 + wn + (ni << 4) + lr;
          H[(size_t)list[row] * HID + col] += acc[mi][ni][r];
        }
      }
}

// ---------------------------------------------------------------------------
// Small kernels (unchanged)
// ---------------------------------------------------------------------------
__global__ void tables_kernel(float* __restrict__ CT, float* __restrict__ ST)
{
  int idx = blockIdx.x * 256 + threadIdx.x;
  int s = idx >> 5, i = idx & 31;
  double inv = exp(-log(10000.0) * (double)i / 32.0);
  double ang = (double)s * inv;
  CT[idx] = (float)cos(ang);
  ST[idx] = (float)sin(ang);
}

__global__ __launch_bounds__(256) void embed_kernel(
    const int* __restrict__ ids, const float* __restrict__ E, float* __restrict__ H)
{
  int t = blockIdx.x;
  int id = ids[t];
  ((float4*)(H + (size_t)t * HID))[threadIdx.x] =
      ((const float4*)(E + (size_t)id * HID))[threadIdx.x];
}

__global__ __launch_bounds__(256) void rmsnorm_kernel(
    const float* __restrict__ X, const float* __restrict__ W, float* __restrict__ O)
{
  int t = blockIdx.x;
  int tid = threadIdx.x;
  float4 v = ((const float4*)(X + (size_t)t * HID))[tid];
  float ss = v.x * v.x + v.y * v.y + v.z * v.z + v.w * v.w;
#pragma unroll
  for (int d = 1; d < 64; d <<= 1) ss += __shfl_xor(ss, d);
  __shared__ float red[4];
  if ((tid & 63) == 0) red[tid >> 6] = ss;
  __syncthreads();
  float tot = red[0] + red[1] + red[2] + red[3];
  float inv = 1.0f / sqrtf(tot * (1.0f / 1024.0f) + 1e-6f);
  float4 w = ((const float4*)W)[tid];
  float4 r;
  r.x = v.x * inv * w.x; r.y = v.y * inv * w.y;
  r.z = v.z * inv * w.z; r.w = v.w * inv * w.w;
  ((float4*)(O + (size_t)t * HID))[tid] = r;
}

__global__ __launch_bounds__(256) void rope_kernel(
    float* __restrict__ X,
    const float* __restrict__ CT, const float* __restrict__ ST, float scale)
{
  int idx = blockIdx.x * 256 + threadIdx.x;
  int s = idx >> 9;
  int rr = idx & 511;
  int hd = rr >> 5;
  int i = rr & 31;
  float c = CT[(s << 5) + i], sn = ST[(s << 5) + i];
  size_t base = (size_t)s * HID + hd * 64 + i;
  float x1 = X[base], x2 = X[base + 32];
  X[base]      = (x1 * c - x2 * sn) * scale;
  X[base + 32] = (x2 * c + x1 * sn) * scale;
}

__global__ __launch_bounds__(256) void silu_kernel(
    const float* __restrict__ G, const float* __restrict__ U, float* __restrict__ A)
{
  int t = blockIdx.y;
  int i = blockIdx.x * 256 + threadIdx.x;
  size_t idx = (size_t)t * IDIM + i;
  float gv = G[idx], uv = U[idx];
  A[idx] = gv / (1.f + __expf(-gv)) * uv;
}

__global__ __launch_bounds__(256) void silu_moe_kernel(
    const float* __restrict__ G, const float* __restrict__ U, float* __restrict__ A,
    const float* __restrict__ W, const int* __restrict__ list,
    const int* __restrict__ cntp, int e)
{
  int t = blockIdx.y;
  if (t >= cntp[0]) return;
  int i = blockIdx.x * 256 + threadIdx.x;
  size_t idx = (size_t)t * IDIM + i;
  float gv = G[idx], uv = U[idx];
  A[idx] = gv / (1.f + __expf(-gv)) * uv * W[list[t] * 8 + e];
}

__global__ __launch_bounds__(256) void router_kernel(
    const float* __restrict__ X, const float* __restrict__ RW, float* __restrict__ RL)
{
  int wid = threadIdx.x >> 6, lane = threadIdx.x & 63;
  int t = blockIdx.x * 4 + wid;
  const float* x = X + (size_t)t * HID;
  float a0 = 0, a1 = 0, a2 = 0, a3 = 0, a4 = 0, a5 = 0, a6 = 0, a7 = 0;
  for (int hh = lane; hh < HID; hh += 64) {
    float xv = x[hh];
    float4 f0 = *(const float4*)(RW + hh * 8);
    float4 f1 = *(const float4*)(RW + hh * 8 + 4);
    a0 += xv * f0.x; a1 += xv * f0.y; a2 += xv * f0.z; a3 += xv * f0.w;
    a4 += xv * f1.x; a5 += xv * f1.y; a6 += xv * f1.z; a7 += xv * f1.w;
  }
#pragma unroll
  for (int d = 1; d < 64; d <<= 1) {
    a0 += __shfl_xor(a0, d); a1 += __shfl_xor(a1, d);
    a2 += __shfl_xor(a2, d); a3 += __shfl_xor(a3, d);
    a4 += __shfl_xor(a4, d); a5 += __shfl_xor(a5, d);
    a6 += __shfl_xor(a6, d); a7 += __shfl_xor(a7, d);
  }
  if (lane == 0) {
    float* dst = RL + (size_t)t * 8;
    dst[0] = a0; dst[1] = a1; dst[2] = a2; dst[3] = a3;
    dst[4] = a4; dst[5] = a5; dst[6] = a6; dst[7] = a7;
  }
}

__global__ void zero_kernel(float* __restrict__ p, int n)
{
  int i = threadIdx.x;
  if (i < n) p[i] = 0.f;
}

__global__ void zeroi_kernel(int* __restrict__ p, int n)
{
  int i = threadIdx.x;
  if (i < n) p[i] = 0;
}

__global__ __launch_bounds__(256) void topk_kernel(
    const float* __restrict__ RL, float* __restrict__ W, float* __restrict__ AUX)
{
  int t = blockIdx.x * 256 + threadIdx.x;
  int lane = threadIdx.x & 63;
  float r[8];
#pragma unroll
  for (int e = 0; e < 8; ++e) r[e] = RL[t * 8 + e];
  float mx = r[0];
#pragma unroll
  for (int e = 1; e < 8; ++e) mx = fmaxf(mx, r[e]);
  float p[8];
  float se = 0.f;
#pragma unroll
  for (int e = 0; e < 8; ++e) { p[e] = __expf(r[e] - mx); se += p[e]; }
  float inv = 1.f / se;
#pragma unroll
  for (int e = 0; e < 8; ++e) p[e] *= inv;
  float lse = logf(se) + mx;
  int i1 = 0; float v1 = p[0];
#pragma unroll
  for (int e = 1; e < 8; ++e) if (p[e] > v1) { v1 = p[e]; i1 = e; }
  int i2 = -1; float v2 = -1.f;
#pragma unroll
  for (int e = 0; e < 8; ++e) if (e != i1 && p[e] > v2) { v2 = p[e]; i2 = e; }
  float s12 = v1 + v2;
#pragma unroll
  for (int e = 0; e < 8; ++e)
    W[t * 8 + e] = (e == i1) ? v1 / s12 : ((e == i2) ? v2 / s12 : 0.f);
#pragma unroll
  for (int e = 0; e < 8; ++e) {
    float fe = ((i1 == e) ? 1.f : 0.f) + ((i2 == e) ? 1.f : 0.f);
    float pe = p[e];
#pragma unroll
    for (int d = 1; d < 64; d <<= 1) { fe += __shfl_xor(fe, d); pe += __shfl_xor(pe, d); }
    if (lane == 0) { atomicAdd(&AUX[e], fe); atomicAdd(&AUX[8 + e], pe); }
  }
  float zz = lse * lse;
#pragma unroll
  for (int d = 1; d < 64; d <<= 1) zz += __shfl_xor(zz, d);
  if (lane == 0) atomicAdd(&AUX[16], zz);
}

__global__ void aux_kernel(const float* __restrict__ AUX, float* __restrict__ OUT)
{
  float s = 0.f;
#pragma unroll
  for (int e = 0; e < 8; ++e)
    s += (AUX[e] * (1.f / 2048.f)) * (AUX[8 + e] * (1.f / 2048.f));
  float auxv = 0.01f * 8.f * s;
  float z = 0.001f * (AUX[16] * (1.f / 2048.f));
  OUT[(size_t)SEQ * VOCAB] = auxv + z;
}

__global__ __launch_bounds__(256) void build_list_kernel(
    const float* __restrict__ W, int* __restrict__ cnt, int* __restrict__ list)
{
  int t = blockIdx.x * 256 + threadIdx.x;
#pragma unroll
  for (int e = 0; e < 8; ++e) {
    if (W[t * 8 + e] > 0.f) {
      int p = atomicAdd(&cnt[e], 1);
      list[e * SEQ + p] = t;
    }
  }
}

// ---------------------------------------------------------------------------
extern "C" void kernel_launch(void* const* d_in, const int* in_sizes, int n_in,
                              void* d_out, int out_size, void* d_ws, size_t ws_size,
                              hipStream_t stream)
{
  const int*   ids   = (const int*)d_in[0];
  const float* embed = (const float*)d_in[1];
  const float* ln1   = (const float*)d_in[2];
  const float* ln2   = (const float*)d_in[3];
  const float* wq    = (const float*)d_in[4];
  const float* wk    = (const float*)d_in[5];
  const float* wv    = (const float*)d_in[6];
  const float* wo    = (const float*)d_in[7];
  const float* dg    = (const float*)d_in[8];
  const float* du    = (const float*)d_in[9];
  const float* dd    = (const float*)d_in[10];
  const float* rw    = (const float*)d_in[11];
  const float* mg    = (const float*)d_in[12];
  const float* mu    = (const float*)d_in[13];
  const float* md    = (const float*)d_in[14];
  const float* fin   = (const float*)d_in[15];
  float* out = (float*)d_out;

  char* ws = (char*)d_ws;
  float* h    = (float*)(ws + 0);            // 2048x1024 f32
  float* hn   = (float*)(ws + 8388608);
  float* q    = (float*)(ws + 16777216);
  float* k    = (float*)(ws + 25165824);
  float* v    = (float*)(ws + 33554432);
  float* o    = (float*)(ws + 41943040);
  float* g    = (float*)(ws + 50331648);     // 2048x2816 f32
  float* u    = (float*)(ws + 73400320);
  float* ct   = (float*)(ws + 96468992);     // 2048x32
  float* st   = (float*)(ws + 96731136);
  float* rl   = (float*)(ws + 96993280);     // 2048x8
  float* wmoe = (float*)(ws + 97058816);
  float* aux  = (float*)(ws + 97124352);     // 17 f
  int*   cnt  = (int*)  (ws + 97124608);     // 8 i
  int*   list = (int*)  (ws + 97124864);     // 8x2048 i
  // pre-split/transposed weights (bf16): values identical to inline split8
  __bf16* wqh = (__bf16*)(ws + 97320960);    // [4][1024][1024] each, 8.39MB
  __bf16* wql = (__bf16*)(ws + 105709568);
  __bf16* wkh = (__bf16*)(ws + 114098176);
  __bf16* wkl = (__bf16*)(ws + 122486784);
  __bf16* wvh = (__bf16*)(ws + 130875392);
  __bf16* wvl = (__bf16*)(ws + 139264000);
  __bf16* woh = (__bf16*)(ws + 147652608);
  __bf16* wol = (__bf16*)(ws + 156041216);
  __bf16* dgh = (__bf16*)(ws + 164429824);   // [3][2816][1024] each, 17.3MB
  __bf16* dgl = (__bf16*)(ws + 181731328);
  __bf16* duh = (__bf16*)(ws + 199032832);
  __bf16* dul = (__bf16*)(ws + 216334336);
  __bf16* ddh = (__bf16*)(ws + 233635840);   // [3][1024][2816]
  __bf16* ddl = (__bf16*)(ws + 250937344);
  __bf16* eh  = (__bf16*)(ws + 268238848);   // [32000][1024] hi, 65.5MB
  // end: 333,774,848 bytes

  // ---- one-time weight preprocessing (deterministic, ~120us) ----
  wsplit_t_kernel<<<dim3(16, 16, 4), 256, 0, stream>>>(wq, wqh, wql, HID, HID);
  wsplit_t_kernel<<<dim3(16, 16, 4), 256, 0, stream>>>(wk, wkh, wkl, HID, HID);
  wsplit_t_kernel<<<dim3(16, 16, 4), 256, 0, stream>>>(wv, wvh, wvl, HID, HID);
  wsplit_t_kernel<<<dim3(16, 16, 4), 256, 0, stream>>>(wo, woh, wol, HID, HID);
  wsplit_t_kernel<<<dim3(44, 16, 3), 256, 0, stream>>>(dg, dgh, dgl, HID, IDIM);
  wsplit_t_kernel<<<dim3(44, 16, 3), 256, 0, stream>>>(du, duh, dul, HID, IDIM);
  wsplit_t_kernel<<<dim3(16, 44, 3), 256, 0, stream>>>(dd, ddh, ddl, IDIM, HID);
  esplit_kernel<<<16000, 256, 0, stream>>>(embed, eh);

  tables_kernel<<<256, 256, 0, stream>>>(ct, st);
  embed_kernel<<<SEQ, 256, 0, stream>>>(ids, embed, h);

  for (int li = 0; li < 4; ++li) {
    const bool comp = (li <= 2);   // selection-grade precision pre-router
    rmsnorm_kernel<<<SEQ, 256, 0, stream>>>(h, ln1 + li * HID, hn);
    size_t wofs = (size_t)li * HID * HID;   // elements
    if (comp)
      gemm_bt_kernel<true, false, false><<<dim3(8, 16, 3), 256, 0, stream>>>(
          hn, wqh + wofs, wql + wofs, wkh + wofs, wkl + wofs, wvh + wofs, wvl + wofs,
          q, k, v, SEQ, HID, HID);
    else
      gemm_bt_kernel<false, false, false><<<dim3(8, 16, 3), 256, 0, stream>>>(
          hn, wqh + wofs, wqh + wofs, wkh + wofs, wkh + wofs, wvh + wofs, wvh + wofs,
          q, k, v, SEQ, HID, HID);
    rope_kernel<<<4096, 256, 0, stream>>>(q, ct, st, 0.125f);
    rope_kernel<<<4096, 256, 0, stream>>>(k, ct, st, 1.0f);

    attn_flash_kernel<<<dim3(32, 16), 256, 0, stream>>>(q, k, v, o);

    if (comp)
      gemm_bt_kernel<true, true, false><<<dim3(8, 16, 1), 256, 0, stream>>>(
          o, woh + wofs, wol + wofs, woh + wofs, wol + wofs, woh + wofs, wol + wofs,
          h, h, h, SEQ, HID, HID);
    else
      gemm_bt_kernel<false, true, false><<<dim3(8, 16, 1), 256, 0, stream>>>(
          o, woh + wofs, woh + wofs, woh + wofs, woh + wofs, woh + wofs, woh + wofs,
          h, h, h, SEQ, HID, HID);

    rmsnorm_kernel<<<SEQ, 256, 0, stream>>>(h, ln2 + li * HID, hn);
    if (li == 2) {
      router_kernel<<<512, 256, 0, stream>>>(hn, rw, rl);
      zero_kernel<<<1, 32, 0, stream>>>(aux, 17);
      topk_kernel<<<8, 256, 0, stream>>>(rl, wmoe, aux);
      aux_kernel<<<1, 1, 0, stream>>>(aux, out);
      zeroi_kernel<<<1, 32, 0, stream>>>(cnt, 8);
      build_list_kernel<<<8, 256, 0, stream>>>(wmoe, cnt, list);
      for (int e = 0; e < 8; ++e) {
        size_t go = (size_t)e * HID * IDIM;
        gemm_moe_gu_kernel<<<dim3(22, 16, 2), 256, 0, stream>>>(
            hn, mg + go, mu + go, g, u, list + e * SEQ, cnt + e);
        silu_moe_kernel<<<dim3(11, SEQ), 256, 0, stream>>>(
            g, u, g, wmoe, list + e * SEQ, cnt + e, e);
        gemm_moe_down_kernel<<<dim3(8, 16), 256, 0, stream>>>(
            g, md + (size_t)e * IDIM * HID, h, list + e * SEQ, cnt + e);
      }
    } else {
      int d = (li < 2) ? li : li - 1;
      size_t go = (size_t)d * HID * IDIM;   // elements
      if (comp) {
        gemm_bt_kernel<true, false, false><<<dim3(22, 16, 2), 256, 0, stream>>>(
            hn, dgh + go, dgl + go, duh + go, dul + go, duh + go, dul + go,
            g, u, u, SEQ, IDIM, HID);
        silu_kernel<<<dim3(11, SEQ), 256, 0, stream>>>(g, u, g);
        gemm_bt_kernel<true, true, false><<<dim3(8, 16, 1), 256, 0, stream>>>(
            g, ddh + go, ddl + go, ddh + go, ddl + go, ddh + go, ddl + go,
            h, h, h, SEQ, HID, IDIM);
      } else {
        gemm_bt_kernel<false, false, false><<<dim3(22, 16, 2), 256, 0, stream>>>(
            hn, dgh + go, dgh + go, duh + go, duh + go, duh + go, duh + go,
            g, u, u, SEQ, IDIM, HID);
        silu_kernel<<<dim3(11, SEQ), 256, 0, stream>>>(g, u, g);
        gemm_bt_kernel<false, true, false><<<dim3(8, 16, 1), 256, 0, stream>>>(
            g, ddh + go, ddh + go, ddh + go, ddh + go, ddh + go, ddh + go,
            h, h, h, SEQ, HID, IDIM);
      }
    }
  }
  rmsnorm_kernel<<<SEQ, 256, 0, stream>>>(h, fin, hn);
  // logits: SWAP grid so 16 consecutive blocks share one embed panel
  gemm_bt_kernel<false, false, true><<<dim3(16, 250, 1), 256, 0, stream>>>(
      hn, eh, eh, eh, eh, eh, eh, out, out, out, SEQ, VOCAB, HID);
}

// Round 8
// 4428.305 us; speedup vs baseline: 6.2748x; 1.0577x over previous
//
#include <hip/hip_runtime.h>
#include <hip/hip_bf16.h>
#include <math.h>

#define SEQ 2048
#define HID 1024
#define NHEAD 16
#define HDIM 64
#define IDIM 2816
#define NEXP 8
#define VOCAB 32000

// LDS row stride for 32-k bf16 tiles: 64B data + 16B pad (bank-conflict-free)
#define LSTRIDE 80
// LDS row stride for 64-k bf16 tiles (attention): 128B data + 16B pad
#define ASTRIDE 144

typedef float f32x4v __attribute__((ext_vector_type(4)));
typedef __bf16 bf16x8v __attribute__((ext_vector_type(8)));

__device__ __forceinline__ bf16x8v cvt8(const float4& a, const float4& b) {
  bf16x8v r;
  r[0] = (__bf16)a.x; r[1] = (__bf16)a.y; r[2] = (__bf16)a.z; r[3] = (__bf16)a.w;
  r[4] = (__bf16)b.x; r[5] = (__bf16)b.y; r[6] = (__bf16)b.z; r[7] = (__bf16)b.w;
  return r;
}

__device__ __forceinline__ void split8(const float4& a, const float4& b,
                                       bf16x8v& h, bf16x8v& l) {
  float f[8] = {a.x, a.y, a.z, a.w, b.x, b.y, b.z, b.w};
#pragma unroll
  for (int i = 0; i < 8; ++i) {
    __bf16 hb = (__bf16)f[i];
    h[i] = hb;
    l[i] = (__bf16)(f[i] - (float)hb);
  }
}

#define MFMA(a, b, c) __builtin_amdgcn_mfma_f32_16x16x32_bf16(a, b, c, 0, 0, 0)

// ---------------------------------------------------------------------------
// Weight preprocessing: W[K,N] f32 -> WH,WL [N,K] bf16 (transposed hi/lo).
// ---------------------------------------------------------------------------
__global__ __launch_bounds__(256) void wsplit_t_kernel(
    const float* __restrict__ W, __bf16* __restrict__ WH, __bf16* __restrict__ WL,
    int K, int N)
{
  __shared__ float tile[64][65];
  const int tid = threadIdx.x;
  const size_t zofs = (size_t)blockIdx.z * K * N;
  const int n0 = blockIdx.x * 64, k0 = blockIdx.y * 64;
#pragma unroll
  for (int r = 0; r < 4; ++r) {
    int kk = (tid >> 4) + r * 16;
    int nn = (tid & 15) * 4;
    float4 v = *(const float4*)(W + zofs + (size_t)(k0 + kk) * N + n0 + nn);
    tile[kk][nn] = v.x; tile[kk][nn + 1] = v.y;
    tile[kk][nn + 2] = v.z; tile[kk][nn + 3] = v.w;
  }
  __syncthreads();
  const int nn = tid >> 2;
  const int kk = (tid & 3) * 16;
  __bf16* dh = WH + zofs + (size_t)(n0 + nn) * K + k0 + kk;
  __bf16* dl = WL + zofs + (size_t)(n0 + nn) * K + k0 + kk;
  bf16x8v h0, l0, h1, l1;
#pragma unroll
  for (int j = 0; j < 8; ++j) {
    float f = tile[kk + j][nn];
    __bf16 hb = (__bf16)f; h0[j] = hb; l0[j] = (__bf16)(f - (float)hb);
    f = tile[kk + 8 + j][nn];
    hb = (__bf16)f; h1[j] = hb; l1[j] = (__bf16)(f - (float)hb);
  }
  *(bf16x8v*)dh = h0; *(bf16x8v*)(dh + 8) = h1;
  *(bf16x8v*)dl = l0; *(bf16x8v*)(dl + 8) = l1;
}

__global__ __launch_bounds__(256) void esplit_kernel(
    const float* __restrict__ E, __bf16* __restrict__ EH)
{
  size_t i = ((size_t)blockIdx.x * 256 + threadIdx.x) * 8;
  float4 a = *(const float4*)(E + i);
  float4 b = *(const float4*)(E + i + 4);
  *(bf16x8v*)(EH + i) = cvt8(a, b);
}

// ---------------------------------------------------------------------------
// Unified BT GEMM: C[M,N] (+)= A[M,K] * B^T, B pre-split bf16 [N,K].
// Pad-80 LDS rows (no XOR). COMP: 3-pass hi/lo. SWAP: B-panel-major grid.
// ---------------------------------------------------------------------------
template<bool COMP, bool ACCUM, bool SWAP>
__global__ __launch_bounds__(256) void gemm_bt_kernel(
    const float* __restrict__ A,
    const __bf16* __restrict__ B0h, const __bf16* __restrict__ B0l,
    const __bf16* __restrict__ B1h, const __bf16* __restrict__ B1l,
    const __bf16* __restrict__ B2h, const __bf16* __restrict__ B2l,
    float* __restrict__ C0, float* __restrict__ C1, float* __restrict__ C2,
    int M, int N, int Kd)
{
  const __bf16* __restrict__ Bh = (blockIdx.z == 0) ? B0h : (blockIdx.z == 1 ? B1h : B2h);
  const __bf16* __restrict__ Bl = (blockIdx.z == 0) ? B0l : (blockIdx.z == 1 ? B1l : B2l);
  float* __restrict__ C         = (blockIdx.z == 0) ? C0 : (blockIdx.z == 1 ? C1 : C2);
  __shared__ __align__(16) char smem[COMP ? 4 * 128 * LSTRIDE : 2 * 128 * LSTRIDE];
  char* AsH = smem;
  char* BsH = smem + 128 * LSTRIDE;
  char* AsL = COMP ? smem + 2 * 128 * LSTRIDE : smem;
  char* BsL = COMP ? smem + 3 * 128 * LSTRIDE : smem + 128 * LSTRIDE;
  const int tid = threadIdx.x;
  const int bm = SWAP ? blockIdx.x : blockIdx.y;
  const int bn = SWAP ? blockIdx.y : blockIdx.x;
  const int wid = tid >> 6, lane = tid & 63;
  const int wm = (wid >> 1) << 6, wn = (wid & 1) << 6;
  const int lr = lane & 15, kh = lane >> 4;

  f32x4v acc[4][4];
  const f32x4v z4 = {0.f, 0.f, 0.f, 0.f};
#pragma unroll
  for (int i = 0; i < 4; ++i)
#pragma unroll
    for (int j = 0; j < 4; ++j) acc[i][j] = z4;

  for (int k0 = 0; k0 < Kd; k0 += 32) {
    __syncthreads();
#pragma unroll
    for (int p = 0; p < 2; ++p) {
      int g = tid + (p << 8);
      int r = g >> 2;
      int kk = (g & 3) << 3;
      int off = r * LSTRIDE + (kk << 1);
      const float* src = A + (size_t)(bm * 128 + r) * Kd + k0 + kk;
      float4 f0 = *(const float4*)src;
      float4 f1 = *(const float4*)(src + 4);
      if (COMP) {
        bf16x8v hv, lv;
        split8(f0, f1, hv, lv);
        *(bf16x8v*)(AsH + off) = hv;
        *(bf16x8v*)(AsL + off) = lv;
      } else {
        *(bf16x8v*)(AsH + off) = cvt8(f0, f1);
      }
      *(bf16x8v*)(BsH + off) =
          *(const bf16x8v*)(Bh + (size_t)(bn * 128 + r) * Kd + k0 + kk);
      if (COMP)
        *(bf16x8v*)(BsL + off) =
            *(const bf16x8v*)(Bl + (size_t)(bn * 128 + r) * Kd + k0 + kk);
    }
    __syncthreads();

    bf16x8v ah[4], al[4], bh4[4], bl4[4];
#pragma unroll
    for (int i = 0; i < 4; ++i) {
      int r = wm + (i << 4) + lr;
      int off = r * LSTRIDE + (kh << 4);
      ah[i] = *(const bf16x8v*)(AsH + off);
      if (COMP) al[i] = *(const bf16x8v*)(AsL + off);
    }
#pragma unroll
    for (int i = 0; i < 4; ++i) {
      int r = wn + (i << 4) + lr;
      int off = r * LSTRIDE + (kh << 4);
      bh4[i] = *(const bf16x8v*)(BsH + off);
      if (COMP) bl4[i] = *(const bf16x8v*)(BsL + off);
    }
#pragma unroll
    for (int mi = 0; mi < 4; ++mi)
#pragma unroll
      for (int ni = 0; ni < 4; ++ni) {
        if (COMP) {
          acc[mi][ni] = MFMA(al[mi], bh4[ni], acc[mi][ni]);
          acc[mi][ni] = MFMA(ah[mi], bl4[ni], acc[mi][ni]);
        }
        acc[mi][ni] = MFMA(ah[mi], bh4[ni], acc[mi][ni]);
      }
  }

  const int cr0 = kh << 2;
#pragma unroll
  for (int mi = 0; mi < 4; ++mi)
#pragma unroll
    for (int ni = 0; ni < 4; ++ni)
#pragma unroll
      for (int r = 0; r < 4; ++r) {
        int row = bm * 128 + wm + (mi << 4) + cr0 + r;
        int col = bn * 128 + wn + (ni << 4) + lr;
        size_t idx = (size_t)row * N + col;
        if (ACCUM) C[idx] += acc[mi][ni][r];
        else       C[idx] = acc[mi][ni][r];
      }
}

// ---------------------------------------------------------------------------
// rope + hi/lo split for Q (scale 1/8) and K: f32 in, bf16 hi/lo out.
// ---------------------------------------------------------------------------
__global__ __launch_bounds__(256) void rope_split_kernel(
    const float* __restrict__ Q, const float* __restrict__ K,
    __bf16* __restrict__ QH, __bf16* __restrict__ QL,
    __bf16* __restrict__ KH, __bf16* __restrict__ KL,
    const float* __restrict__ CT, const float* __restrict__ ST)
{
  int idx = blockIdx.x * 256 + threadIdx.x;   // < SEQ*NHEAD*32
  int s = idx >> 9;
  int rr = idx & 511;
  int hd = rr >> 5;
  int i = rr & 31;
  float c = CT[(s << 5) + i], sn = ST[(s << 5) + i];
  size_t base = (size_t)s * HID + hd * 64 + i;
  {
    float x1 = Q[base], x2 = Q[base + 32];
    float o1 = (x1 * c - x2 * sn) * 0.125f;
    float o2 = (x2 * c + x1 * sn) * 0.125f;
    __bf16 h1 = (__bf16)o1, h2 = (__bf16)o2;
    QH[base] = h1;      QL[base] = (__bf16)(o1 - (float)h1);
    QH[base + 32] = h2; QL[base + 32] = (__bf16)(o2 - (float)h2);
  }
  {
    float x1 = K[base], x2 = K[base + 32];
    float o1 = x1 * c - x2 * sn;
    float o2 = x2 * c + x1 * sn;
    __bf16 h1 = (__bf16)o1, h2 = (__bf16)o2;
    KH[base] = h1;      KL[base] = (__bf16)(o1 - (float)h1);
    KH[base + 32] = h2; KL[base + 32] = (__bf16)(o2 - (float)h2);
  }
}

// V f32 [S][HID] -> per-head transposed hi/lo bf16 [NHEAD][HDIM][SEQ]
// FIXED (r7 bug): each thread now covers TWO d-rows -> all 64 dims written.
__global__ __launch_bounds__(256) void vtsplit_kernel(
    const float* __restrict__ V, __bf16* __restrict__ VTH, __bf16* __restrict__ VTL)
{
  __shared__ float tile[64][65];
  const int tid = threadIdx.x;
  const int s0 = blockIdx.x * 64;
  const int head = blockIdx.y;
#pragma unroll
  for (int r = 0; r < 4; ++r) {
    int ss = (tid >> 4) + r * 16;
    int dd = (tid & 15) * 4;
    float4 v = *(const float4*)(V + (size_t)(s0 + ss) * HID + head * 64 + dd);
    tile[ss][dd] = v.x; tile[ss][dd + 1] = v.y;
    tile[ss][dd + 2] = v.z; tile[ss][dd + 3] = v.w;
  }
  __syncthreads();
#pragma unroll
  for (int half = 0; half < 2; ++half) {
    const int d = (tid >> 3) + (half << 5);
    const int c = tid & 7;
    bf16x8v hv, lv;
#pragma unroll
    for (int j = 0; j < 8; ++j) {
      float f = tile[c * 8 + j][d];
      __bf16 hb = (__bf16)f;
      hv[j] = hb; lv[j] = (__bf16)(f - (float)hb);
    }
    size_t dst = (size_t)(head * 64 + d) * SEQ + s0 + c * 8;
    *(bf16x8v*)(VTH + dst) = hv;
    *(bf16x8v*)(VTL + dst) = lv;
  }
}

// ---------------------------------------------------------------------------
// Compensated flash attention. Inputs pre-split bf16 (Q,K rope'd; V^T per head).
// Staging = pure 16B vector copies. Pad-144 LDS rows (conflict-free).
// ---------------------------------------------------------------------------
__global__ __launch_bounds__(256) void attn_flash_kernel(
    const __bf16* __restrict__ QH, const __bf16* __restrict__ QL,
    const __bf16* __restrict__ KH, const __bf16* __restrict__ KL,
    const __bf16* __restrict__ VTH, const __bf16* __restrict__ VTL,
    float* __restrict__ O)
{
  const int qt = blockIdx.x;
  const int head = blockIdx.y;
  const int tid = threadIdx.x, wid = tid >> 6, lane = tid & 63;
  const int lr = lane & 15, kh = lane >> 4;
  __shared__ __align__(16) char KsH[64 * ASTRIDE], KsL[64 * ASTRIDE];
  __shared__ __align__(16) char VtH[64 * ASTRIDE], VtL[64 * ASTRIDE];
  __shared__ __align__(16) char PsH[4][16 * ASTRIDE], PsL[4][16 * ASTRIDE];

  const size_t qofs = (size_t)(qt * 64 + wid * 16 + lr) * HID + head * HDIM;
  const bf16x8v qfh0 = *(const bf16x8v*)(QH + qofs + (kh << 3));
  const bf16x8v qfh1 = *(const bf16x8v*)(QH + qofs + 32 + (kh << 3));
  const bf16x8v qfl0 = *(const bf16x8v*)(QL + qofs + (kh << 3));
  const bf16x8v qfl1 = *(const bf16x8v*)(QL + qofs + 32 + (kh << 3));

  float m_run[4], l_run[4];
  f32x4v oacc[4];
  const f32x4v z4 = {0.f, 0.f, 0.f, 0.f};
#pragma unroll
  for (int i = 0; i < 4; ++i) { m_run[i] = -1e30f; l_run[i] = 0.f; oacc[i] = z4; }

  for (int kt = 0; kt <= qt; ++kt) {
    __syncthreads();
#pragma unroll
    for (int p = 0; p < 2; ++p) {
      int g = tid + (p << 8);
      int r = g >> 3;                 // row 0..63
      int c = g & 7;                  // 16B chunk
      int off = r * ASTRIDE + (c << 4);
      const size_t kofs = (size_t)(kt * 64 + r) * HID + head * HDIM + (c << 3);
      *(bf16x8v*)(KsH + off) = *(const bf16x8v*)(KH + kofs);
      *(bf16x8v*)(KsL + off) = *(const bf16x8v*)(KL + kofs);
      const size_t vofs = (size_t)(head * 64 + r) * SEQ + kt * 64 + (c << 3);
      *(bf16x8v*)(VtH + off) = *(const bf16x8v*)(VTH + vofs);
      *(bf16x8v*)(VtL + off) = *(const bf16x8v*)(VTL + vofs);
    }
    __syncthreads();

    float sv[4][4];
#pragma unroll
    for (int stt = 0; stt < 4; ++stt) {
      int r = (stt << 4) + lr;
      int off0 = r * ASTRIDE + (kh << 4);
      int off1 = off0 + 64;
      bf16x8v kfh0 = *(const bf16x8v*)(KsH + off0);
      bf16x8v kfl0 = *(const bf16x8v*)(KsL + off0);
      bf16x8v kfh1 = *(const bf16x8v*)(KsH + off1);
      bf16x8v kfl1 = *(const bf16x8v*)(KsL + off1);
      f32x4v s = z4;
      s = MFMA(qfl0, kfh0, s);
      s = MFMA(qfh0, kfl0, s);
      s = MFMA(qfh0, kfh0, s);
      s = MFMA(qfl1, kfh1, s);
      s = MFMA(qfh1, kfl1, s);
      s = MFMA(qfh1, kfh1, s);
      int key = kt * 64 + (stt << 4) + lr;
#pragma unroll
      for (int rr = 0; rr < 4; ++rr) {
        int qr = qt * 64 + wid * 16 + (kh << 2) + rr;
        sv[stt][rr] = (key <= qr) ? s[rr] : -1e30f;
      }
    }

#pragma unroll
    for (int rr = 0; rr < 4; ++rr) {
      float mx = fmaxf(fmaxf(sv[0][rr], sv[1][rr]), fmaxf(sv[2][rr], sv[3][rr]));
#pragma unroll
      for (int d = 1; d < 16; d <<= 1) mx = fmaxf(mx, __shfl_xor(mx, d));
      float mnew = fmaxf(m_run[rr], mx);
      float scl = __expf(m_run[rr] - mnew);
      float pv[4];
#pragma unroll
      for (int stt = 0; stt < 4; ++stt) pv[stt] = __expf(sv[stt][rr] - mnew);
      float rs = pv[0] + pv[1] + pv[2] + pv[3];
#pragma unroll
      for (int d = 1; d < 16; d <<= 1) rs += __shfl_xor(rs, d);
      l_run[rr] = l_run[rr] * scl + rs;
      m_run[rr] = mnew;
#pragma unroll
      for (int n = 0; n < 4; ++n) oacc[n][rr] *= scl;
      int qlr = (kh << 2) + rr;
#pragma unroll
      for (int stt = 0; stt < 4; ++stt) {
        __bf16 hb = (__bf16)pv[stt];
        __bf16 lb = (__bf16)(pv[stt] - (float)hb);
        int off = qlr * ASTRIDE + (((stt << 4) + lr) << 1);
        *(__bf16*)(PsH[wid] + off) = hb;
        *(__bf16*)(PsL[wid] + off) = lb;
      }
    }

    int poff0 = lr * ASTRIDE + (kh << 4);
    int poff1 = poff0 + 64;
    bf16x8v pah0 = *(const bf16x8v*)(PsH[wid] + poff0);
    bf16x8v pal0 = *(const bf16x8v*)(PsL[wid] + poff0);
    bf16x8v pah1 = *(const bf16x8v*)(PsH[wid] + poff1);
    bf16x8v pal1 = *(const bf16x8v*)(PsL[wid] + poff1);
#pragma unroll
    for (int n = 0; n < 4; ++n) {
      int vr = (n << 4) + lr;
      int voff0 = vr * ASTRIDE + (kh << 4);
      int voff1 = voff0 + 64;
      bf16x8v vfh0 = *(const bf16x8v*)(VtH + voff0);
      bf16x8v vfl0 = *(const bf16x8v*)(VtL + voff0);
      bf16x8v vfh1 = *(const bf16x8v*)(VtH + voff1);
      bf16x8v vfl1 = *(const bf16x8v*)(VtL + voff1);
      oacc[n] = MFMA(pal0, vfh0, oacc[n]);
      oacc[n] = MFMA(pah0, vfl0, oacc[n]);
      oacc[n] = MFMA(pah0, vfh0, oacc[n]);
      oacc[n] = MFMA(pal1, vfh1, oacc[n]);
      oacc[n] = MFMA(pah1, vfl1, oacc[n]);
      oacc[n] = MFMA(pah1, vfh1, oacc[n]);
    }
  }

#pragma unroll
  for (int n = 0; n < 4; ++n)
#pragma unroll
    for (int rr = 0; rr < 4; ++rr) {
      int qr = qt * 64 + wid * 16 + (kh << 2) + rr;
      O[(size_t)qr * HID + head * HDIM + (n << 4) + lr] = oacc[n][rr] / l_run[rr];
    }
}

// ---------------------------------------------------------------------------
// MoE gathered GEMMs (pad-80 LDS; f32 weights, plain bf16)
// ---------------------------------------------------------------------------
__global__ __launch_bounds__(256) void gemm_moe_gu_kernel(
    const float* __restrict__ X,
    const float* __restrict__ B0, const float* __restrict__ B1,
    float* __restrict__ C0, float* __restrict__ C1,
    const int* __restrict__ list, const int* __restrict__ cntp)
{
  const int cnt = cntp[0];
  const int bm = blockIdx.y, bn = blockIdx.x;
  if (bm * 128 >= cnt) return;
  const float* __restrict__ B = blockIdx.z ? B1 : B0;
  float* __restrict__ C       = blockIdx.z ? C1 : C0;
  __shared__ __align__(16) char AsB[128 * LSTRIDE];
  __shared__ __align__(16) char BsB[128 * LSTRIDE];
  const int tid = threadIdx.x;
  const int wid = tid >> 6, lane = tid & 63;
  const int wm = (wid >> 1) << 6, wn = (wid & 1) << 6;
  const int lr = lane & 15, kh = lane >> 4;

  f32x4v acc[4][4];
  const f32x4v z4 = {0.f, 0.f, 0.f, 0.f};
#pragma unroll
  for (int i = 0; i < 4; ++i)
#pragma unroll
    for (int j = 0; j < 4; ++j) acc[i][j] = z4;

  for (int k0 = 0; k0 < HID; k0 += 32) {
    __syncthreads();
#pragma unroll
    for (int p = 0; p < 2; ++p) {
      int g = tid + (p << 8);
      int r = g >> 2;
      int kk = (g & 3) << 3;
      int rg = bm * 128 + r;
      int tok = list[rg < cnt ? rg : cnt - 1];
      const float* src = X + (size_t)tok * HID + k0 + kk;
      float4 f0 = *(const float4*)src;
      float4 f1 = *(const float4*)(src + 4);
      *(bf16x8v*)(AsB + r * LSTRIDE + (kk << 1)) = cvt8(f0, f1);
    }
#pragma unroll
    for (int p = 0; p < 2; ++p) {
      int g = tid + (p << 8);
      int k = g >> 4;
      int n8 = (g & 15) << 3;
      const float* src = B + (size_t)(k0 + k) * IDIM + bn * 128 + n8;
      float4 f0 = *(const float4*)src;
      float4 f1 = *(const float4*)(src + 4);
      float fv[8] = {f0.x, f0.y, f0.z, f0.w, f1.x, f1.y, f1.z, f1.w};
#pragma unroll
      for (int i = 0; i < 8; ++i) {
        int r = n8 + i;
        *(__bf16*)(BsB + r * LSTRIDE + (k << 1)) = (__bf16)fv[i];
      }
    }
    __syncthreads();

    bf16x8v af[4], bfv[4];
#pragma unroll
    for (int i = 0; i < 4; ++i) {
      int r = wm + (i << 4) + lr;
      af[i] = *(const bf16x8v*)(AsB + r * LSTRIDE + (kh << 4));
    }
#pragma unroll
    for (int i = 0; i < 4; ++i) {
      int r = wn + (i << 4) + lr;
      bfv[i] = *(const bf16x8v*)(BsB + r * LSTRIDE + (kh << 4));
    }
#pragma unroll
    for (int mi = 0; mi < 4; ++mi)
#pragma unroll
      for (int ni = 0; ni < 4; ++ni)
        acc[mi][ni] = MFMA(af[mi], bfv[ni], acc[mi][ni]);
  }

  const int cr0 = kh << 2;
#pragma unroll
  for (int mi = 0; mi < 4; ++mi)
#pragma unroll
    for (int ni = 0; ni < 4; ++ni)
#pragma unroll
      for (int r = 0; r < 4; ++r) {
        int row = bm * 128 + wm + (mi << 4) + cr0 + r;
        if (row < cnt) {
          int col = bn * 128 + wn + (ni << 4) + lr;
          C[(size_t)row * IDIM + col] = acc[mi][ni][r];
        }
      }
}

__global__ __launch_bounds__(256) void gemm_moe_down_kernel(
    const float* __restrict__ G, const float* __restrict__ MD,
    float* __restrict__ H,
    const int* __restrict__ list, const int* __restrict__ cntp)
{
  const int cnt = cntp[0];
  const int bm = blockIdx.y, bn = blockIdx.x;
  if (bm * 128 >= cnt) return;
  __shared__ __align__(16) char AsB[128 * LSTRIDE];
  __shared__ __align__(16) char BsB[128 * LSTRIDE];
  const int tid = threadIdx.x;
  const int wid = tid >> 6, lane = tid & 63;
  const int wm = (wid >> 1) << 6, wn = (wid & 1) << 6;
  const int lr = lane & 15, kh = lane >> 4;

  f32x4v acc[4][4];
  const f32x4v z4 = {0.f, 0.f, 0.f, 0.f};
#pragma unroll
  for (int i = 0; i < 4; ++i)
#pragma unroll
    for (int j = 0; j < 4; ++j) acc[i][j] = z4;

  for (int k0 = 0; k0 < IDIM; k0 += 32) {
    __syncthreads();
#pragma unroll
    for (int p = 0; p < 2; ++p) {
      int g = tid + (p << 8);
      int r = g >> 2;
      int kk = (g & 3) << 3;
      int rg = bm * 128 + r;
      const float* src = G + (size_t)(rg < cnt ? rg : cnt - 1) * IDIM + k0 + kk;
      float4 f0 = *(const float4*)src;
      float4 f1 = *(const float4*)(src + 4);
      *(bf16x8v*)(AsB + r * LSTRIDE + (kk << 1)) = cvt8(f0, f1);
    }
#pragma unroll
    for (int p = 0; p < 2; ++p) {
      int g = tid + (p << 8);
      int k = g >> 4;
      int n8 = (g & 15) << 3;
      const float* src = MD + (size_t)(k0 + k) * HID + bn * 128 + n8;
      float4 f0 = *(const float4*)src;
      float4 f1 = *(const float4*)(src + 4);
      float fv[8] = {f0.x, f0.y, f0.z, f0.w, f1.x, f1.y, f1.z, f1.w};
#pragma unroll
      for (int i = 0; i < 8; ++i) {
        int r = n8 + i;
        *(__bf16*)(BsB + r * LSTRIDE + (k << 1)) = (__bf16)fv[i];
      }
    }
    __syncthreads();

    bf16x8v af[4], bfv[4];
#pragma unroll
    for (int i = 0; i < 4; ++i) {
      int r = wm + (i << 4) + lr;
      af[i] = *(const bf16x8v*)(AsB + r * LSTRIDE + (kh << 4));
    }
#pragma unroll
    for (int i = 0; i < 4; ++i) {
      int r = wn + (i << 4) + lr;
      bfv[i] = *(const bf16x8v*)(BsB + r * LSTRIDE + (kh << 4));
    }
#pragma unroll
    for (int mi = 0; mi < 4; ++mi)
#pragma unroll
      for (int ni = 0; ni < 4; ++ni)
        acc[mi][ni] = MFMA(af[mi], bfv[ni], acc[mi][ni]);
  }

  const int cr0 = kh << 2;
#pragma unroll
  for (int mi = 0; mi < 4; ++mi)
#pragma unroll
    for (int ni = 0; ni < 4; ++ni)
#pragma unroll
      for (int r = 0; r < 4; ++r) {
        int row = bm * 128 + wm + (mi << 4) + cr0 + r;
        if (row < cnt) {
          int col = bn * 128 + wn + (ni << 4) + lr;
          H[(size_t)list[row] * HID + col] += acc[mi][ni][r];
        }
      }
}

// ---------------------------------------------------------------------------
// Small kernels
// ---------------------------------------------------------------------------
__global__ void tables_kernel(float* __restrict__ CT, float* __restrict__ ST)
{
  int idx = blockIdx.x * 256 + threadIdx.x;
  int s = idx >> 5, i = idx & 31;
  double inv = exp(-log(10000.0) * (double)i / 32.0);
  double ang = (double)s * inv;
  CT[idx] = (float)cos(ang);
  ST[idx] = (float)sin(ang);
}

__global__ __launch_bounds__(256) void embed_kernel(
    const int* __restrict__ ids, const float* __restrict__ E, float* __restrict__ H)
{
  int t = blockIdx.x;
  int id = ids[t];
  ((float4*)(H + (size_t)t * HID))[threadIdx.x] =
      ((const float4*)(E + (size_t)id * HID))[threadIdx.x];
}

__global__ __launch_bounds__(256) void rmsnorm_kernel(
    const float* __restrict__ X, const float* __restrict__ W, float* __restrict__ O)
{
  int t = blockIdx.x;
  int tid = threadIdx.x;
  float4 v = ((const float4*)(X + (size_t)t * HID))[tid];
  float ss = v.x * v.x + v.y * v.y + v.z * v.z + v.w * v.w;
#pragma unroll
  for (int d = 1; d < 64; d <<= 1) ss += __shfl_xor(ss, d);
  __shared__ float red[4];
  if ((tid & 63) == 0) red[tid >> 6] = ss;
  __syncthreads();
  float tot = red[0] + red[1] + red[2] + red[3];
  float inv = 1.0f / sqrtf(tot * (1.0f / 1024.0f) + 1e-6f);
  float4 w = ((const float4*)W)[tid];
  float4 r;
  r.x = v.x * inv * w.x; r.y = v.y * inv * w.y;
  r.z = v.z * inv * w.z; r.w = v.w * inv * w.w;
  ((float4*)(O + (size_t)t * HID))[tid] = r;
}

__global__ __launch_bounds__(256) void silu_kernel(
    const float* __restrict__ G, const float* __restrict__ U, float* __restrict__ A)
{
  int t = blockIdx.y;
  int i = blockIdx.x * 256 + threadIdx.x;
  size_t idx = (size_t)t * IDIM + i;
  float gv = G[idx], uv = U[idx];
  A[idx] = gv / (1.f + __expf(-gv)) * uv;
}

__global__ __launch_bounds__(256) void silu_moe_kernel(
    const float* __restrict__ G, const float* __restrict__ U, float* __restrict__ A,
    const float* __restrict__ W, const int* __restrict__ list,
    const int* __restrict__ cntp, int e)
{
  int t = blockIdx.y;
  if (t >= cntp[0]) return;
  int i = blockIdx.x * 256 + threadIdx.x;
  size_t idx = (size_t)t * IDIM + i;
  float gv = G[idx], uv = U[idx];
  A[idx] = gv / (1.f + __expf(-gv)) * uv * W[list[t] * 8 + e];
}

__global__ __launch_bounds__(256) void router_kernel(
    const float* __restrict__ X, const float* __restrict__ RW, float* __restrict__ RL)
{
  int wid = threadIdx.x >> 6, lane = threadIdx.x & 63;
  int t = blockIdx.x * 4 + wid;
  const float* x = X + (size_t)t * HID;
  float a0 = 0, a1 = 0, a2 = 0, a3 = 0, a4 = 0, a5 = 0, a6 = 0, a7 = 0;
  for (int hh = lane; hh < HID; hh += 64) {
    float xv = x[hh];
    float4 f0 = *(const float4*)(RW + hh * 8);
    float4 f1 = *(const float4*)(RW + hh * 8 + 4);
    a0 += xv * f0.x; a1 += xv * f0.y; a2 += xv * f0.z; a3 += xv * f0.w;
    a4 += xv * f1.x; a5 += xv * f1.y; a6 += xv * f1.z; a7 += xv * f1.w;
  }
#pragma unroll
  for (int d = 1; d < 64; d <<= 1) {
    a0 += __shfl_xor(a0, d); a1 += __shfl_xor(a1, d);
    a2 += __shfl_xor(a2, d); a3 += __shfl_xor(a3, d);
    a4 += __shfl_xor(a4, d); a5 += __shfl_xor(a5, d);
    a6 += __shfl_xor(a6, d); a7 += __shfl_xor(a7, d);
  }
  if (lane == 0) {
    float* dst = RL + (size_t)t * 8;
    dst[0] = a0; dst[1] = a1; dst[2] = a2; dst[3] = a3;
    dst[4] = a4; dst[5] = a5; dst[6] = a6; dst[7] = a7;
  }
}

__global__ void zero_kernel(float* __restrict__ p, int n)
{
  int i = threadIdx.x;
  if (i < n) p[i] = 0.f;
}

__global__ void zeroi_kernel(int* __restrict__ p, int n)
{
  int i = threadIdx.x;
  if (i < n) p[i] = 0;
}

__global__ __launch_bounds__(256) void topk_kernel(
    const float* __restrict__ RL, float* __restrict__ W, float* __restrict__ AUX)
{
  int t = blockIdx.x * 256 + threadIdx.x;
  int lane = threadIdx.x & 63;
  float r[8];
#pragma unroll
  for (int e = 0; e < 8; ++e) r[e] = RL[t * 8 + e];
  float mx = r[0];
#pragma unroll
  for (int e = 1; e < 8; ++e) mx = fmaxf(mx, r[e]);
  float p[8];
  float se = 0.f;
#pragma unroll
  for (int e = 0; e < 8; ++e) { p[e] = __expf(r[e] - mx); se += p[e]; }
  float inv = 1.f / se;
#pragma unroll
  for (int e = 0; e < 8; ++e) p[e] *= inv;
  float lse = logf(se) + mx;
  int i1 = 0; float v1 = p[0];
#pragma unroll
  for (int e = 1; e < 8; ++e) if (p[e] > v1) { v1 = p[e]; i1 = e; }
  int i2 = -1; float v2 = -1.f;
#pragma unroll
  for (int e = 0; e < 8; ++e) if (e != i1 && p[e] > v2) { v2 = p[e]; i2 = e; }
  float s12 = v1 + v2;
#pragma unroll
  for (int e = 0; e < 8; ++e)
    W[t * 8 + e] = (e == i1) ? v1 / s12 : ((e == i2) ? v2 / s12 : 0.f);
#pragma unroll
  for (int e = 0; e < 8; ++e) {
    float fe = ((i1 == e) ? 1.f : 0.f) + ((i2 == e) ? 1.f : 0.f);
    float pe = p[e];
#pragma unroll
    for (int d = 1; d < 64; d <<= 1) { fe += __shfl_xor(fe, d); pe += __shfl_xor(pe, d); }
    if (lane == 0) { atomicAdd(&AUX[e], fe); atomicAdd(&AUX[8 + e], pe); }
  }
  float zz = lse * lse;
#pragma unroll
  for (int d = 1; d < 64; d <<= 1) zz += __shfl_xor(zz, d);
  if (lane == 0) atomicAdd(&AUX[16], zz);
}

__global__ void aux_kernel(const float* __restrict__ AUX, float* __restrict__ OUT)
{
  float s = 0.f;
#pragma unroll
  for (int e = 0; e < 8; ++e)
    s += (AUX[e] * (1.f / 2048.f)) * (AUX[8 + e] * (1.f / 2048.f));
  float auxv = 0.01f * 8.f * s;
  float z = 0.001f * (AUX[16] * (1.f / 2048.f));
  OUT[(size_t)SEQ * VOCAB] = auxv + z;
}

__global__ __launch_bounds__(256) void build_list_kernel(
    const float* __restrict__ W, int* __restrict__ cnt, int* __restrict__ list)
{
  int t = blockIdx.x * 256 + threadIdx.x;
#pragma unroll
  for (int e = 0; e < 8; ++e) {
    if (W[t * 8 + e] > 0.f) {
      int p = atomicAdd(&cnt[e], 1);
      list[e * SEQ + p] = t;
    }
  }
}

// ---------------------------------------------------------------------------
extern "C" void kernel_launch(void* const* d_in, const int* in_sizes, int n_in,
                              void* d_out, int out_size, void* d_ws, size_t ws_size,
                              hipStream_t stream)
{
  const int*   ids   = (const int*)d_in[0];
  const float* embed = (const float*)d_in[1];
  const float* ln1   = (const float*)d_in[2];
  const float* ln2   = (const float*)d_in[3];
  const float* wq    = (const float*)d_in[4];
  const float* wk    = (const float*)d_in[5];
  const float* wv    = (const float*)d_in[6];
  const float* wo    = (const float*)d_in[7];
  const float* dg    = (const float*)d_in[8];
  const float* du    = (const float*)d_in[9];
  const float* dd    = (const float*)d_in[10];
  const float* rw    = (const float*)d_in[11];
  const float* mg    = (const float*)d_in[12];
  const float* mu    = (const float*)d_in[13];
  const float* md    = (const float*)d_in[14];
  const float* fin   = (const float*)d_in[15];
  float* out = (float*)d_out;

  char* ws = (char*)d_ws;
  float* h    = (float*)(ws + 0);            // 2048x1024 f32
  float* hn   = (float*)(ws + 8388608);
  float* q    = (float*)(ws + 16777216);
  float* k    = (float*)(ws + 25165824);
  float* v    = (float*)(ws + 33554432);
  float* o    = (float*)(ws + 41943040);
  float* g    = (float*)(ws + 50331648);     // 2048x2816 f32 (MLP scratch)
  float* u    = (float*)(ws + 73400320);
  float* ct   = (float*)(ws + 96468992);     // 2048x32
  float* st   = (float*)(ws + 96731136);
  float* rl   = (float*)(ws + 96993280);     // 2048x8
  float* wmoe = (float*)(ws + 97058816);
  float* aux  = (float*)(ws + 97124352);     // 17 f
  int*   cnt  = (int*)  (ws + 97124608);     // 8 i
  int*   list = (int*)  (ws + 97124864);     // 8x2048 i
  // pre-split/transposed weights (bf16)
  __bf16* wqh = (__bf16*)(ws + 97320960);
  __bf16* wql = (__bf16*)(ws + 105709568);
  __bf16* wkh = (__bf16*)(ws + 114098176);
  __bf16* wkl = (__bf16*)(ws + 122486784);
  __bf16* wvh = (__bf16*)(ws + 130875392);
  __bf16* wvl = (__bf16*)(ws + 139264000);
  __bf16* woh = (__bf16*)(ws + 147652608);
  __bf16* wol = (__bf16*)(ws + 156041216);
  __bf16* dgh = (__bf16*)(ws + 164429824);
  __bf16* dgl = (__bf16*)(ws + 181731328);
  __bf16* duh = (__bf16*)(ws + 199032832);
  __bf16* dul = (__bf16*)(ws + 216334336);
  __bf16* ddh = (__bf16*)(ws + 233635840);
  __bf16* ddl = (__bf16*)(ws + 250937344);
  __bf16* eh  = (__bf16*)(ws + 268238848);   // [32000][1024] hi
  // end: 333,774,848 bytes
  // attention bf16 buffers aliased into g/u (dead during attention phase):
  __bf16* qh  = (__bf16*)g;                      // 4MB each
  __bf16* ql  = (__bf16*)((char*)g + 4194304);
  __bf16* kbh = (__bf16*)((char*)g + 8388608);
  __bf16* kbl = (__bf16*)((char*)g + 12582912);
  __bf16* vth = (__bf16*)u;
  __bf16* vtl = (__bf16*)((char*)u + 4194304);

  // ---- one-time weight preprocessing ----
  wsplit_t_kernel<<<dim3(16, 16, 4), 256, 0, stream>>>(wq, wqh, wql, HID, HID);
  wsplit_t_kernel<<<dim3(16, 16, 4), 256, 0, stream>>>(wk, wkh, wkl, HID, HID);
  wsplit_t_kernel<<<dim3(16, 16, 4), 256, 0, stream>>>(wv, wvh, wvl, HID, HID);
  wsplit_t_kernel<<<dim3(16, 16, 4), 256, 0, stream>>>(wo, woh, wol, HID, HID);
  wsplit_t_kernel<<<dim3(44, 16, 3), 256, 0, stream>>>(dg, dgh, dgl, HID, IDIM);
  wsplit_t_kernel<<<dim3(44, 16, 3), 256, 0, stream>>>(du, duh, dul, HID, IDIM);
  wsplit_t_kernel<<<dim3(16, 44, 3), 256, 0, stream>>>(dd, ddh, ddl, IDIM, HID);
  esplit_kernel<<<16000, 256, 0, stream>>>(embed, eh);

  tables_kernel<<<256, 256, 0, stream>>>(ct, st);
  embed_kernel<<<SEQ, 256, 0, stream>>>(ids, embed, h);

  for (int li = 0; li < 4; ++li) {
    const bool comp = (li <= 2);   // selection-grade precision pre-router
    rmsnorm_kernel<<<SEQ, 256, 0, stream>>>(h, ln1 + li * HID, hn);
    size_t wofs = (size_t)li * HID * HID;
    if (comp)
      gemm_bt_kernel<true, false, false><<<dim3(8, 16, 3), 256, 0, stream>>>(
          hn, wqh + wofs, wql + wofs, wkh + wofs, wkl + wofs, wvh + wofs, wvl + wofs,
          q, k, v, SEQ, HID, HID);
    else
      gemm_bt_kernel<false, false, false><<<dim3(8, 16, 3), 256, 0, stream>>>(
          hn, wqh + wofs, wqh + wofs, wkh + wofs, wkh + wofs, wvh + wofs, wvh + wofs,
          q, k, v, SEQ, HID, HID);

    rope_split_kernel<<<4096, 256, 0, stream>>>(q, k, qh, ql, kbh, kbl, ct, st);
    vtsplit_kernel<<<dim3(32, 16), 256, 0, stream>>>(v, vth, vtl);

    attn_flash_kernel<<<dim3(32, 16), 256, 0, stream>>>(
        qh, ql, kbh, kbl, vth, vtl, o);

    if (comp)
      gemm_bt_kernel<true, true, false><<<dim3(8, 16, 1), 256, 0, stream>>>(
          o, woh + wofs, wol + wofs, woh + wofs, wol + wofs, woh + wofs, wol + wofs,
          h, h, h, SEQ, HID, HID);
    else
      gemm_bt_kernel<false, true, false><<<dim3(8, 16, 1), 256, 0, stream>>>(
          o, woh + wofs, woh + wofs, woh + wofs, woh + wofs, woh + wofs, woh + wofs,
          h, h, h, SEQ, HID, HID);

    rmsnorm_kernel<<<SEQ, 256, 0, stream>>>(h, ln2 + li * HID, hn);
    if (li == 2) {
      router_kernel<<<512, 256, 0, stream>>>(hn, rw, rl);
      zero_kernel<<<1, 32, 0, stream>>>(aux, 17);
      topk_kernel<<<8, 256, 0, stream>>>(rl, wmoe, aux);
      aux_kernel<<<1, 1, 0, stream>>>(aux, out);
      zeroi_kernel<<<1, 32, 0, stream>>>(cnt, 8);
      build_list_kernel<<<8, 256, 0, stream>>>(wmoe, cnt, list);
      for (int e = 0; e < 8; ++e) {
        size_t go = (size_t)e * HID * IDIM;
        gemm_moe_gu_kernel<<<dim3(22, 16, 2), 256, 0, stream>>>(
            hn, mg + go, mu + go, g, u, list + e * SEQ, cnt + e);
        silu_moe_kernel<<<dim3(11, SEQ), 256, 0, stream>>>(
            g, u, g, wmoe, list + e * SEQ, cnt + e, e);
        gemm_moe_down_kernel<<<dim3(8, 16), 256, 0, stream>>>(
            g, md + (size_t)e * IDIM * HID, h, list + e * SEQ, cnt + e);
      }
    } else {
      int d = (li < 2) ? li : li - 1;
      size_t go = (size_t)d * HID * IDIM;
      if (comp) {
        gemm_bt_kernel<true, false, false><<<dim3(22, 16, 2), 256, 0, stream>>>(
            hn, dgh + go, dgl + go, duh + go, dul + go, duh + go, dul + go,
            g, u, u, SEQ, IDIM, HID);
        silu_kernel<<<dim3(11, SEQ), 256, 0, stream>>>(g, u, g);
        gemm_bt_kernel<true, true, false><<<dim3(8, 16, 1), 256, 0, stream>>>(
            g, ddh + go, ddl + go, ddh + go, ddl + go, ddh + go, ddl + go,
            h, h, h, SEQ, HID, IDIM);
      } else {
        gemm_bt_kernel<false, false, false><<<dim3(22, 16, 2), 256, 0, stream>>>(
            hn, dgh + go, dgh + go, duh + go, duh + go, duh + go, duh + go,
            g, u, u, SEQ, IDIM, HID);
        silu_kernel<<<dim3(11, SEQ), 256, 0, stream>>>(g, u, g);
        gemm_bt_kernel<false, true, false><<<dim3(8, 16, 1), 256, 0, stream>>>(
            g, ddh + go, ddh + go, ddh + go, ddh + go, ddh + go, ddh + go,
            h, h, h, SEQ, HID, IDIM);
      }
    }
  }
  rmsnorm_kernel<<<SEQ, 256, 0, stream>>>(h, fin, hn);
  gemm_bt_kernel<false, false, true><<<dim3(16, 250, 1), 256, 0, stream>>>(
      hn, eh, eh, eh, eh, eh, eh, out, out, out, SEQ, VOCAB, HID);
}

// Round 9
// 4084.845 us; speedup vs baseline: 6.8024x; 1.0841x over previous
//
#include <hip/hip_runtime.h>
#include <hip/hip_bf16.h>
#include <math.h>

#define SEQ 2048
#define HID 1024
#define NHEAD 16
#define HDIM 64
#define IDIM 2816
#define NEXP 8
#define VOCAB 32000

#define LSTRIDE 80   // 64B data + 16B pad per 32-k bf16 row
#define ASTRIDE 144  // 128B data + 16B pad per 64-k bf16 row (attention)

typedef float f32x4v __attribute__((ext_vector_type(4)));
typedef __bf16 bf16x8v __attribute__((ext_vector_type(8)));
typedef __bf16 bf16x4v __attribute__((ext_vector_type(4)));

__device__ __forceinline__ bf16x8v cvt8(const float4& a, const float4& b) {
  bf16x8v r;
  r[0] = (__bf16)a.x; r[1] = (__bf16)a.y; r[2] = (__bf16)a.z; r[3] = (__bf16)a.w;
  r[4] = (__bf16)b.x; r[5] = (__bf16)b.y; r[6] = (__bf16)b.z; r[7] = (__bf16)b.w;
  return r;
}

#define MFMA(a, b, c) __builtin_amdgcn_mfma_f32_16x16x32_bf16(a, b, c, 0, 0, 0)

// ---------------------------------------------------------------------------
// Weight preprocessing: W[K,N] f32 -> WH,WL [N,K] bf16 (transposed hi/lo).
// ---------------------------------------------------------------------------
__global__ __launch_bounds__(256) void wsplit_t_kernel(
    const float* __restrict__ W, __bf16* __restrict__ WH, __bf16* __restrict__ WL,
    int K, int N)
{
  __shared__ float tile[64][65];
  const int tid = threadIdx.x;
  const size_t zofs = (size_t)blockIdx.z * K * N;
  const int n0 = blockIdx.x * 64, k0 = blockIdx.y * 64;
#pragma unroll
  for (int r = 0; r < 4; ++r) {
    int kk = (tid >> 4) + r * 16;
    int nn = (tid & 15) * 4;
    float4 v = *(const float4*)(W + zofs + (size_t)(k0 + kk) * N + n0 + nn);
    tile[kk][nn] = v.x; tile[kk][nn + 1] = v.y;
    tile[kk][nn + 2] = v.z; tile[kk][nn + 3] = v.w;
  }
  __syncthreads();
  const int nn = tid >> 2;
  const int kk = (tid & 3) * 16;
  __bf16* dh = WH + zofs + (size_t)(n0 + nn) * K + k0 + kk;
  __bf16* dl = WL + zofs + (size_t)(n0 + nn) * K + k0 + kk;
  bf16x8v h0, l0, h1, l1;
#pragma unroll
  for (int j = 0; j < 8; ++j) {
    float f = tile[kk + j][nn];
    __bf16 hb = (__bf16)f; h0[j] = hb; l0[j] = (__bf16)(f - (float)hb);
    f = tile[kk + 8 + j][nn];
    hb = (__bf16)f; h1[j] = hb; l1[j] = (__bf16)(f - (float)hb);
  }
  *(bf16x8v*)dh = h0; *(bf16x8v*)(dh + 8) = h1;
  *(bf16x8v*)dl = l0; *(bf16x8v*)(dl + 8) = l1;
}

__global__ __launch_bounds__(256) void esplit_kernel(
    const float* __restrict__ E, __bf16* __restrict__ EH)
{
  size_t i = ((size_t)blockIdx.x * 256 + threadIdx.x) * 8;
  float4 a = *(const float4*)(E + i);
  float4 b = *(const float4*)(E + i + 4);
  *(bf16x8v*)(EH + i) = cvt8(a, b);
}

// ---------------------------------------------------------------------------
// Unified BT GEMM. A pre-split bf16 [M,K] (Ah,Al); B pre-split bf16 [N,K].
// Staging = pure 16B vector copies. BM = 128 or 64 (64 fills CUs for N=1024).
// ---------------------------------------------------------------------------
template<bool COMP, bool ACCUM, bool SWAP, int BM>
__global__ __launch_bounds__(256) void gemm_bt_kernel(
    const __bf16* __restrict__ Ah, const __bf16* __restrict__ Al,
    const __bf16* __restrict__ B0h, const __bf16* __restrict__ B0l,
    const __bf16* __restrict__ B1h, const __bf16* __restrict__ B1l,
    const __bf16* __restrict__ B2h, const __bf16* __restrict__ B2l,
    float* __restrict__ C0, float* __restrict__ C1, float* __restrict__ C2,
    int M, int N, int Kd)
{
  const __bf16* __restrict__ Bh = (blockIdx.z == 0) ? B0h : (blockIdx.z == 1 ? B1h : B2h);
  const __bf16* __restrict__ Bl = (blockIdx.z == 0) ? B0l : (blockIdx.z == 1 ? B1l : B2l);
  float* __restrict__ C         = (blockIdx.z == 0) ? C0 : (blockIdx.z == 1 ? C1 : C2);
  constexpr int ABYTES = BM * LSTRIDE;
  constexpr int BBYTES = 128 * LSTRIDE;
  constexpr int MFR = BM / 32;           // A fragments per wave (4 or 2)
  __shared__ __align__(16) char smem[COMP ? 2 * (ABYTES + BBYTES) : (ABYTES + BBYTES)];
  char* AsH = smem;
  char* BsH = smem + ABYTES;
  char* AsL = COMP ? smem + ABYTES + BBYTES : smem;
  char* BsL = COMP ? smem + 2 * ABYTES + BBYTES : smem + ABYTES;
  const int tid = threadIdx.x;
  const int bm = SWAP ? blockIdx.x : blockIdx.y;
  const int bn = SWAP ? blockIdx.y : blockIdx.x;
  const int wid = tid >> 6, lane = tid & 63;
  const int wm = (wid >> 1) * (BM / 2), wn = (wid & 1) << 6;
  const int lr = lane & 15, kh = lane >> 4;

  f32x4v acc[MFR][4];
  const f32x4v z4 = {0.f, 0.f, 0.f, 0.f};
#pragma unroll
  for (int i = 0; i < MFR; ++i)
#pragma unroll
    for (int j = 0; j < 4; ++j) acc[i][j] = z4;

  for (int k0 = 0; k0 < Kd; k0 += 32) {
    __syncthreads();
#pragma unroll
    for (int p = 0; p < BM / 64; ++p) {       // A: BM*4 16B chunks
      int g = tid + (p << 8);
      int r = g >> 2;
      int c = g & 3;
      int off = r * LSTRIDE + (c << 4);
      size_t src = (size_t)(bm * BM + r) * Kd + k0 + (c << 3);
      *(bf16x8v*)(AsH + off) = *(const bf16x8v*)(Ah + src);
      if (COMP) *(bf16x8v*)(AsL + off) = *(const bf16x8v*)(Al + src);
    }
#pragma unroll
    for (int p = 0; p < 2; ++p) {             // B: 512 16B chunks
      int g = tid + (p << 8);
      int r = g >> 2;
      int c = g & 3;
      int off = r * LSTRIDE + (c << 4);
      size_t src = (size_t)(bn * 128 + r) * Kd + k0 + (c << 3);
      *(bf16x8v*)(BsH + off) = *(const bf16x8v*)(Bh + src);
      if (COMP) *(bf16x8v*)(BsL + off) = *(const bf16x8v*)(Bl + src);
    }
    __syncthreads();

    bf16x8v ah[MFR], al[MFR], bh4[4], bl4[4];
#pragma unroll
    for (int i = 0; i < MFR; ++i) {
      int r = wm + (i << 4) + lr;
      int off = r * LSTRIDE + (kh << 4);
      ah[i] = *(const bf16x8v*)(AsH + off);
      if (COMP) al[i] = *(const bf16x8v*)(AsL + off);
    }
#pragma unroll
    for (int i = 0; i < 4; ++i) {
      int r = wn + (i << 4) + lr;
      int off = r * LSTRIDE + (kh << 4);
      bh4[i] = *(const bf16x8v*)(BsH + off);
      if (COMP) bl4[i] = *(const bf16x8v*)(BsL + off);
    }
#pragma unroll
    for (int mi = 0; mi < MFR; ++mi)
#pragma unroll
      for (int ni = 0; ni < 4; ++ni) {
        if (COMP) {
          acc[mi][ni] = MFMA(al[mi], bh4[ni], acc[mi][ni]);
          acc[mi][ni] = MFMA(ah[mi], bl4[ni], acc[mi][ni]);
        }
        acc[mi][ni] = MFMA(ah[mi], bh4[ni], acc[mi][ni]);
      }
  }

  const int cr0 = kh << 2;
#pragma unroll
  for (int mi = 0; mi < MFR; ++mi)
#pragma unroll
    for (int ni = 0; ni < 4; ++ni)
#pragma unroll
      for (int r = 0; r < 4; ++r) {
        int row = bm * BM + wm + (mi << 4) + cr0 + r;
        int col = bn * 128 + wn + (ni << 4) + lr;
        size_t idx = (size_t)row * N + col;
        if (ACCUM) C[idx] += acc[mi][ni][r];
        else       C[idx] = acc[mi][ni][r];
      }
}

// ---------------------------------------------------------------------------
// rope + hi/lo split for Q (scale 1/8) and K
// ---------------------------------------------------------------------------
__global__ __launch_bounds__(256) void rope_split_kernel(
    const float* __restrict__ Q, const float* __restrict__ K,
    __bf16* __restrict__ QH, __bf16* __restrict__ QL,
    __bf16* __restrict__ KH, __bf16* __restrict__ KL,
    const float* __restrict__ CT, const float* __restrict__ ST)
{
  int idx = blockIdx.x * 256 + threadIdx.x;
  int s = idx >> 9;
  int rr = idx & 511;
  int hd = rr >> 5;
  int i = rr & 31;
  float c = CT[(s << 5) + i], sn = ST[(s << 5) + i];
  size_t base = (size_t)s * HID + hd * 64 + i;
  {
    float x1 = Q[base], x2 = Q[base + 32];
    float o1 = (x1 * c - x2 * sn) * 0.125f;
    float o2 = (x2 * c + x1 * sn) * 0.125f;
    __bf16 h1 = (__bf16)o1, h2 = (__bf16)o2;
    QH[base] = h1;      QL[base] = (__bf16)(o1 - (float)h1);
    QH[base + 32] = h2; QL[base + 32] = (__bf16)(o2 - (float)h2);
  }
  {
    float x1 = K[base], x2 = K[base + 32];
    float o1 = x1 * c - x2 * sn;
    float o2 = x2 * c + x1 * sn;
    __bf16 h1 = (__bf16)o1, h2 = (__bf16)o2;
    KH[base] = h1;      KL[base] = (__bf16)(o1 - (float)h1);
    KH[base + 32] = h2; KL[base + 32] = (__bf16)(o2 - (float)h2);
  }
}

// V f32 [S][HID] -> per-head transposed hi/lo bf16 [NHEAD][HDIM][SEQ]
__global__ __launch_bounds__(256) void vtsplit_kernel(
    const float* __restrict__ V, __bf16* __restrict__ VTH, __bf16* __restrict__ VTL)
{
  __shared__ float tile[64][65];
  const int tid = threadIdx.x;
  const int s0 = blockIdx.x * 64;
  const int head = blockIdx.y;
#pragma unroll
  for (int r = 0; r < 4; ++r) {
    int ss = (tid >> 4) + r * 16;
    int dd = (tid & 15) * 4;
    float4 v = *(const float4*)(V + (size_t)(s0 + ss) * HID + head * 64 + dd);
    tile[ss][dd] = v.x; tile[ss][dd + 1] = v.y;
    tile[ss][dd + 2] = v.z; tile[ss][dd + 3] = v.w;
  }
  __syncthreads();
#pragma unroll
  for (int half = 0; half < 2; ++half) {
    const int d = (tid >> 3) + (half << 5);
    const int c = tid & 7;
    bf16x8v hv, lv;
#pragma unroll
    for (int j = 0; j < 8; ++j) {
      float f = tile[c * 8 + j][d];
      __bf16 hb = (__bf16)f;
      hv[j] = hb; lv[j] = (__bf16)(f - (float)hb);
    }
    size_t dst = (size_t)(head * 64 + d) * SEQ + s0 + c * 8;
    *(bf16x8v*)(VTH + dst) = hv;
    *(bf16x8v*)(VTL + dst) = lv;
  }
}

// ---------------------------------------------------------------------------
// Compensated flash attention; O written directly as bf16 hi/lo.
// ---------------------------------------------------------------------------
__global__ __launch_bounds__(256) void attn_flash_kernel(
    const __bf16* __restrict__ QH, const __bf16* __restrict__ QL,
    const __bf16* __restrict__ KH, const __bf16* __restrict__ KL,
    const __bf16* __restrict__ VTH, const __bf16* __restrict__ VTL,
    __bf16* __restrict__ OH, __bf16* __restrict__ OL)
{
  const int qt = blockIdx.x;
  const int head = blockIdx.y;
  const int tid = threadIdx.x, wid = tid >> 6, lane = tid & 63;
  const int lr = lane & 15, kh = lane >> 4;
  __shared__ __align__(16) char KsH[64 * ASTRIDE], KsL[64 * ASTRIDE];
  __shared__ __align__(16) char VtH[64 * ASTRIDE], VtL[64 * ASTRIDE];
  __shared__ __align__(16) char PsH[4][16 * ASTRIDE], PsL[4][16 * ASTRIDE];

  const size_t qofs = (size_t)(qt * 64 + wid * 16 + lr) * HID + head * HDIM;
  const bf16x8v qfh0 = *(const bf16x8v*)(QH + qofs + (kh << 3));
  const bf16x8v qfh1 = *(const bf16x8v*)(QH + qofs + 32 + (kh << 3));
  const bf16x8v qfl0 = *(const bf16x8v*)(QL + qofs + (kh << 3));
  const bf16x8v qfl1 = *(const bf16x8v*)(QL + qofs + 32 + (kh << 3));

  float m_run[4], l_run[4];
  f32x4v oacc[4];
  const f32x4v z4 = {0.f, 0.f, 0.f, 0.f};
#pragma unroll
  for (int i = 0; i < 4; ++i) { m_run[i] = -1e30f; l_run[i] = 0.f; oacc[i] = z4; }

  for (int kt = 0; kt <= qt; ++kt) {
    __syncthreads();
#pragma unroll
    for (int p = 0; p < 2; ++p) {
      int g = tid + (p << 8);
      int r = g >> 3;
      int c = g & 7;
      int off = r * ASTRIDE + (c << 4);
      const size_t kofs = (size_t)(kt * 64 + r) * HID + head * HDIM + (c << 3);
      *(bf16x8v*)(KsH + off) = *(const bf16x8v*)(KH + kofs);
      *(bf16x8v*)(KsL + off) = *(const bf16x8v*)(KL + kofs);
      const size_t vofs = (size_t)(head * 64 + r) * SEQ + kt * 64 + (c << 3);
      *(bf16x8v*)(VtH + off) = *(const bf16x8v*)(VTH + vofs);
      *(bf16x8v*)(VtL + off) = *(const bf16x8v*)(VTL + vofs);
    }
    __syncthreads();

    float sv[4][4];
#pragma unroll
    for (int stt = 0; stt < 4; ++stt) {
      int r = (stt << 4) + lr;
      int off0 = r * ASTRIDE + (kh << 4);
      int off1 = off0 + 64;
      bf16x8v kfh0 = *(const bf16x8v*)(KsH + off0);
      bf16x8v kfl0 = *(const bf16x8v*)(KsL + off0);
      bf16x8v kfh1 = *(const bf16x8v*)(KsH + off1);
      bf16x8v kfl1 = *(const bf16x8v*)(KsL + off1);
      f32x4v s = z4;
      s = MFMA(qfl0, kfh0, s);
      s = MFMA(qfh0, kfl0, s);
      s = MFMA(qfh0, kfh0, s);
      s = MFMA(qfl1, kfh1, s);
      s = MFMA(qfh1, kfl1, s);
      s = MFMA(qfh1, kfh1, s);
      int key = kt * 64 + (stt << 4) + lr;
#pragma unroll
      for (int rr = 0; rr < 4; ++rr) {
        int qr = qt * 64 + wid * 16 + (kh << 2) + rr;
        sv[stt][rr] = (key <= qr) ? s[rr] : -1e30f;
      }
    }

#pragma unroll
    for (int rr = 0; rr < 4; ++rr) {
      float mx = fmaxf(fmaxf(sv[0][rr], sv[1][rr]), fmaxf(sv[2][rr], sv[3][rr]));
#pragma unroll
      for (int d = 1; d < 16; d <<= 1) mx = fmaxf(mx, __shfl_xor(mx, d));
      float mnew = fmaxf(m_run[rr], mx);
      float scl = __expf(m_run[rr] - mnew);
      float pv[4];
#pragma unroll
      for (int stt = 0; stt < 4; ++stt) pv[stt] = __expf(sv[stt][rr] - mnew);
      float rs = pv[0] + pv[1] + pv[2] + pv[3];
#pragma unroll
      for (int d = 1; d < 16; d <<= 1) rs += __shfl_xor(rs, d);
      l_run[rr] = l_run[rr] * scl + rs;
      m_run[rr] = mnew;
#pragma unroll
      for (int n = 0; n < 4; ++n) oacc[n][rr] *= scl;
      int qlr = (kh << 2) + rr;
#pragma unroll
      for (int stt = 0; stt < 4; ++stt) {
        __bf16 hb = (__bf16)pv[stt];
        __bf16 lb = (__bf16)(pv[stt] - (float)hb);
        int off = qlr * ASTRIDE + (((stt << 4) + lr) << 1);
        *(__bf16*)(PsH[wid] + off) = hb;
        *(__bf16*)(PsL[wid] + off) = lb;
      }
    }

    int poff0 = lr * ASTRIDE + (kh << 4);
    int poff1 = poff0 + 64;
    bf16x8v pah0 = *(const bf16x8v*)(PsH[wid] + poff0);
    bf16x8v pal0 = *(const bf16x8v*)(PsL[wid] + poff0);
    bf16x8v pah1 = *(const bf16x8v*)(PsH[wid] + poff1);
    bf16x8v pal1 = *(const bf16x8v*)(PsL[wid] + poff1);
#pragma unroll
    for (int n = 0; n < 4; ++n) {
      int vr = (n << 4) + lr;
      int voff0 = vr * ASTRIDE + (kh << 4);
      int voff1 = voff0 + 64;
      bf16x8v vfh0 = *(const bf16x8v*)(VtH + voff0);
      bf16x8v vfl0 = *(const bf16x8v*)(VtL + voff0);
      bf16x8v vfh1 = *(const bf16x8v*)(VtH + voff1);
      bf16x8v vfl1 = *(const bf16x8v*)(VtL + voff1);
      oacc[n] = MFMA(pal0, vfh0, oacc[n]);
      oacc[n] = MFMA(pah0, vfl0, oacc[n]);
      oacc[n] = MFMA(pah0, vfh0, oacc[n]);
      oacc[n] = MFMA(pal1, vfh1, oacc[n]);
      oacc[n] = MFMA(pah1, vfl1, oacc[n]);
      oacc[n] = MFMA(pah1, vfh1, oacc[n]);
    }
  }

#pragma unroll
  for (int n = 0; n < 4; ++n)
#pragma unroll
    for (int rr = 0; rr < 4; ++rr) {
      int qr = qt * 64 + wid * 16 + (kh << 2) + rr;
      size_t ofs = (size_t)qr * HID + head * HDIM + (n << 4) + lr;
      float val = oacc[n][rr] / l_run[rr];
      __bf16 hb = (__bf16)val;
      OH[ofs] = hb;
      OL[ofs] = (__bf16)(val - (float)hb);
    }
}

// ---------------------------------------------------------------------------
// MoE gathered GEMMs (plain bf16). A-side now pre-split bf16 (pure copies).
// ---------------------------------------------------------------------------
__global__ __launch_bounds__(256) void gemm_moe_gu_kernel(
    const __bf16* __restrict__ Xh,
    const float* __restrict__ B0, const float* __restrict__ B1,
    float* __restrict__ C0, float* __restrict__ C1,
    const int* __restrict__ list, const int* __restrict__ cntp)
{
  const int cnt = cntp[0];
  const int bm = blockIdx.y, bn = blockIdx.x;
  if (bm * 128 >= cnt) return;
  const float* __restrict__ B = blockIdx.z ? B1 : B0;
  float* __restrict__ C       = blockIdx.z ? C1 : C0;
  __shared__ __align__(16) char AsB[128 * LSTRIDE];
  __shared__ __align__(16) char BsB[128 * LSTRIDE];
  const int tid = threadIdx.x;
  const int wid = tid >> 6, lane = tid & 63;
  const int wm = (wid >> 1) << 6, wn = (wid & 1) << 6;
  const int lr = lane & 15, kh = lane >> 4;

  f32x4v acc[4][4];
  const f32x4v z4 = {0.f, 0.f, 0.f, 0.f};
#pragma unroll
  for (int i = 0; i < 4; ++i)
#pragma unroll
    for (int j = 0; j < 4; ++j) acc[i][j] = z4;

  for (int k0 = 0; k0 < HID; k0 += 32) {
    __syncthreads();
#pragma unroll
    for (int p = 0; p < 2; ++p) {
      int g = tid + (p << 8);
      int r = g >> 2;
      int c = g & 3;
      int rg = bm * 128 + r;
      int tok = list[rg < cnt ? rg : cnt - 1];
      *(bf16x8v*)(AsB + r * LSTRIDE + (c << 4)) =
          *(const bf16x8v*)(Xh + (size_t)tok * HID + k0 + (c << 3));
    }
#pragma unroll
    for (int p = 0; p < 2; ++p) {
      int g = tid + (p << 8);
      int k = g >> 4;
      int n8 = (g & 15) << 3;
      const float* src = B + (size_t)(k0 + k) * IDIM + bn * 128 + n8;
      float4 f0 = *(const float4*)src;
      float4 f1 = *(const float4*)(src + 4);
      float fv[8] = {f0.x, f0.y, f0.z, f0.w, f1.x, f1.y, f1.z, f1.w};
#pragma unroll
      for (int i = 0; i < 8; ++i) {
        int r = n8 + i;
        *(__bf16*)(BsB + r * LSTRIDE + (k << 1)) = (__bf16)fv[i];
      }
    }
    __syncthreads();

    bf16x8v af[4], bfv[4];
#pragma unroll
    for (int i = 0; i < 4; ++i) {
      int r = wm + (i << 4) + lr;
      af[i] = *(const bf16x8v*)(AsB + r * LSTRIDE + (kh << 4));
    }
#pragma unroll
    for (int i = 0; i < 4; ++i) {
      int r = wn + (i << 4) + lr;
      bfv[i] = *(const bf16x8v*)(BsB + r * LSTRIDE + (kh << 4));
    }
#pragma unroll
    for (int mi = 0; mi < 4; ++mi)
#pragma unroll
      for (int ni = 0; ni < 4; ++ni)
        acc[mi][ni] = MFMA(af[mi], bfv[ni], acc[mi][ni]);
  }

  const int cr0 = kh << 2;
#pragma unroll
  for (int mi = 0; mi < 4; ++mi)
#pragma unroll
    for (int ni = 0; ni < 4; ++ni)
#pragma unroll
      for (int r = 0; r < 4; ++r) {
        int row = bm * 128 + wm + (mi << 4) + cr0 + r;
        if (row < cnt) {
          int col = bn * 128 + wn + (ni << 4) + lr;
          C[(size_t)row * IDIM + col] = acc[mi][ni][r];
        }
      }
}

__global__ __launch_bounds__(256) void gemm_moe_down_kernel(
    const __bf16* __restrict__ Gh, const float* __restrict__ MD,
    float* __restrict__ H,
    const int* __restrict__ list, const int* __restrict__ cntp)
{
  const int cnt = cntp[0];
  const int bm = blockIdx.y, bn = blockIdx.x;
  if (bm * 128 >= cnt) return;
  __shared__ __align__(16) char AsB[128 * LSTRIDE];
  __shared__ __align__(16) char BsB[128 * LSTRIDE];
  const int tid = threadIdx.x;
  const int wid = tid >> 6, lane = tid & 63;
  const int wm = (wid >> 1) << 6, wn = (wid & 1) << 6;
  const int lr = lane & 15, kh = lane >> 4;

  f32x4v acc[4][4];
  const f32x4v z4 = {0.f, 0.f, 0.f, 0.f};
#pragma unroll
  for (int i = 0; i < 4; ++i)
#pragma unroll
    for (int j = 0; j < 4; ++j) acc[i][j] = z4;

  for (int k0 = 0; k0 < IDIM; k0 += 32) {
    __syncthreads();
#pragma unroll
    for (int p = 0; p < 2; ++p) {
      int g = tid + (p << 8);
      int r = g >> 2;
      int c = g & 3;
      int rg = bm * 128 + r;
      *(bf16x8v*)(AsB + r * LSTRIDE + (c << 4)) =
          *(const bf16x8v*)(Gh + (size_t)(rg < cnt ? rg : cnt - 1) * IDIM + k0 + (c << 3));
    }
#pragma unroll
    for (int p = 0; p < 2; ++p) {
      int g = tid + (p << 8);
      int k = g >> 4;
      int n8 = (g & 15) << 3;
      const float* src = MD + (size_t)(k0 + k) * HID + bn * 128 + n8;
      float4 f0 = *(const float4*)src;
      float4 f1 = *(const float4*)(src + 4);
      float fv[8] = {f0.x, f0.y, f0.z, f0.w, f1.x, f1.y, f1.z, f1.w};
#pragma unroll
      for (int i = 0; i < 8; ++i) {
        int r = n8 + i;
        *(__bf16*)(BsB + r * LSTRIDE + (k << 1)) = (__bf16)fv[i];
      }
    }
    __syncthreads();

    bf16x8v af[4], bfv[4];
#pragma unroll
    for (int i = 0; i < 4; ++i) {
      int r = wm + (i << 4) + lr;
      af[i] = *(const bf16x8v*)(AsB + r * LSTRIDE + (kh << 4));
    }
#pragma unroll
    for (int i = 0; i < 4; ++i) {
      int r = wn + (i << 4) + lr;
      bfv[i] = *(const bf16x8v*)(BsB + r * LSTRIDE + (kh << 4));
    }
#pragma unroll
    for (int mi = 0; mi < 4; ++mi)
#pragma unroll
      for (int ni = 0; ni < 4; ++ni)
        acc[mi][ni] = MFMA(af[mi], bfv[ni], acc[mi][ni]);
  }

  const int cr0 = kh << 2;
#pragma unroll
  for (int mi = 0; mi < 4; ++mi)
#pragma unroll
    for (int ni = 0; ni < 4; ++ni)
#pragma unroll
      for (int r = 0; r < 4; ++r) {
        int row = bm * 128 + wm + (mi << 4) + cr0 + r;
        if (row < cnt) {
          int col = bn * 128 + wn + (ni << 4) + lr;
          H[(size_t)list[row] * HID + col] += acc[mi][ni][r];
        }
      }
}

// ---------------------------------------------------------------------------
// Small kernels
// ---------------------------------------------------------------------------
__global__ void tables_kernel(float* __restrict__ CT, float* __restrict__ ST)
{
  int idx = blockIdx.x * 256 + threadIdx.x;
  int s = idx >> 5, i = idx & 31;
  double inv = exp(-log(10000.0) * (double)i / 32.0);
  double ang = (double)s * inv;
  CT[idx] = (float)cos(ang);
  ST[idx] = (float)sin(ang);
}

__global__ __launch_bounds__(256) void embed_kernel(
    const int* __restrict__ ids, const float* __restrict__ E, float* __restrict__ H)
{
  int t = blockIdx.x;
  int id = ids[t];
  ((float4*)(H + (size_t)t * HID))[threadIdx.x] =
      ((const float4*)(E + (size_t)id * HID))[threadIdx.x];
}

// rmsnorm: writes f32 hn (router/gather) AND bf16 hi/lo (GEMM A operand)
__global__ __launch_bounds__(256) void rmsnorm_kernel(
    const float* __restrict__ X, const float* __restrict__ W,
    float* __restrict__ O, __bf16* __restrict__ OHb, __bf16* __restrict__ OLb)
{
  int t = blockIdx.x;
  int tid = threadIdx.x;
  float4 v = ((const float4*)(X + (size_t)t * HID))[tid];
  float ss = v.x * v.x + v.y * v.y + v.z * v.z + v.w * v.w;
#pragma unroll
  for (int d = 1; d < 64; d <<= 1) ss += __shfl_xor(ss, d);
  __shared__ float red[4];
  if ((tid & 63) == 0) red[tid >> 6] = ss;
  __syncthreads();
  float tot = red[0] + red[1] + red[2] + red[3];
  float inv = 1.0f / sqrtf(tot * (1.0f / 1024.0f) + 1e-6f);
  float4 w = ((const float4*)W)[tid];
  float4 r;
  r.x = v.x * inv * w.x; r.y = v.y * inv * w.y;
  r.z = v.z * inv * w.z; r.w = v.w * inv * w.w;
  ((float4*)(O + (size_t)t * HID))[tid] = r;
  float f[4] = {r.x, r.y, r.z, r.w};
  bf16x4v hv, lv;
#pragma unroll
  for (int j = 0; j < 4; ++j) {
    __bf16 hb = (__bf16)f[j];
    hv[j] = hb; lv[j] = (__bf16)(f[j] - (float)hb);
  }
  *(bf16x4v*)(OHb + (size_t)t * HID + tid * 4) = hv;
  *(bf16x4v*)(OLb + (size_t)t * HID + tid * 4) = lv;
}

// silu: writes bf16 hi/lo directly (down-GEMM A operand)
__global__ __launch_bounds__(256) void silu_kernel(
    const float* __restrict__ G, const float* __restrict__ U,
    __bf16* __restrict__ AH, __bf16* __restrict__ AL)
{
  int t = blockIdx.y;
  int i = blockIdx.x * 256 + threadIdx.x;
  size_t idx = (size_t)t * IDIM + i;
  float gv = G[idx], uv = U[idx];
  float a = gv / (1.f + __expf(-gv)) * uv;
  __bf16 hb = (__bf16)a;
  AH[idx] = hb;
  AL[idx] = (__bf16)(a - (float)hb);
}

// compacted silu with router weight folded; bf16 hi only (plain MoE path)
__global__ __launch_bounds__(256) void silu_moe_kernel(
    const float* __restrict__ G, const float* __restrict__ U, __bf16* __restrict__ AH,
    const float* __restrict__ W, const int* __restrict__ list,
    const int* __restrict__ cntp, int e)
{
  int t = blockIdx.y;
  if (t >= cntp[0]) return;
  int i = blockIdx.x * 256 + threadIdx.x;
  size_t idx = (size_t)t * IDIM + i;
  float gv = G[idx], uv = U[idx];
  AH[idx] = (__bf16)(gv / (1.f + __expf(-gv)) * uv * W[list[t] * 8 + e]);
}

__global__ __launch_bounds__(256) void router_kernel(
    const float* __restrict__ X, const float* __restrict__ RW, float* __restrict__ RL)
{
  int wid = threadIdx.x >> 6, lane = threadIdx.x & 63;
  int t = blockIdx.x * 4 + wid;
  const float* x = X + (size_t)t * HID;
  float a0 = 0, a1 = 0, a2 = 0, a3 = 0, a4 = 0, a5 = 0, a6 = 0, a7 = 0;
  for (int hh = lane; hh < HID; hh += 64) {
    float xv = x[hh];
    float4 f0 = *(const float4*)(RW + hh * 8);
    float4 f1 = *(const float4*)(RW + hh * 8 + 4);
    a0 += xv * f0.x; a1 += xv * f0.y; a2 += xv * f0.z; a3 += xv * f0.w;
    a4 += xv * f1.x; a5 += xv * f1.y; a6 += xv * f1.z; a7 += xv * f1.w;
  }
#pragma unroll
  for (int d = 1; d < 64; d <<= 1) {
    a0 += __shfl_xor(a0, d); a1 += __shfl_xor(a1, d);
    a2 += __shfl_xor(a2, d); a3 += __shfl_xor(a3, d);
    a4 += __shfl_xor(a4, d); a5 += __shfl_xor(a5, d);
    a6 += __shfl_xor(a6, d); a7 += __shfl_xor(a7, d);
  }
  if (lane == 0) {
    float* dst = RL + (size_t)t * 8;
    dst[0] = a0; dst[1] = a1; dst[2] = a2; dst[3] = a3;
    dst[4] = a4; dst[5] = a5; dst[6] = a6; dst[7] = a7;
  }
}

__global__ void zero_kernel(float* __restrict__ p, int n)
{
  int i = threadIdx.x;
  if (i < n) p[i] = 0.f;
}

__global__ void zeroi_kernel(int* __restrict__ p, int n)
{
  int i = threadIdx.x;
  if (i < n) p[i] = 0;
}

__global__ __launch_bounds__(256) void topk_kernel(
    const float* __restrict__ RL, float* __restrict__ W, float* __restrict__ AUX)
{
  int t = blockIdx.x * 256 + threadIdx.x;
  int lane = threadIdx.x & 63;
  float r[8];
#pragma unroll
  for (int e = 0; e < 8; ++e) r[e] = RL[t * 8 + e];
  float mx = r[0];
#pragma unroll
  for (int e = 1; e < 8; ++e) mx = fmaxf(mx, r[e]);
  float p[8];
  float se = 0.f;
#pragma unroll
  for (int e = 0; e < 8; ++e) { p[e] = __expf(r[e] - mx); se += p[e]; }
  float inv = 1.f / se;
#pragma unroll
  for (int e = 0; e < 8; ++e) p[e] *= inv;
  float lse = logf(se) + mx;
  int i1 = 0; float v1 = p[0];
#pragma unroll
  for (int e = 1; e < 8; ++e) if (p[e] > v1) { v1 = p[e]; i1 = e; }
  int i2 = -1; float v2 = -1.f;
#pragma unroll
  for (int e = 0; e < 8; ++e) if (e != i1 && p[e] > v2) { v2 = p[e]; i2 = e; }
  float s12 = v1 + v2;
#pragma unroll
  for (int e = 0; e < 8; ++e)
    W[t * 8 + e] = (e == i1) ? v1 / s12 : ((e == i2) ? v2 / s12 : 0.f);
#pragma unroll
  for (int e = 0; e < 8; ++e) {
    float fe = ((i1 == e) ? 1.f : 0.f) + ((i2 == e) ? 1.f : 0.f);
    float pe = p[e];
#pragma unroll
    for (int d = 1; d < 64; d <<= 1) { fe += __shfl_xor(fe, d); pe += __shfl_xor(pe, d); }
    if (lane == 0) { atomicAdd(&AUX[e], fe); atomicAdd(&AUX[8 + e], pe); }
  }
  float zz = lse * lse;
#pragma unroll
  for (int d = 1; d < 64; d <<= 1) zz += __shfl_xor(zz, d);
  if (lane == 0) atomicAdd(&AUX[16], zz);
}

__global__ void aux_kernel(const float* __restrict__ AUX, float* __restrict__ OUT)
{
  float s = 0.f;
#pragma unroll
  for (int e = 0; e < 8; ++e)
    s += (AUX[e] * (1.f / 2048.f)) * (AUX[8 + e] * (1.f / 2048.f));
  float auxv = 0.01f * 8.f * s;
  float z = 0.001f * (AUX[16] * (1.f / 2048.f));
  OUT[(size_t)SEQ * VOCAB] = auxv + z;
}

__global__ __launch_bounds__(256) void build_list_kernel(
    const float* __restrict__ W, int* __restrict__ cnt, int* __restrict__ list)
{
  int t = blockIdx.x * 256 + threadIdx.x;
#pragma unroll
  for (int e = 0; e < 8; ++e) {
    if (W[t * 8 + e] > 0.f) {
      int p = atomicAdd(&cnt[e], 1);
      list[e * SEQ + p] = t;
    }
  }
}

// ---------------------------------------------------------------------------
extern "C" void kernel_launch(void* const* d_in, const int* in_sizes, int n_in,
                              void* d_out, int out_size, void* d_ws, size_t ws_size,
                              hipStream_t stream)
{
  const int*   ids   = (const int*)d_in[0];
  const float* embed = (const float*)d_in[1];
  const float* ln1   = (const float*)d_in[2];
  const float* ln2   = (const float*)d_in[3];
  const float* wq    = (const float*)d_in[4];
  const float* wk    = (const float*)d_in[5];
  const float* wv    = (const float*)d_in[6];
  const float* wo    = (const float*)d_in[7];
  const float* dg    = (const float*)d_in[8];
  const float* du    = (const float*)d_in[9];
  const float* dd    = (const float*)d_in[10];
  const float* rw    = (const float*)d_in[11];
  const float* mg    = (const float*)d_in[12];
  const float* mu    = (const float*)d_in[13];
  const float* md    = (const float*)d_in[14];
  const float* fin   = (const float*)d_in[15];
  float* out = (float*)d_out;

  char* ws = (char*)d_ws;
  float* h    = (float*)(ws + 0);
  float* hn   = (float*)(ws + 8388608);
  float* q    = (float*)(ws + 16777216);
  float* k    = (float*)(ws + 25165824);
  float* v    = (float*)(ws + 33554432);
  __bf16* oh  = (__bf16*)(ws + 41943040);    // attn O hi (4MB)
  __bf16* ol  = (__bf16*)(ws + 46137344);    // attn O lo (4MB)
  float* g    = (float*)(ws + 50331648);     // 23MB MLP scratch (aliased in attn)
  float* u    = (float*)(ws + 73400320);
  float* ct   = (float*)(ws + 96468992);
  float* st   = (float*)(ws + 96731136);
  float* rl   = (float*)(ws + 96993280);
  float* wmoe = (float*)(ws + 97058816);
  float* aux  = (float*)(ws + 97124352);
  int*   cnt  = (int*)  (ws + 97124608);
  int*   list = (int*)  (ws + 97124864);
  __bf16* wqh = (__bf16*)(ws + 97320960);
  __bf16* wql = (__bf16*)(ws + 105709568);
  __bf16* wkh = (__bf16*)(ws + 114098176);
  __bf16* wkl = (__bf16*)(ws + 122486784);
  __bf16* wvh = (__bf16*)(ws + 130875392);
  __bf16* wvl = (__bf16*)(ws + 139264000);
  __bf16* woh = (__bf16*)(ws + 147652608);
  __bf16* wol = (__bf16*)(ws + 156041216);
  __bf16* dgh = (__bf16*)(ws + 164429824);
  __bf16* dgl = (__bf16*)(ws + 181731328);
  __bf16* duh = (__bf16*)(ws + 199032832);
  __bf16* dul = (__bf16*)(ws + 216334336);
  __bf16* ddh = (__bf16*)(ws + 233635840);
  __bf16* ddl = (__bf16*)(ws + 250937344);
  __bf16* eh  = (__bf16*)(ws + 268238848);
  __bf16* hnh = (__bf16*)(ws + 333774848);   // rmsnorm out hi (4MB)
  __bf16* hnl = (__bf16*)(ws + 337969152);   // rmsnorm out lo (4MB)
  __bf16* gh  = (__bf16*)(ws + 342163456);   // silu out hi (11.5MB; MoE compact reuse)
  __bf16* gl  = (__bf16*)(ws + 353697792);   // silu out lo -> end 365,232,128
  // attention bf16 buffers aliased into g/u (dead during attention phase)
  __bf16* qh  = (__bf16*)g;
  __bf16* ql  = (__bf16*)((char*)g + 4194304);
  __bf16* kbh = (__bf16*)((char*)g + 8388608);
  __bf16* kbl = (__bf16*)((char*)g + 12582912);
  __bf16* vth = (__bf16*)u;
  __bf16* vtl = (__bf16*)((char*)u + 4194304);

  // ---- one-time weight preprocessing ----
  wsplit_t_kernel<<<dim3(16, 16, 4), 256, 0, stream>>>(wq, wqh, wql, HID, HID);
  wsplit_t_kernel<<<dim3(16, 16, 4), 256, 0, stream>>>(wk, wkh, wkl, HID, HID);
  wsplit_t_kernel<<<dim3(16, 16, 4), 256, 0, stream>>>(wv, wvh, wvl, HID, HID);
  wsplit_t_kernel<<<dim3(16, 16, 4), 256, 0, stream>>>(wo, woh, wol, HID, HID);
  wsplit_t_kernel<<<dim3(44, 16, 3), 256, 0, stream>>>(dg, dgh, dgl, HID, IDIM);
  wsplit_t_kernel<<<dim3(44, 16, 3), 256, 0, stream>>>(du, duh, dul, HID, IDIM);
  wsplit_t_kernel<<<dim3(16, 44, 3), 256, 0, stream>>>(dd, ddh, ddl, IDIM, HID);
  esplit_kernel<<<16000, 256, 0, stream>>>(embed, eh);

  tables_kernel<<<256, 256, 0, stream>>>(ct, st);
  embed_kernel<<<SEQ, 256, 0, stream>>>(ids, embed, h);

  for (int li = 0; li < 4; ++li) {
    const bool comp = (li <= 2);
    rmsnorm_kernel<<<SEQ, 256, 0, stream>>>(h, ln1 + li * HID, hn, hnh, hnl);
    size_t wofs = (size_t)li * HID * HID;
    if (comp)
      gemm_bt_kernel<true, false, false, 64><<<dim3(8, 32, 3), 256, 0, stream>>>(
          hnh, hnl, wqh + wofs, wql + wofs, wkh + wofs, wkl + wofs,
          wvh + wofs, wvl + wofs, q, k, v, SEQ, HID, HID);
    else
      gemm_bt_kernel<false, false, false, 64><<<dim3(8, 32, 3), 256, 0, stream>>>(
          hnh, hnh, wqh + wofs, wqh + wofs, wkh + wofs, wkh + wofs,
          wvh + wofs, wvh + wofs, q, k, v, SEQ, HID, HID);

    rope_split_kernel<<<4096, 256, 0, stream>>>(q, k, qh, ql, kbh, kbl, ct, st);
    vtsplit_kernel<<<dim3(32, 16), 256, 0, stream>>>(v, vth, vtl);

    attn_flash_kernel<<<dim3(32, 16), 256, 0, stream>>>(
        qh, ql, kbh, kbl, vth, vtl, oh, ol);

    if (comp)
      gemm_bt_kernel<true, true, false, 64><<<dim3(8, 32, 1), 256, 0, stream>>>(
          oh, ol, woh + wofs, wol + wofs, woh + wofs, wol + wofs,
          woh + wofs, wol + wofs, h, h, h, SEQ, HID, HID);
    else
      gemm_bt_kernel<false, true, false, 64><<<dim3(8, 32, 1), 256, 0, stream>>>(
          oh, oh, woh + wofs, woh + wofs, woh + wofs, woh + wofs,
          woh + wofs, woh + wofs, h, h, h, SEQ, HID, HID);

    rmsnorm_kernel<<<SEQ, 256, 0, stream>>>(h, ln2 + li * HID, hn, hnh, hnl);
    if (li == 2) {
      router_kernel<<<512, 256, 0, stream>>>(hn, rw, rl);
      zero_kernel<<<1, 32, 0, stream>>>(aux, 17);
      topk_kernel<<<8, 256, 0, stream>>>(rl, wmoe, aux);
      aux_kernel<<<1, 1, 0, stream>>>(aux, out);
      zeroi_kernel<<<1, 32, 0, stream>>>(cnt, 8);
      build_list_kernel<<<8, 256, 0, stream>>>(wmoe, cnt, list);
      for (int e = 0; e < 8; ++e) {
        size_t go = (size_t)e * HID * IDIM;
        gemm_moe_gu_kernel<<<dim3(22, 16, 2), 256, 0, stream>>>(
            hnh, mg + go, mu + go, g, u, list + e * SEQ, cnt + e);
        silu_moe_kernel<<<dim3(11, SEQ), 256, 0, stream>>>(
            g, u, gh, wmoe, list + e * SEQ, cnt + e, e);
        gemm_moe_down_kernel<<<dim3(8, 16), 256, 0, stream>>>(
            gh, md + (size_t)e * IDIM * HID, h, list + e * SEQ, cnt + e);
      }
    } else {
      int d = (li < 2) ? li : li - 1;
      size_t go = (size_t)d * HID * IDIM;
      if (comp) {
        gemm_bt_kernel<true, false, false, 128><<<dim3(22, 16, 2), 256, 0, stream>>>(
            hnh, hnl, dgh + go, dgl + go, duh + go, dul + go,
            duh + go, dul + go, g, u, u, SEQ, IDIM, HID);
        silu_kernel<<<dim3(11, SEQ), 256, 0, stream>>>(g, u, gh, gl);
        gemm_bt_kernel<true, true, false, 64><<<dim3(8, 32, 1), 256, 0, stream>>>(
            gh, gl, ddh + go, ddl + go, ddh + go, ddl + go,
            ddh + go, ddl + go, h, h, h, SEQ, HID, IDIM);
      } else {
        gemm_bt_kernel<false, false, false, 128><<<dim3(22, 16, 2), 256, 0, stream>>>(
            hnh, hnh, dgh + go, dgh + go, duh + go, duh + go,
            duh + go, duh + go, g, u, u, SEQ, IDIM, HID);
        silu_kernel<<<dim3(11, SEQ), 256, 0, stream>>>(g, u, gh, gl);
        gemm_bt_kernel<false, true, false, 64><<<dim3(8, 32, 1), 256, 0, stream>>>(
            gh, gh, ddh + go, ddh + go, ddh + go, ddh + go,
            ddh + go, ddh + go, h, h, h, SEQ, HID, IDIM);
      }
    }
  }
  rmsnorm_kernel<<<SEQ, 256, 0, stream>>>(h, fin, hn, hnh, hnl);
  gemm_bt_kernel<false, false, true, 128><<<dim3(16, 250, 1), 256, 0, stream>>>(
      hnh, hnh, eh, eh, eh, eh, eh, eh, out, out, out, SEQ, VOCAB, HID);
}

// Round 10
// 3993.380 us; speedup vs baseline: 6.9582x; 1.0229x over previous
//
#include <hip/hip_runtime.h>
#include <hip/hip_bf16.h>
#include <math.h>

#define SEQ 2048
#define HID 1024
#define NHEAD 16
#define HDIM 64
#define IDIM 2816
#define NEXP 8
#define VOCAB 32000

#define LSTRIDE 80   // padded rows (MoE kernels)
#define ASTRIDE 144  // padded rows (attention)

typedef float f32x4v __attribute__((ext_vector_type(4)));
typedef __bf16 bf16x8v __attribute__((ext_vector_type(8)));
typedef __bf16 bf16x4v __attribute__((ext_vector_type(4)));

__device__ __forceinline__ bf16x8v cvt8(const float4& a, const float4& b) {
  bf16x8v r;
  r[0] = (__bf16)a.x; r[1] = (__bf16)a.y; r[2] = (__bf16)a.z; r[3] = (__bf16)a.w;
  r[4] = (__bf16)b.x; r[5] = (__bf16)b.y; r[6] = (__bf16)b.z; r[7] = (__bf16)b.w;
  return r;
}

#define MFMA(a, b, c) __builtin_amdgcn_mfma_f32_16x16x32_bf16(a, b, c, 0, 0, 0)

// async global->LDS DMA, 16B per lane; lds base must be wave-uniform
__device__ __forceinline__ void gld_lds16(const void* g, void* l) {
  __builtin_amdgcn_global_load_lds(
      (const __attribute__((address_space(1))) unsigned int*)(unsigned long long)g,
      (__attribute__((address_space(3))) unsigned int*)(unsigned int)(unsigned long long)l,
      16, 0, 0);
}

// ---------------------------------------------------------------------------
// Weight preprocessing: W[K,N] f32 -> WH,WL [N,K] bf16 (transposed hi/lo).
// ---------------------------------------------------------------------------
__global__ __launch_bounds__(256) void wsplit_t_kernel(
    const float* __restrict__ W, __bf16* __restrict__ WH, __bf16* __restrict__ WL,
    int K, int N)
{
  __shared__ float tile[64][65];
  const int tid = threadIdx.x;
  const size_t zofs = (size_t)blockIdx.z * K * N;
  const int n0 = blockIdx.x * 64, k0 = blockIdx.y * 64;
#pragma unroll
  for (int r = 0; r < 4; ++r) {
    int kk = (tid >> 4) + r * 16;
    int nn = (tid & 15) * 4;
    float4 v = *(const float4*)(W + zofs + (size_t)(k0 + kk) * N + n0 + nn);
    tile[kk][nn] = v.x; tile[kk][nn + 1] = v.y;
    tile[kk][nn + 2] = v.z; tile[kk][nn + 3] = v.w;
  }
  __syncthreads();
  const int nn = tid >> 2;
  const int kk = (tid & 3) * 16;
  __bf16* dh = WH + zofs + (size_t)(n0 + nn) * K + k0 + kk;
  __bf16* dl = WL + zofs + (size_t)(n0 + nn) * K + k0 + kk;
  bf16x8v h0, l0, h1, l1;
#pragma unroll
  for (int j = 0; j < 8; ++j) {
    float f = tile[kk + j][nn];
    __bf16 hb = (__bf16)f; h0[j] = hb; l0[j] = (__bf16)(f - (float)hb);
    f = tile[kk + 8 + j][nn];
    hb = (__bf16)f; h1[j] = hb; l1[j] = (__bf16)(f - (float)hb);
  }
  *(bf16x8v*)dh = h0; *(bf16x8v*)(dh + 8) = h1;
  *(bf16x8v*)dl = l0; *(bf16x8v*)(dl + 8) = l1;
}

__global__ __launch_bounds__(256) void esplit_kernel(
    const float* __restrict__ E, __bf16* __restrict__ EH)
{
  size_t i = ((size_t)blockIdx.x * 256 + threadIdx.x) * 8;
  float4 a = *(const float4*)(E + i);
  float4 b = *(const float4*)(E + i + 4);
  *(bf16x8v*)(EH + i) = cvt8(a, b);
}

// ---------------------------------------------------------------------------
// Unified BT GEMM. A,B pre-split bf16. Staging = global_load_lds DMA (16B),
// LINEAR LDS rows (64B/row) as required by the DMA's lane-linear dest.
// ---------------------------------------------------------------------------
template<bool COMP, bool ACCUM, bool SWAP, int BM>
__global__ __launch_bounds__(256) void gemm_bt_kernel(
    const __bf16* __restrict__ Ah, const __bf16* __restrict__ Al,
    const __bf16* __restrict__ B0h, const __bf16* __restrict__ B0l,
    const __bf16* __restrict__ B1h, const __bf16* __restrict__ B1l,
    const __bf16* __restrict__ B2h, const __bf16* __restrict__ B2l,
    float* __restrict__ C0, float* __restrict__ C1, float* __restrict__ C2,
    int M, int N, int Kd)
{
  const __bf16* __restrict__ Bh = (blockIdx.z == 0) ? B0h : (blockIdx.z == 1 ? B1h : B2h);
  const __bf16* __restrict__ Bl = (blockIdx.z == 0) ? B0l : (blockIdx.z == 1 ? B1l : B2l);
  float* __restrict__ C         = (blockIdx.z == 0) ? C0 : (blockIdx.z == 1 ? C1 : C2);
  constexpr int ATILE = BM * 64;      // bytes (32 k-elems * 2B per row)
  constexpr int BTILE = 128 * 64;
  constexpr int MFR = BM / 32;
  __shared__ __align__(16) char smem[COMP ? 2 * (ATILE + BTILE) : (ATILE + BTILE)];
  char* AsH = smem;
  char* BsH = smem + ATILE;
  char* AsL = COMP ? smem + ATILE + BTILE : smem;
  char* BsL = COMP ? smem + 2 * ATILE + BTILE : smem + ATILE;
  const int tid = threadIdx.x;
  const int bm = SWAP ? blockIdx.x : blockIdx.y;
  const int bn = SWAP ? blockIdx.y : blockIdx.x;
  const int wid = tid >> 6, lane = tid & 63;
  const int wm = (wid >> 1) * (BM / 2), wn = (wid & 1) << 6;
  const int lr = lane & 15, kh = lane >> 4;
  const int lrow = lane >> 2;          // DMA: row within 16-row chunk
  const int lcol = (lane & 3) << 3;    // DMA: bf16 elem offset within row

  f32x4v acc[MFR][4];
  const f32x4v z4 = {0.f, 0.f, 0.f, 0.f};
#pragma unroll
  for (int i = 0; i < MFR; ++i)
#pragma unroll
    for (int j = 0; j < 4; ++j) acc[i][j] = z4;

  for (int k0 = 0; k0 < Kd; k0 += 32) {
    __syncthreads();
#pragma unroll
    for (int c = wid; c < BM / 16; c += 4) {   // A chunks (1024B each)
      size_t gofs = (size_t)(bm * BM + c * 16 + lrow) * Kd + k0 + lcol;
      gld_lds16(Ah + gofs, AsH + c * 1024);
      if (COMP) gld_lds16(Al + gofs, AsL + c * 1024);
    }
#pragma unroll
    for (int c = wid; c < 8; c += 4) {         // B chunks
      size_t gofs = (size_t)(bn * 128 + c * 16 + lrow) * Kd + k0 + lcol;
      gld_lds16(Bh + gofs, BsH + c * 1024);
      if (COMP) gld_lds16(Bl + gofs, BsL + c * 1024);
    }
    __syncthreads();   // drains vmcnt -> LDS data visible

    bf16x8v ah[MFR], al[MFR], bh4[4], bl4[4];
#pragma unroll
    for (int i = 0; i < MFR; ++i) {
      int r = wm + (i << 4) + lr;
      int off = r * 64 + (kh << 4);
      ah[i] = *(const bf16x8v*)(AsH + off);
      if (COMP) al[i] = *(const bf16x8v*)(AsL + off);
    }
#pragma unroll
    for (int i = 0; i < 4; ++i) {
      int r = wn + (i << 4) + lr;
      int off = r * 64 + (kh << 4);
      bh4[i] = *(const bf16x8v*)(BsH + off);
      if (COMP) bl4[i] = *(const bf16x8v*)(BsL + off);
    }
#pragma unroll
    for (int mi = 0; mi < MFR; ++mi)
#pragma unroll
      for (int ni = 0; ni < 4; ++ni) {
        if (COMP) {
          acc[mi][ni] = MFMA(al[mi], bh4[ni], acc[mi][ni]);
          acc[mi][ni] = MFMA(ah[mi], bl4[ni], acc[mi][ni]);
        }
        acc[mi][ni] = MFMA(ah[mi], bh4[ni], acc[mi][ni]);
      }
  }

  const int cr0 = kh << 2;
#pragma unroll
  for (int mi = 0; mi < MFR; ++mi)
#pragma unroll
    for (int ni = 0; ni < 4; ++ni)
#pragma unroll
      for (int r = 0; r < 4; ++r) {
        int row = bm * BM + wm + (mi << 4) + cr0 + r;
        int col = bn * 128 + wn + (ni << 4) + lr;
        size_t idx = (size_t)row * N + col;
        if (ACCUM) C[idx] += acc[mi][ni][r];
        else       C[idx] = acc[mi][ni][r];
      }
}

// ---------------------------------------------------------------------------
// rope + hi/lo split for Q (scale 1/8) and K
// ---------------------------------------------------------------------------
__global__ __launch_bounds__(256) void rope_split_kernel(
    const float* __restrict__ Q, const float* __restrict__ K,
    __bf16* __restrict__ QH, __bf16* __restrict__ QL,
    __bf16* __restrict__ KH, __bf16* __restrict__ KL,
    const float* __restrict__ CT, const float* __restrict__ ST)
{
  int idx = blockIdx.x * 256 + threadIdx.x;
  int s = idx >> 9;
  int rr = idx & 511;
  int hd = rr >> 5;
  int i = rr & 31;
  float c = CT[(s << 5) + i], sn = ST[(s << 5) + i];
  size_t base = (size_t)s * HID + hd * 64 + i;
  {
    float x1 = Q[base], x2 = Q[base + 32];
    float o1 = (x1 * c - x2 * sn) * 0.125f;
    float o2 = (x2 * c + x1 * sn) * 0.125f;
    __bf16 h1 = (__bf16)o1, h2 = (__bf16)o2;
    QH[base] = h1;      QL[base] = (__bf16)(o1 - (float)h1);
    QH[base + 32] = h2; QL[base + 32] = (__bf16)(o2 - (float)h2);
  }
  {
    float x1 = K[base], x2 = K[base + 32];
    float o1 = x1 * c - x2 * sn;
    float o2 = x2 * c + x1 * sn;
    __bf16 h1 = (__bf16)o1, h2 = (__bf16)o2;
    KH[base] = h1;      KL[base] = (__bf16)(o1 - (float)h1);
    KH[base + 32] = h2; KL[base + 32] = (__bf16)(o2 - (float)h2);
  }
}

// V f32 [S][HID] -> per-head transposed hi/lo bf16 [NHEAD][HDIM][SEQ]
__global__ __launch_bounds__(256) void vtsplit_kernel(
    const float* __restrict__ V, __bf16* __restrict__ VTH, __bf16* __restrict__ VTL)
{
  __shared__ float tile[64][65];
  const int tid = threadIdx.x;
  const int s0 = blockIdx.x * 64;
  const int head = blockIdx.y;
#pragma unroll
  for (int r = 0; r < 4; ++r) {
    int ss = (tid >> 4) + r * 16;
    int dd = (tid & 15) * 4;
    float4 v = *(const float4*)(V + (size_t)(s0 + ss) * HID + head * 64 + dd);
    tile[ss][dd] = v.x; tile[ss][dd + 1] = v.y;
    tile[ss][dd + 2] = v.z; tile[ss][dd + 3] = v.w;
  }
  __syncthreads();
#pragma unroll
  for (int half = 0; half < 2; ++half) {
    const int d = (tid >> 3) + (half << 5);
    const int c = tid & 7;
    bf16x8v hv, lv;
#pragma unroll
    for (int j = 0; j < 8; ++j) {
      float f = tile[c * 8 + j][d];
      __bf16 hb = (__bf16)f;
      hv[j] = hb; lv[j] = (__bf16)(f - (float)hb);
    }
    size_t dst = (size_t)(head * 64 + d) * SEQ + s0 + c * 8;
    *(bf16x8v*)(VTH + dst) = hv;
    *(bf16x8v*)(VTL + dst) = lv;
  }
}

// ---------------------------------------------------------------------------
// Compensated flash attention; padded LDS (reads need the pad); O -> bf16 hi/lo
// ---------------------------------------------------------------------------
__global__ __launch_bounds__(256) void attn_flash_kernel(
    const __bf16* __restrict__ QH, const __bf16* __restrict__ QL,
    const __bf16* __restrict__ KH, const __bf16* __restrict__ KL,
    const __bf16* __restrict__ VTH, const __bf16* __restrict__ VTL,
    __bf16* __restrict__ OH, __bf16* __restrict__ OL)
{
  const int qt = blockIdx.x;
  const int head = blockIdx.y;
  const int tid = threadIdx.x, wid = tid >> 6, lane = tid & 63;
  const int lr = lane & 15, kh = lane >> 4;
  __shared__ __align__(16) char KsH[64 * ASTRIDE], KsL[64 * ASTRIDE];
  __shared__ __align__(16) char VtH[64 * ASTRIDE], VtL[64 * ASTRIDE];
  __shared__ __align__(16) char PsH[4][16 * ASTRIDE], PsL[4][16 * ASTRIDE];

  const size_t qofs = (size_t)(qt * 64 + wid * 16 + lr) * HID + head * HDIM;
  const bf16x8v qfh0 = *(const bf16x8v*)(QH + qofs + (kh << 3));
  const bf16x8v qfh1 = *(const bf16x8v*)(QH + qofs + 32 + (kh << 3));
  const bf16x8v qfl0 = *(const bf16x8v*)(QL + qofs + (kh << 3));
  const bf16x8v qfl1 = *(const bf16x8v*)(QL + qofs + 32 + (kh << 3));

  float m_run[4], l_run[4];
  f32x4v oacc[4];
  const f32x4v z4 = {0.f, 0.f, 0.f, 0.f};
#pragma unroll
  for (int i = 0; i < 4; ++i) { m_run[i] = -1e30f; l_run[i] = 0.f; oacc[i] = z4; }

  for (int kt = 0; kt <= qt; ++kt) {
    __syncthreads();
#pragma unroll
    for (int p = 0; p < 2; ++p) {
      int g = tid + (p << 8);
      int r = g >> 3;
      int c = g & 7;
      int off = r * ASTRIDE + (c << 4);
      const size_t kofs = (size_t)(kt * 64 + r) * HID + head * HDIM + (c << 3);
      *(bf16x8v*)(KsH + off) = *(const bf16x8v*)(KH + kofs);
      *(bf16x8v*)(KsL + off) = *(const bf16x8v*)(KL + kofs);
      const size_t vofs = (size_t)(head * 64 + r) * SEQ + kt * 64 + (c << 3);
      *(bf16x8v*)(VtH + off) = *(const bf16x8v*)(VTH + vofs);
      *(bf16x8v*)(VtL + off) = *(const bf16x8v*)(VTL + vofs);
    }
    __syncthreads();

    float sv[4][4];
#pragma unroll
    for (int stt = 0; stt < 4; ++stt) {
      int r = (stt << 4) + lr;
      int off0 = r * ASTRIDE + (kh << 4);
      int off1 = off0 + 64;
      bf16x8v kfh0 = *(const bf16x8v*)(KsH + off0);
      bf16x8v kfl0 = *(const bf16x8v*)(KsL + off0);
      bf16x8v kfh1 = *(const bf16x8v*)(KsH + off1);
      bf16x8v kfl1 = *(const bf16x8v*)(KsL + off1);
      f32x4v s = z4;
      s = MFMA(qfl0, kfh0, s);
      s = MFMA(qfh0, kfl0, s);
      s = MFMA(qfh0, kfh0, s);
      s = MFMA(qfl1, kfh1, s);
      s = MFMA(qfh1, kfl1, s);
      s = MFMA(qfh1, kfh1, s);
      int key = kt * 64 + (stt << 4) + lr;
#pragma unroll
      for (int rr = 0; rr < 4; ++rr) {
        int qr = qt * 64 + wid * 16 + (kh << 2) + rr;
        sv[stt][rr] = (key <= qr) ? s[rr] : -1e30f;
      }
    }

#pragma unroll
    for (int rr = 0; rr < 4; ++rr) {
      float mx = fmaxf(fmaxf(sv[0][rr], sv[1][rr]), fmaxf(sv[2][rr], sv[3][rr]));
#pragma unroll
      for (int d = 1; d < 16; d <<= 1) mx = fmaxf(mx, __shfl_xor(mx, d));
      float mnew = fmaxf(m_run[rr], mx);
      float scl = __expf(m_run[rr] - mnew);
      float pv[4];
#pragma unroll
      for (int stt = 0; stt < 4; ++stt) pv[stt] = __expf(sv[stt][rr] - mnew);
      float rs = pv[0] + pv[1] + pv[2] + pv[3];
#pragma unroll
      for (int d = 1; d < 16; d <<= 1) rs += __shfl_xor(rs, d);
      l_run[rr] = l_run[rr] * scl + rs;
      m_run[rr] = mnew;
#pragma unroll
      for (int n = 0; n < 4; ++n) oacc[n][rr] *= scl;
      int qlr = (kh << 2) + rr;
#pragma unroll
      for (int stt = 0; stt < 4; ++stt) {
        __bf16 hb = (__bf16)pv[stt];
        __bf16 lb = (__bf16)(pv[stt] - (float)hb);
        int off = qlr * ASTRIDE + (((stt << 4) + lr) << 1);
        *(__bf16*)(PsH[wid] + off) = hb;
        *(__bf16*)(PsL[wid] + off) = lb;
      }
    }

    int poff0 = lr * ASTRIDE + (kh << 4);
    int poff1 = poff0 + 64;
    bf16x8v pah0 = *(const bf16x8v*)(PsH[wid] + poff0);
    bf16x8v pal0 = *(const bf16x8v*)(PsL[wid] + poff0);
    bf16x8v pah1 = *(const bf16x8v*)(PsH[wid] + poff1);
    bf16x8v pal1 = *(const bf16x8v*)(PsL[wid] + poff1);
#pragma unroll
    for (int n = 0; n < 4; ++n) {
      int vr = (n << 4) + lr;
      int voff0 = vr * ASTRIDE + (kh << 4);
      int voff1 = voff0 + 64;
      bf16x8v vfh0 = *(const bf16x8v*)(VtH + voff0);
      bf16x8v vfl0 = *(const bf16x8v*)(VtL + voff0);
      bf16x8v vfh1 = *(const bf16x8v*)(VtH + voff1);
      bf16x8v vfl1 = *(const bf16x8v*)(VtL + voff1);
      oacc[n] = MFMA(pal0, vfh0, oacc[n]);
      oacc[n] = MFMA(pah0, vfl0, oacc[n]);
      oacc[n] = MFMA(pah0, vfh0, oacc[n]);
      oacc[n] = MFMA(pal1, vfh1, oacc[n]);
      oacc[n] = MFMA(pah1, vfl1, oacc[n]);
      oacc[n] = MFMA(pah1, vfh1, oacc[n]);
    }
  }

#pragma unroll
  for (int n = 0; n < 4; ++n)
#pragma unroll
    for (int rr = 0; rr < 4; ++rr) {
      int qr = qt * 64 + wid * 16 + (kh << 2) + rr;
      size_t ofs = (size_t)qr * HID + head * HDIM + (n << 4) + lr;
      float val = oacc[n][rr] / l_run[rr];
      __bf16 hb = (__bf16)val;
      OH[ofs] = hb;
      OL[ofs] = (__bf16)(val - (float)hb);
    }
}

// ---------------------------------------------------------------------------
// MoE gathered GEMMs (unchanged; pad-80 LDS, f32 B convert in-kernel)
// ---------------------------------------------------------------------------
__global__ __launch_bounds__(256) void gemm_moe_gu_kernel(
    const __bf16* __restrict__ Xh,
    const float* __restrict__ B0, const float* __restrict__ B1,
    float* __restrict__ C0, float* __restrict__ C1,
    const int* __restrict__ list, const int* __restrict__ cntp)
{
  const int cnt = cntp[0];
  const int bm = blockIdx.y, bn = blockIdx.x;
  if (bm * 128 >= cnt) return;
  const float* __restrict__ B = blockIdx.z ? B1 : B0;
  float* __restrict__ C       = blockIdx.z ? C1 : C0;
  __shared__ __align__(16) char AsB[128 * LSTRIDE];
  __shared__ __align__(16) char BsB[128 * LSTRIDE];
  const int tid = threadIdx.x;
  const int wid = tid >> 6, lane = tid & 63;
  const int wm = (wid >> 1) << 6, wn = (wid & 1) << 6;
  const int lr = lane & 15, kh = lane >> 4;

  f32x4v acc[4][4];
  const f32x4v z4 = {0.f, 0.f, 0.f, 0.f};
#pragma unroll
  for (int i = 0; i < 4; ++i)
#pragma unroll
    for (int j = 0; j < 4; ++j) acc[i][j] = z4;

  for (int k0 = 0; k0 < HID; k0 += 32) {
    __syncthreads();
#pragma unroll
    for (int p = 0; p < 2; ++p) {
      int g = tid + (p << 8);
      int r = g >> 2;
      int c = g & 3;
      int rg = bm * 128 + r;
      int tok = list[rg < cnt ? rg : cnt - 1];
      *(bf16x8v*)(AsB + r * LSTRIDE + (c << 4)) =
          *(const bf16x8v*)(Xh + (size_t)tok * HID + k0 + (c << 3));
    }
#pragma unroll
    for (int p = 0; p < 2; ++p) {
      int g = tid + (p << 8);
      int k = g >> 4;
      int n8 = (g & 15) << 3;
      const float* src = B + (size_t)(k0 + k) * IDIM + bn * 128 + n8;
      float4 f0 = *(const float4*)src;
      float4 f1 = *(const float4*)(src + 4);
      float fv[8] = {f0.x, f0.y, f0.z, f0.w, f1.x, f1.y, f1.z, f1.w};
#pragma unroll
      for (int i = 0; i < 8; ++i) {
        int r = n8 + i;
        *(__bf16*)(BsB + r * LSTRIDE + (k << 1)) = (__bf16)fv[i];
      }
    }
    __syncthreads();

    bf16x8v af[4], bfv[4];
#pragma unroll
    for (int i = 0; i < 4; ++i) {
      int r = wm + (i << 4) + lr;
      af[i] = *(const bf16x8v*)(AsB + r * LSTRIDE + (kh << 4));
    }
#pragma unroll
    for (int i = 0; i < 4; ++i) {
      int r = wn + (i << 4) + lr;
      bfv[i] = *(const bf16x8v*)(BsB + r * LSTRIDE + (kh << 4));
    }
#pragma unroll
    for (int mi = 0; mi < 4; ++mi)
#pragma unroll
      for (int ni = 0; ni < 4; ++ni)
        acc[mi][ni] = MFMA(af[mi], bfv[ni], acc[mi][ni]);
  }

  const int cr0 = kh << 2;
#pragma unroll
  for (int mi = 0; mi < 4; ++mi)
#pragma unroll
    for (int ni = 0; ni < 4; ++ni)
#pragma unroll
      for (int r = 0; r < 4; ++r) {
        int row = bm * 128 + wm + (mi << 4) + cr0 + r;
        if (row < cnt) {
          int col = bn * 128 + wn + (ni << 4) + lr;
          C[(size_t)row * IDIM + col] = acc[mi][ni][r];
        }
      }
}

__global__ __launch_bounds__(256) void gemm_moe_down_kernel(
    const __bf16* __restrict__ Gh, const float* __restrict__ MD,
    float* __restrict__ H,
    const int* __restrict__ list, const int* __restrict__ cntp)
{
  const int cnt = cntp[0];
  const int bm = blockIdx.y, bn = blockIdx.x;
  if (bm * 128 >= cnt) return;
  __shared__ __align__(16) char AsB[128 * LSTRIDE];
  __shared__ __align__(16) char BsB[128 * LSTRIDE];
  const int tid = threadIdx.x;
  const int wid = tid >> 6, lane = tid & 63;
  const int wm = (wid >> 1) << 6, wn = (wid & 1) << 6;
  const int lr = lane & 15, kh = lane >> 4;

  f32x4v acc[4][4];
  const f32x4v z4 = {0.f, 0.f, 0.f, 0.f};
#pragma unroll
  for (int i = 0; i < 4; ++i)
#pragma unroll
    for (int j = 0; j < 4; ++j) acc[i][j] = z4;

  for (int k0 = 0; k0 < IDIM; k0 += 32) {
    __syncthreads();
#pragma unroll
    for (int p = 0; p < 2; ++p) {
      int g = tid + (p << 8);
      int r = g >> 2;
      int c = g & 3;
      int rg = bm * 128 + r;
      *(bf16x8v*)(AsB + r * LSTRIDE + (c << 4)) =
          *(const bf16x8v*)(Gh + (size_t)(rg < cnt ? rg : cnt - 1) * IDIM + k0 + (c << 3));
    }
#pragma unroll
    for (int p = 0; p < 2; ++p) {
      int g = tid + (p << 8);
      int k = g >> 4;
      int n8 = (g & 15) << 3;
      const float* src = MD + (size_t)(k0 + k) * HID + bn * 128 + n8;
      float4 f0 = *(const float4*)src;
      float4 f1 = *(const float4*)(src + 4);
      float fv[8] = {f0.x, f0.y, f0.z, f0.w, f1.x, f1.y, f1.z, f1.w};
#pragma unroll
      for (int i = 0; i < 8; ++i) {
        int r = n8 + i;
        *(__bf16*)(BsB + r * LSTRIDE + (k << 1)) = (__bf16)fv[i];
      }
    }
    __syncthreads();

    bf16x8v af[4], bfv[4];
#pragma unroll
    for (int i = 0; i < 4; ++i) {
      int r = wm + (i << 4) + lr;
      af[i] = *(const bf16x8v*)(AsB + r * LSTRIDE + (kh << 4));
    }
#pragma unroll
    for (int i = 0; i < 4; ++i) {
      int r = wn + (i << 4) + lr;
      bfv[i] = *(const bf16x8v*)(BsB + r * LSTRIDE + (kh << 4));
    }
#pragma unroll
    for (int mi = 0; mi < 4; ++mi)
#pragma unroll
      for (int ni = 0; ni < 4; ++ni)
        acc[mi][ni] = MFMA(af[mi], bfv[ni], acc[mi][ni]);
  }

  const int cr0 = kh << 2;
#pragma unroll
  for (int mi = 0; mi < 4; ++mi)
#pragma unroll
    for (int ni = 0; ni < 4; ++ni)
#pragma unroll
      for (int r = 0; r < 4; ++r) {
        int row = bm * 128 + wm + (mi << 4) + cr0 + r;
        if (row < cnt) {
          int col = bn * 128 + wn + (ni << 4) + lr;
          H[(size_t)list[row] * HID + col] += acc[mi][ni][r];
        }
      }
}

// ---------------------------------------------------------------------------
// Small kernels
// ---------------------------------------------------------------------------
__global__ void tables_kernel(float* __restrict__ CT, float* __restrict__ ST)
{
  int idx = blockIdx.x * 256 + threadIdx.x;
  int s = idx >> 5, i = idx & 31;
  double inv = exp(-log(10000.0) * (double)i / 32.0);
  double ang = (double)s * inv;
  CT[idx] = (float)cos(ang);
  ST[idx] = (float)sin(ang);
}

__global__ __launch_bounds__(256) void embed_kernel(
    const int* __restrict__ ids, const float* __restrict__ E, float* __restrict__ H)
{
  int t = blockIdx.x;
  int id = ids[t];
  ((float4*)(H + (size_t)t * HID))[threadIdx.x] =
      ((const float4*)(E + (size_t)id * HID))[threadIdx.x];
}

__global__ __launch_bounds__(256) void rmsnorm_kernel(
    const float* __restrict__ X, const float* __restrict__ W,
    float* __restrict__ O, __bf16* __restrict__ OHb, __bf16* __restrict__ OLb)
{
  int t = blockIdx.x;
  int tid = threadIdx.x;
  float4 v = ((const float4*)(X + (size_t)t * HID))[tid];
  float ss = v.x * v.x + v.y * v.y + v.z * v.z + v.w * v.w;
#pragma unroll
  for (int d = 1; d < 64; d <<= 1) ss += __shfl_xor(ss, d);
  __shared__ float red[4];
  if ((tid & 63) == 0) red[tid >> 6] = ss;
  __syncthreads();
  float tot = red[0] + red[1] + red[2] + red[3];
  float inv = 1.0f / sqrtf(tot * (1.0f / 1024.0f) + 1e-6f);
  float4 w = ((const float4*)W)[tid];
  float4 r;
  r.x = v.x * inv * w.x; r.y = v.y * inv * w.y;
  r.z = v.z * inv * w.z; r.w = v.w * inv * w.w;
  ((float4*)(O + (size_t)t * HID))[tid] = r;
  float f[4] = {r.x, r.y, r.z, r.w};
  bf16x4v hv, lv;
#pragma unroll
  for (int j = 0; j < 4; ++j) {
    __bf16 hb = (__bf16)f[j];
    hv[j] = hb; lv[j] = (__bf16)(f[j] - (float)hb);
  }
  *(bf16x4v*)(OHb + (size_t)t * HID + tid * 4) = hv;
  *(bf16x4v*)(OLb + (size_t)t * HID + tid * 4) = lv;
}

__global__ __launch_bounds__(256) void silu_kernel(
    const float* __restrict__ G, const float* __restrict__ U,
    __bf16* __restrict__ AH, __bf16* __restrict__ AL)
{
  int t = blockIdx.y;
  int i = blockIdx.x * 256 + threadIdx.x;
  size_t idx = (size_t)t * IDIM + i;
  float gv = G[idx], uv = U[idx];
  float a = gv / (1.f + __expf(-gv)) * uv;
  __bf16 hb = (__bf16)a;
  AH[idx] = hb;
  AL[idx] = (__bf16)(a - (float)hb);
}

__global__ __launch_bounds__(256) void silu_moe_kernel(
    const float* __restrict__ G, const float* __restrict__ U, __bf16* __restrict__ AH,
    const float* __restrict__ W, const int* __restrict__ list,
    const int* __restrict__ cntp, int e)
{
  int t = blockIdx.y;
  if (t >= cntp[0]) return;
  int i = blockIdx.x * 256 + threadIdx.x;
  size_t idx = (size_t)t * IDIM + i;
  float gv = G[idx], uv = U[idx];
  AH[idx] = (__bf16)(gv / (1.f + __expf(-gv)) * uv * W[list[t] * 8 + e]);
}

__global__ __launch_bounds__(256) void router_kernel(
    const float* __restrict__ X, const float* __restrict__ RW, float* __restrict__ RL)
{
  int wid = threadIdx.x >> 6, lane = threadIdx.x & 63;
  int t = blockIdx.x * 4 + wid;
  const float* x = X + (size_t)t * HID;
  float a0 = 0, a1 = 0, a2 = 0, a3 = 0, a4 = 0, a5 = 0, a6 = 0, a7 = 0;
  for (int hh = lane; hh < HID; hh += 64) {
    float xv = x[hh];
    float4 f0 = *(const float4*)(RW + hh * 8);
    float4 f1 = *(const float4*)(RW + hh * 8 + 4);
    a0 += xv * f0.x; a1 += xv * f0.y; a2 += xv * f0.z; a3 += xv * f0.w;
    a4 += xv * f1.x; a5 += xv * f1.y; a6 += xv * f1.z; a7 += xv * f1.w;
  }
#pragma unroll
  for (int d = 1; d < 64; d <<= 1) {
    a0 += __shfl_xor(a0, d); a1 += __shfl_xor(a1, d);
    a2 += __shfl_xor(a2, d); a3 += __shfl_xor(a3, d);
    a4 += __shfl_xor(a4, d); a5 += __shfl_xor(a5, d);
    a6 += __shfl_xor(a6, d); a7 += __shfl_xor(a7, d);
  }
  if (lane == 0) {
    float* dst = RL + (size_t)t * 8;
    dst[0] = a0; dst[1] = a1; dst[2] = a2; dst[3] = a3;
    dst[4] = a4; dst[5] = a5; dst[6] = a6; dst[7] = a7;
  }
}

__global__ void zero_kernel(float* __restrict__ p, int n)
{
  int i = threadIdx.x;
  if (i < n) p[i] = 0.f;
}

__global__ void zeroi_kernel(int* __restrict__ p, int n)
{
  int i = threadIdx.x;
  if (i < n) p[i] = 0;
}

__global__ __launch_bounds__(256) void topk_kernel(
    const float* __restrict__ RL, float* __restrict__ W, float* __restrict__ AUX)
{
  int t = blockIdx.x * 256 + threadIdx.x;
  int lane = threadIdx.x & 63;
  float r[8];
#pragma unroll
  for (int e = 0; e < 8; ++e) r[e] = RL[t * 8 + e];
  float mx = r[0];
#pragma unroll
  for (int e = 1; e < 8; ++e) mx = fmaxf(mx, r[e]);
  float p[8];
  float se = 0.f;
#pragma unroll
  for (int e = 0; e < 8; ++e) { p[e] = __expf(r[e] - mx); se += p[e]; }
  float inv = 1.f / se;
#pragma unroll
  for (int e = 0; e < 8; ++e) p[e] *= inv;
  float lse = logf(se) + mx;
  int i1 = 0; float v1 = p[0];
#pragma unroll
  for (int e = 1; e < 8; ++e) if (p[e] > v1) { v1 = p[e]; i1 = e; }
  int i2 = -1; float v2 = -1.f;
#pragma unroll
  for (int e = 0; e < 8; ++e) if (e != i1 && p[e] > v2) { v2 = p[e]; i2 = e; }
  float s12 = v1 + v2;
#pragma unroll
  for (int e = 0; e < 8; ++e)
    W[t * 8 + e] = (e == i1) ? v1 / s12 : ((e == i2) ? v2 / s12 : 0.f);
#pragma unroll
  for (int e = 0; e < 8; ++e) {
    float fe = ((i1 == e) ? 1.f : 0.f) + ((i2 == e) ? 1.f : 0.f);
    float pe = p[e];
#pragma unroll
    for (int d = 1; d < 64; d <<= 1) { fe += __shfl_xor(fe, d); pe += __shfl_xor(pe, d); }
    if (lane == 0) { atomicAdd(&AUX[e], fe); atomicAdd(&AUX[8 + e], pe); }
  }
  float zz = lse * lse;
#pragma unroll
  for (int d = 1; d < 64; d <<= 1) zz += __shfl_xor(zz, d);
  if (lane == 0) atomicAdd(&AUX[16], zz);
}

__global__ void aux_kernel(const float* __restrict__ AUX, float* __restrict__ OUT)
{
  float s = 0.f;
#pragma unroll
  for (int e = 0; e < 8; ++e)
    s += (AUX[e] * (1.f / 2048.f)) * (AUX[8 + e] * (1.f / 2048.f));
  float auxv = 0.01f * 8.f * s;
  float z = 0.001f * (AUX[16] * (1.f / 2048.f));
  OUT[(size_t)SEQ * VOCAB] = auxv + z;
}

__global__ __launch_bounds__(256) void build_list_kernel(
    const float* __restrict__ W, int* __restrict__ cnt, int* __restrict__ list)
{
  int t = blockIdx.x * 256 + threadIdx.x;
#pragma unroll
  for (int e = 0; e < 8; ++e) {
    if (W[t * 8 + e] > 0.f) {
      int p = atomicAdd(&cnt[e], 1);
      list[e * SEQ + p] = t;
    }
  }
}

// ---------------------------------------------------------------------------
extern "C" void kernel_launch(void* const* d_in, const int* in_sizes, int n_in,
                              void* d_out, int out_size, void* d_ws, size_t ws_size,
                              hipStream_t stream)
{
  const int*   ids   = (const int*)d_in[0];
  const float* embed = (const float*)d_in[1];
  const float* ln1   = (const float*)d_in[2];
  const float* ln2   = (const float*)d_in[3];
  const float* wq    = (const float*)d_in[4];
  const float* wk    = (const float*)d_in[5];
  const float* wv    = (const float*)d_in[6];
  const float* wo    = (const float*)d_in[7];
  const float* dg    = (const float*)d_in[8];
  const float* du    = (const float*)d_in[9];
  const float* dd    = (const float*)d_in[10];
  const float* rw    = (const float*)d_in[11];
  const float* mg    = (const float*)d_in[12];
  const float* mu    = (const float*)d_in[13];
  const float* md    = (const float*)d_in[14];
  const float* fin   = (const float*)d_in[15];
  float* out = (float*)d_out;

  char* ws = (char*)d_ws;
  float* h    = (float*)(ws + 0);
  float* hn   = (float*)(ws + 8388608);
  float* q    = (float*)(ws + 16777216);
  float* k    = (float*)(ws + 25165824);
  float* v    = (float*)(ws + 33554432);
  __bf16* oh  = (__bf16*)(ws + 41943040);
  __bf16* ol  = (__bf16*)(ws + 46137344);
  float* g    = (float*)(ws + 50331648);
  float* u    = (float*)(ws + 73400320);
  float* ct   = (float*)(ws + 96468992);
  float* st   = (float*)(ws + 96731136);
  float* rl   = (float*)(ws + 96993280);
  float* wmoe = (float*)(ws + 97058816);
  float* aux  = (float*)(ws + 97124352);
  int*   cnt  = (int*)  (ws + 97124608);
  int*   list = (int*)  (ws + 97124864);
  __bf16* wqh = (__bf16*)(ws + 97320960);
  __bf16* wql = (__bf16*)(ws + 105709568);
  __bf16* wkh = (__bf16*)(ws + 114098176);
  __bf16* wkl = (__bf16*)(ws + 122486784);
  __bf16* wvh = (__bf16*)(ws + 130875392);
  __bf16* wvl = (__bf16*)(ws + 139264000);
  __bf16* woh = (__bf16*)(ws + 147652608);
  __bf16* wol = (__bf16*)(ws + 156041216);
  __bf16* dgh = (__bf16*)(ws + 164429824);
  __bf16* dgl = (__bf16*)(ws + 181731328);
  __bf16* duh = (__bf16*)(ws + 199032832);
  __bf16* dul = (__bf16*)(ws + 216334336);
  __bf16* ddh = (__bf16*)(ws + 233635840);
  __bf16* ddl = (__bf16*)(ws + 250937344);
  __bf16* eh  = (__bf16*)(ws + 268238848);
  __bf16* hnh = (__bf16*)(ws + 333774848);
  __bf16* hnl = (__bf16*)(ws + 337969152);
  __bf16* gh  = (__bf16*)(ws + 342163456);
  __bf16* gl  = (__bf16*)(ws + 353697792);   // end 365,232,128
  __bf16* qh  = (__bf16*)g;
  __bf16* ql  = (__bf16*)((char*)g + 4194304);
  __bf16* kbh = (__bf16*)((char*)g + 8388608);
  __bf16* kbl = (__bf16*)((char*)g + 12582912);
  __bf16* vth = (__bf16*)u;
  __bf16* vtl = (__bf16*)((char*)u + 4194304);

  wsplit_t_kernel<<<dim3(16, 16, 4), 256, 0, stream>>>(wq, wqh, wql, HID, HID);
  wsplit_t_kernel<<<dim3(16, 16, 4), 256, 0, stream>>>(wk, wkh, wkl, HID, HID);
  wsplit_t_kernel<<<dim3(16, 16, 4), 256, 0, stream>>>(wv, wvh, wvl, HID, HID);
  wsplit_t_kernel<<<dim3(16, 16, 4), 256, 0, stream>>>(wo, woh, wol, HID, HID);
  wsplit_t_kernel<<<dim3(44, 16, 3), 256, 0, stream>>>(dg, dgh, dgl, HID, IDIM);
  wsplit_t_kernel<<<dim3(44, 16, 3), 256, 0, stream>>>(du, duh, dul, HID, IDIM);
  wsplit_t_kernel<<<dim3(16, 44, 3), 256, 0, stream>>>(dd, ddh, ddl, IDIM, HID);
  esplit_kernel<<<16000, 256, 0, stream>>>(embed, eh);

  tables_kernel<<<256, 256, 0, stream>>>(ct, st);
  embed_kernel<<<SEQ, 256, 0, stream>>>(ids, embed, h);

  for (int li = 0; li < 4; ++li) {
    const bool comp = (li <= 2);
    rmsnorm_kernel<<<SEQ, 256, 0, stream>>>(h, ln1 + li * HID, hn, hnh, hnl);
    size_t wofs = (size_t)li * HID * HID;
    if (comp)
      gemm_bt_kernel<true, false, false, 64><<<dim3(8, 32, 3), 256, 0, stream>>>(
          hnh, hnl, wqh + wofs, wql + wofs, wkh + wofs, wkl + wofs,
          wvh + wofs, wvl + wofs, q, k, v, SEQ, HID, HID);
    else
      gemm_bt_kernel<false, false, false, 64><<<dim3(8, 32, 3), 256, 0, stream>>>(
          hnh, hnh, wqh + wofs, wqh + wofs, wkh + wofs, wkh + wofs,
          wvh + wofs, wvh + wofs, q, k, v, SEQ, HID, HID);

    rope_split_kernel<<<4096, 256, 0, stream>>>(q, k, qh, ql, kbh, kbl, ct, st);
    vtsplit_kernel<<<dim3(32, 16), 256, 0, stream>>>(v, vth, vtl);

    attn_flash_kernel<<<dim3(32, 16), 256, 0, stream>>>(
        qh, ql, kbh, kbl, vth, vtl, oh, ol);

    if (comp)
      gemm_bt_kernel<true, true, false, 64><<<dim3(8, 32, 1), 256, 0, stream>>>(
          oh, ol, woh + wofs, wol + wofs, woh + wofs, wol + wofs,
          woh + wofs, wol + wofs, h, h, h, SEQ, HID, HID);
    else
      gemm_bt_kernel<false, true, false, 64><<<dim3(8, 32, 1), 256, 0, stream>>>(
          oh, oh, woh + wofs, woh + wofs, woh + wofs, woh + wofs,
          woh + wofs, woh + wofs, h, h, h, SEQ, HID, HID);

    rmsnorm_kernel<<<SEQ, 256, 0, stream>>>(h, ln2 + li * HID, hn, hnh, hnl);
    if (li == 2) {
      router_kernel<<<512, 256, 0, stream>>>(hn, rw, rl);
      zero_kernel<<<1, 32, 0, stream>>>(aux, 17);
      topk_kernel<<<8, 256, 0, stream>>>(rl, wmoe, aux);
      aux_kernel<<<1, 1, 0, stream>>>(aux, out);
      zeroi_kernel<<<1, 32, 0, stream>>>(cnt, 8);
      build_list_kernel<<<8, 256, 0, stream>>>(wmoe, cnt, list);
      for (int e = 0; e < 8; ++e) {
        size_t go = (size_t)e * HID * IDIM;
        gemm_moe_gu_kernel<<<dim3(22, 16, 2), 256, 0, stream>>>(
            hnh, mg + go, mu + go, g, u, list + e * SEQ, cnt + e);
        silu_moe_kernel<<<dim3(11, SEQ), 256, 0, stream>>>(
            g, u, gh, wmoe, list + e * SEQ, cnt + e, e);
        gemm_moe_down_kernel<<<dim3(8, 16), 256, 0, stream>>>(
            gh, md + (size_t)e * IDIM * HID, h, list + e * SEQ, cnt + e);
      }
    } else {
      int d = (li < 2) ? li : li - 1;
      size_t go = (size_t)d * HID * IDIM;
      if (comp) {
        gemm_bt_kernel<true, false, false, 128><<<dim3(22, 16, 2), 256, 0, stream>>>(
            hnh, hnl, dgh + go, dgl + go, duh + go, dul + go,
            duh + go, dul + go, g, u, u, SEQ, IDIM, HID);
        silu_kernel<<<dim3(11, SEQ), 256, 0, stream>>>(g, u, gh, gl);
        gemm_bt_kernel<true, true, false, 64><<<dim3(8, 32, 1), 256, 0, stream>>>(
            gh, gl, ddh + go, ddl + go, ddh + go, ddl + go,
            ddh + go, ddl + go, h, h, h, SEQ, HID, IDIM);
      } else {
        gemm_bt_kernel<false, false, false, 128><<<dim3(22, 16, 2), 256, 0, stream>>>(
            hnh, hnh, dgh + go, dgh + go, duh + go, duh + go,
            duh + go, duh + go, g, u, u, SEQ, IDIM, HID);
        silu_kernel<<<dim3(11, SEQ), 256, 0, stream>>>(g, u, gh, gl);
        gemm_bt_kernel<false, true, false, 64><<<dim3(8, 32, 1), 256, 0, stream>>>(
            gh, gh, ddh + go, ddh + go, ddh + go, ddh + go,
            ddh + go, ddh + go, h, h, h, SEQ, HID, IDIM);
      }
    }
  }
  rmsnorm_kernel<<<SEQ, 256, 0, stream>>>(h, fin, hn, hnh, hnl);
  gemm_bt_kernel<false, false, true, 128><<<dim3(16, 250, 1), 256, 0, stream>>>(
      hnh, hnh, eh, eh, eh, eh, eh, eh, out, out, out, SEQ, VOCAB, HID);
}

// Round 11
// 2664.724 us; speedup vs baseline: 10.4276x; 1.4986x over previous
//
#include <hip/hip_runtime.h>
#include <hip/hip_bf16.h>
#include <math.h>

#define SEQ 2048
#define HID 1024
#define NHEAD 16
#define HDIM 64
#define IDIM 2816
#define NEXP 8
#define VOCAB 32000

#define LSTRIDE 80   // padded rows (MoE kernels)
#define ASTRIDE 144  // padded rows (attention)

typedef float f32x4v __attribute__((ext_vector_type(4)));
typedef __bf16 bf16x8v __attribute__((ext_vector_type(8)));
typedef __bf16 bf16x4v __attribute__((ext_vector_type(4)));

__device__ __forceinline__ bf16x8v cvt8(const float4& a, const float4& b) {
  bf16x8v r;
  r[0] = (__bf16)a.x; r[1] = (__bf16)a.y; r[2] = (__bf16)a.z; r[3] = (__bf16)a.w;
  r[4] = (__bf16)b.x; r[5] = (__bf16)b.y; r[6] = (__bf16)b.z; r[7] = (__bf16)b.w;
  return r;
}

#define MFMA(a, b, c) __builtin_amdgcn_mfma_f32_16x16x32_bf16(a, b, c, 0, 0, 0)

// async global->LDS DMA, 16B per lane; lds base must be wave-uniform
__device__ __forceinline__ void gld_lds16(const void* g, void* l) {
  __builtin_amdgcn_global_load_lds(
      (const __attribute__((address_space(1))) unsigned int*)(unsigned long long)g,
      (__attribute__((address_space(3))) unsigned int*)(unsigned int)(unsigned long long)l,
      16, 0, 0);
}

// ---------------------------------------------------------------------------
// Weight preprocessing: W[K,N] f32 -> WH,WL [N,K] bf16 (transposed hi/lo).
// ---------------------------------------------------------------------------
__global__ __launch_bounds__(256) void wsplit_t_kernel(
    const float* __restrict__ W, __bf16* __restrict__ WH, __bf16* __restrict__ WL,
    int K, int N)
{
  __shared__ float tile[64][65];
  const int tid = threadIdx.x;
  const size_t zofs = (size_t)blockIdx.z * K * N;
  const int n0 = blockIdx.x * 64, k0 = blockIdx.y * 64;
#pragma unroll
  for (int r = 0; r < 4; ++r) {
    int kk = (tid >> 4) + r * 16;
    int nn = (tid & 15) * 4;
    float4 v = *(const float4*)(W + zofs + (size_t)(k0 + kk) * N + n0 + nn);
    tile[kk][nn] = v.x; tile[kk][nn + 1] = v.y;
    tile[kk][nn + 2] = v.z; tile[kk][nn + 3] = v.w;
  }
  __syncthreads();
  const int nn = tid >> 2;
  const int kk = (tid & 3) * 16;
  __bf16* dh = WH + zofs + (size_t)(n0 + nn) * K + k0 + kk;
  __bf16* dl = WL + zofs + (size_t)(n0 + nn) * K + k0 + kk;
  bf16x8v h0, l0, h1, l1;
#pragma unroll
  for (int j = 0; j < 8; ++j) {
    float f = tile[kk + j][nn];
    __bf16 hb = (__bf16)f; h0[j] = hb; l0[j] = (__bf16)(f - (float)hb);
    f = tile[kk + 8 + j][nn];
    hb = (__bf16)f; h1[j] = hb; l1[j] = (__bf16)(f - (float)hb);
  }
  *(bf16x8v*)dh = h0; *(bf16x8v*)(dh + 8) = h1;
  *(bf16x8v*)dl = l0; *(bf16x8v*)(dl + 8) = l1;
}

__global__ __launch_bounds__(256) void esplit_kernel(
    const float* __restrict__ E, __bf16* __restrict__ EH)
{
  size_t i = ((size_t)blockIdx.x * 256 + threadIdx.x) * 8;
  float4 a = *(const float4*)(E + i);
  float4 b = *(const float4*)(E + i + 4);
  *(bf16x8v*)(EH + i) = cvt8(a, b);
}

// ---------------------------------------------------------------------------
// Unified BT GEMM. A,B pre-split bf16. Staging = global_load_lds DMA (16B),
// LINEAR LDS rows (64B/row).
// ---------------------------------------------------------------------------
template<bool COMP, bool ACCUM, bool SWAP, int BM>
__global__ __launch_bounds__(256) void gemm_bt_kernel(
    const __bf16* __restrict__ Ah, const __bf16* __restrict__ Al,
    const __bf16* __restrict__ B0h, const __bf16* __restrict__ B0l,
    const __bf16* __restrict__ B1h, const __bf16* __restrict__ B1l,
    const __bf16* __restrict__ B2h, const __bf16* __restrict__ B2l,
    float* __restrict__ C0, float* __restrict__ C1, float* __restrict__ C2,
    int M, int N, int Kd)
{
  const __bf16* __restrict__ Bh = (blockIdx.z == 0) ? B0h : (blockIdx.z == 1 ? B1h : B2h);
  const __bf16* __restrict__ Bl = (blockIdx.z == 0) ? B0l : (blockIdx.z == 1 ? B1l : B2l);
  float* __restrict__ C         = (blockIdx.z == 0) ? C0 : (blockIdx.z == 1 ? C1 : C2);
  constexpr int ATILE = BM * 64;
  constexpr int BTILE = 128 * 64;
  constexpr int MFR = BM / 32;
  __shared__ __align__(16) char smem[COMP ? 2 * (ATILE + BTILE) : (ATILE + BTILE)];
  char* AsH = smem;
  char* BsH = smem + ATILE;
  char* AsL = COMP ? smem + ATILE + BTILE : smem;
  char* BsL = COMP ? smem + 2 * ATILE + BTILE : smem + ATILE;
  const int tid = threadIdx.x;
  const int bm = SWAP ? blockIdx.x : blockIdx.y;
  const int bn = SWAP ? blockIdx.y : blockIdx.x;
  const int wid = tid >> 6, lane = tid & 63;
  const int wm = (wid >> 1) * (BM / 2), wn = (wid & 1) << 6;
  const int lr = lane & 15, kh = lane >> 4;
  const int lrow = lane >> 2;
  const int lcol = (lane & 3) << 3;

  f32x4v acc[MFR][4];
  const f32x4v z4 = {0.f, 0.f, 0.f, 0.f};
#pragma unroll
  for (int i = 0; i < MFR; ++i)
#pragma unroll
    for (int j = 0; j < 4; ++j) acc[i][j] = z4;

  for (int k0 = 0; k0 < Kd; k0 += 32) {
    __syncthreads();
#pragma unroll
    for (int c = wid; c < BM / 16; c += 4) {
      size_t gofs = (size_t)(bm * BM + c * 16 + lrow) * Kd + k0 + lcol;
      gld_lds16(Ah + gofs, AsH + c * 1024);
      if (COMP) gld_lds16(Al + gofs, AsL + c * 1024);
    }
#pragma unroll
    for (int c = wid; c < 8; c += 4) {
      size_t gofs = (size_t)(bn * 128 + c * 16 + lrow) * Kd + k0 + lcol;
      gld_lds16(Bh + gofs, BsH + c * 1024);
      if (COMP) gld_lds16(Bl + gofs, BsL + c * 1024);
    }
    __syncthreads();

    bf16x8v ah[MFR], al[MFR], bh4[4], bl4[4];
#pragma unroll
    for (int i = 0; i < MFR; ++i) {
      int r = wm + (i << 4) + lr;
      int off = r * 64 + (kh << 4);
      ah[i] = *(const bf16x8v*)(AsH + off);
      if (COMP) al[i] = *(const bf16x8v*)(AsL + off);
    }
#pragma unroll
    for (int i = 0; i < 4; ++i) {
      int r = wn + (i << 4) + lr;
      int off = r * 64 + (kh << 4);
      bh4[i] = *(const bf16x8v*)(BsH + off);
      if (COMP) bl4[i] = *(const bf16x8v*)(BsL + off);
    }
#pragma unroll
    for (int mi = 0; mi < MFR; ++mi)
#pragma unroll
      for (int ni = 0; ni < 4; ++ni) {
        if (COMP) {
          acc[mi][ni] = MFMA(al[mi], bh4[ni], acc[mi][ni]);
          acc[mi][ni] = MFMA(ah[mi], bl4[ni], acc[mi][ni]);
        }
        acc[mi][ni] = MFMA(ah[mi], bh4[ni], acc[mi][ni]);
      }
  }

  const int cr0 = kh << 2;
#pragma unroll
  for (int mi = 0; mi < MFR; ++mi)
#pragma unroll
    for (int ni = 0; ni < 4; ++ni)
#pragma unroll
      for (int r = 0; r < 4; ++r) {
        int row = bm * BM + wm + (mi << 4) + cr0 + r;
        int col = bn * 128 + wn + (ni << 4) + lr;
        size_t idx = (size_t)row * N + col;
        if (ACCUM) C[idx] += acc[mi][ni][r];
        else       C[idx] = acc[mi][ni][r];
      }
}

// ---------------------------------------------------------------------------
// rope + hi/lo split for Q (scale 1/8) and K
// ---------------------------------------------------------------------------
__global__ __launch_bounds__(256) void rope_split_kernel(
    const float* __restrict__ Q, const float* __restrict__ K,
    __bf16* __restrict__ QH, __bf16* __restrict__ QL,
    __bf16* __restrict__ KH, __bf16* __restrict__ KL,
    const float* __restrict__ CT, const float* __restrict__ ST)
{
  int idx = blockIdx.x * 256 + threadIdx.x;
  int s = idx >> 9;
  int rr = idx & 511;
  int hd = rr >> 5;
  int i = rr & 31;
  float c = CT[(s << 5) + i], sn = ST[(s << 5) + i];
  size_t base = (size_t)s * HID + hd * 64 + i;
  {
    float x1 = Q[base], x2 = Q[base + 32];
    float o1 = (x1 * c - x2 * sn) * 0.125f;
    float o2 = (x2 * c + x1 * sn) * 0.125f;
    __bf16 h1 = (__bf16)o1, h2 = (__bf16)o2;
    QH[base] = h1;      QL[base] = (__bf16)(o1 - (float)h1);
    QH[base + 32] = h2; QL[base + 32] = (__bf16)(o2 - (float)h2);
  }
  {
    float x1 = K[base], x2 = K[base + 32];
    float o1 = x1 * c - x2 * sn;
    float o2 = x2 * c + x1 * sn;
    __bf16 h1 = (__bf16)o1, h2 = (__bf16)o2;
    KH[base] = h1;      KL[base] = (__bf16)(o1 - (float)h1);
    KH[base + 32] = h2; KL[base + 32] = (__bf16)(o2 - (float)h2);
  }
}

// V f32 [S][HID] -> per-head transposed hi/lo bf16 [NHEAD][HDIM][SEQ]
__global__ __launch_bounds__(256) void vtsplit_kernel(
    const float* __restrict__ V, __bf16* __restrict__ VTH, __bf16* __restrict__ VTL)
{
  __shared__ float tile[64][65];
  const int tid = threadIdx.x;
  const int s0 = blockIdx.x * 64;
  const int head = blockIdx.y;
#pragma unroll
  for (int r = 0; r < 4; ++r) {
    int ss = (tid >> 4) + r * 16;
    int dd = (tid & 15) * 4;
    float4 v = *(const float4*)(V + (size_t)(s0 + ss) * HID + head * 64 + dd);
    tile[ss][dd] = v.x; tile[ss][dd + 1] = v.y;
    tile[ss][dd + 2] = v.z; tile[ss][dd + 3] = v.w;
  }
  __syncthreads();
#pragma unroll
  for (int half = 0; half < 2; ++half) {
    const int d = (tid >> 3) + (half << 5);
    const int c = tid & 7;
    bf16x8v hv, lv;
#pragma unroll
    for (int j = 0; j < 8; ++j) {
      float f = tile[c * 8 + j][d];
      __bf16 hb = (__bf16)f;
      hv[j] = hb; lv[j] = (__bf16)(f - (float)hb);
    }
    size_t dst = (size_t)(head * 64 + d) * SEQ + s0 + c * 8;
    *(bf16x8v*)(VTH + dst) = hv;
    *(bf16x8v*)(VTL + dst) = lv;
  }
}

// ---------------------------------------------------------------------------
// Compensated flash attention; padded LDS; O -> bf16 hi/lo
// ---------------------------------------------------------------------------
__global__ __launch_bounds__(256) void attn_flash_kernel(
    const __bf16* __restrict__ QH, const __bf16* __restrict__ QL,
    const __bf16* __restrict__ KH, const __bf16* __restrict__ KL,
    const __bf16* __restrict__ VTH, const __bf16* __restrict__ VTL,
    __bf16* __restrict__ OH, __bf16* __restrict__ OL)
{
  const int qt = blockIdx.x;
  const int head = blockIdx.y;
  const int tid = threadIdx.x, wid = tid >> 6, lane = tid & 63;
  const int lr = lane & 15, kh = lane >> 4;
  __shared__ __align__(16) char KsH[64 * ASTRIDE], KsL[64 * ASTRIDE];
  __shared__ __align__(16) char VtH[64 * ASTRIDE], VtL[64 * ASTRIDE];
  __shared__ __align__(16) char PsH[4][16 * ASTRIDE], PsL[4][16 * ASTRIDE];

  const size_t qofs = (size_t)(qt * 64 + wid * 16 + lr) * HID + head * HDIM;
  const bf16x8v qfh0 = *(const bf16x8v*)(QH + qofs + (kh << 3));
  const bf16x8v qfh1 = *(const bf16x8v*)(QH + qofs + 32 + (kh << 3));
  const bf16x8v qfl0 = *(const bf16x8v*)(QL + qofs + (kh << 3));
  const bf16x8v qfl1 = *(const bf16x8v*)(QL + qofs + 32 + (kh << 3));

  float m_run[4], l_run[4];
  f32x4v oacc[4];
  const f32x4v z4 = {0.f, 0.f, 0.f, 0.f};
#pragma unroll
  for (int i = 0; i < 4; ++i) { m_run[i] = -1e30f; l_run[i] = 0.f; oacc[i] = z4; }

  for (int kt = 0; kt <= qt; ++kt) {
    __syncthreads();
#pragma unroll
    for (int p = 0; p < 2; ++p) {
      int g = tid + (p << 8);
      int r = g >> 3;
      int c = g & 7;
      int off = r * ASTRIDE + (c << 4);
      const size_t kofs = (size_t)(kt * 64 + r) * HID + head * HDIM + (c << 3);
      *(bf16x8v*)(KsH + off) = *(const bf16x8v*)(KH + kofs);
      *(bf16x8v*)(KsL + off) = *(const bf16x8v*)(KL + kofs);
      const size_t vofs = (size_t)(head * 64 + r) * SEQ + kt * 64 + (c << 3);
      *(bf16x8v*)(VtH + off) = *(const bf16x8v*)(VTH + vofs);
      *(bf16x8v*)(VtL + off) = *(const bf16x8v*)(VTL + vofs);
    }
    __syncthreads();

    float sv[4][4];
#pragma unroll
    for (int stt = 0; stt < 4; ++stt) {
      int r = (stt << 4) + lr;
      int off0 = r * ASTRIDE + (kh << 4);
      int off1 = off0 + 64;
      bf16x8v kfh0 = *(const bf16x8v*)(KsH + off0);
      bf16x8v kfl0 = *(const bf16x8v*)(KsL + off0);
      bf16x8v kfh1 = *(const bf16x8v*)(KsH + off1);
      bf16x8v kfl1 = *(const bf16x8v*)(KsL + off1);
      f32x4v s = z4;
      s = MFMA(qfl0, kfh0, s);
      s = MFMA(qfh0, kfl0, s);
      s = MFMA(qfh0, kfh0, s);
      s = MFMA(qfl1, kfh1, s);
      s = MFMA(qfh1, kfl1, s);
      s = MFMA(qfh1, kfh1, s);
      int key = kt * 64 + (stt << 4) + lr;
#pragma unroll
      for (int rr = 0; rr < 4; ++rr) {
        int qr = qt * 64 + wid * 16 + (kh << 2) + rr;
        sv[stt][rr] = (key <= qr) ? s[rr] : -1e30f;
      }
    }

#pragma unroll
    for (int rr = 0; rr < 4; ++rr) {
      float mx = fmaxf(fmaxf(sv[0][rr], sv[1][rr]), fmaxf(sv[2][rr], sv[3][rr]));
#pragma unroll
      for (int d = 1; d < 16; d <<= 1) mx = fmaxf(mx, __shfl_xor(mx, d));
      float mnew = fmaxf(m_run[rr], mx);
      float scl = __expf(m_run[rr] - mnew);
      float pv[4];
#pragma unroll
      for (int stt = 0; stt < 4; ++stt) pv[stt] = __expf(sv[stt][rr] - mnew);
      float rs = pv[0] + pv[1] + pv[2] + pv[3];
#pragma unroll
      for (int d = 1; d < 16; d <<= 1) rs += __shfl_xor(rs, d);
      l_run[rr] = l_run[rr] * scl + rs;
      m_run[rr] = mnew;
#pragma unroll
      for (int n = 0; n < 4; ++n) oacc[n][rr] *= scl;
      int qlr = (kh << 2) + rr;
#pragma unroll
      for (int stt = 0; stt < 4; ++stt) {
        __bf16 hb = (__bf16)pv[stt];
        __bf16 lb = (__bf16)(pv[stt] - (float)hb);
        int off = qlr * ASTRIDE + (((stt << 4) + lr) << 1);
        *(__bf16*)(PsH[wid] + off) = hb;
        *(__bf16*)(PsL[wid] + off) = lb;
      }
    }

    int poff0 = lr * ASTRIDE + (kh << 4);
    int poff1 = poff0 + 64;
    bf16x8v pah0 = *(const bf16x8v*)(PsH[wid] + poff0);
    bf16x8v pal0 = *(const bf16x8v*)(PsL[wid] + poff0);
    bf16x8v pah1 = *(const bf16x8v*)(PsH[wid] + poff1);
    bf16x8v pal1 = *(const bf16x8v*)(PsL[wid] + poff1);
#pragma unroll
    for (int n = 0; n < 4; ++n) {
      int vr = (n << 4) + lr;
      int voff0 = vr * ASTRIDE + (kh << 4);
      int voff1 = voff0 + 64;
      bf16x8v vfh0 = *(const bf16x8v*)(VtH + voff0);
      bf16x8v vfl0 = *(const bf16x8v*)(VtL + voff0);
      bf16x8v vfh1 = *(const bf16x8v*)(VtH + voff1);
      bf16x8v vfl1 = *(const bf16x8v*)(VtL + voff1);
      oacc[n] = MFMA(pal0, vfh0, oacc[n]);
      oacc[n] = MFMA(pah0, vfl0, oacc[n]);
      oacc[n] = MFMA(pah0, vfh0, oacc[n]);
      oacc[n] = MFMA(pal1, vfh1, oacc[n]);
      oacc[n] = MFMA(pah1, vfl1, oacc[n]);
      oacc[n] = MFMA(pah1, vfh1, oacc[n]);
    }
  }

#pragma unroll
  for (int n = 0; n < 4; ++n)
#pragma unroll
    for (int rr = 0; rr < 4; ++rr) {
      int qr = qt * 64 + wid * 16 + (kh << 2) + rr;
      size_t ofs = (size_t)qr * HID + head * HDIM + (n << 4) + lr;
      float val = oacc[n][rr] / l_run[rr];
      __bf16 hb = (__bf16)val;
      OH[ofs] = hb;
      OL[ofs] = (__bf16)(val - (float)hb);
    }
}

// ---------------------------------------------------------------------------
// MoE: fused gate+up+silu (all experts batched in z), batched down, scatter.
// Numerics identical to serial path (same per-row MFMA chains, same order).
// ---------------------------------------------------------------------------
__global__ __launch_bounds__(256) void gemm_moe_guf_kernel(
    const __bf16* __restrict__ Xh,
    const float* __restrict__ MG, const float* __restrict__ MU,
    __bf16* __restrict__ A2, const float* __restrict__ W,
    const int* __restrict__ list, const int* __restrict__ cnt8,
    const int* __restrict__ off8)
{
  const int e = blockIdx.z;
  const int cnt = cnt8[e];
  const int bm = blockIdx.y, bn = blockIdx.x;
  if (bm * 128 >= cnt) return;
  const float* __restrict__ BG = MG + (size_t)e * HID * IDIM;
  const float* __restrict__ BU = MU + (size_t)e * HID * IDIM;
  const int base = off8[e];
  __shared__ __align__(16) char AsB[128 * LSTRIDE];
  __shared__ __align__(16) char BgB[128 * LSTRIDE];
  __shared__ __align__(16) char BuB[128 * LSTRIDE];
  const int tid = threadIdx.x;
  const int wid = tid >> 6, lane = tid & 63;
  const int wm = (wid >> 1) << 6, wn = (wid & 1) << 6;
  const int lr = lane & 15, kh = lane >> 4;

  f32x4v accg[4][4], accu[4][4];
  const f32x4v z4 = {0.f, 0.f, 0.f, 0.f};
#pragma unroll
  for (int i = 0; i < 4; ++i)
#pragma unroll
    for (int j = 0; j < 4; ++j) { accg[i][j] = z4; accu[i][j] = z4; }

  for (int k0 = 0; k0 < HID; k0 += 32) {
    __syncthreads();
#pragma unroll
    for (int p = 0; p < 2; ++p) {
      int g = tid + (p << 8);
      int r = g >> 2;
      int c = g & 3;
      int rg = bm * 128 + r;
      int tok = list[e * SEQ + (rg < cnt ? rg : cnt - 1)];
      *(bf16x8v*)(AsB + r * LSTRIDE + (c << 4)) =
          *(const bf16x8v*)(Xh + (size_t)tok * HID + k0 + (c << 3));
    }
#pragma unroll
    for (int p = 0; p < 2; ++p) {
      int g = tid + (p << 8);
      int k = g >> 4;
      int n8 = (g & 15) << 3;
      size_t src = (size_t)(k0 + k) * IDIM + bn * 128 + n8;
      float4 g0 = *(const float4*)(BG + src);
      float4 g1 = *(const float4*)(BG + src + 4);
      float4 u0 = *(const float4*)(BU + src);
      float4 u1 = *(const float4*)(BU + src + 4);
      float gv[8] = {g0.x, g0.y, g0.z, g0.w, g1.x, g1.y, g1.z, g1.w};
      float uv[8] = {u0.x, u0.y, u0.z, u0.w, u1.x, u1.y, u1.z, u1.w};
#pragma unroll
      for (int i = 0; i < 8; ++i) {
        int r = n8 + i;
        *(__bf16*)(BgB + r * LSTRIDE + (k << 1)) = (__bf16)gv[i];
        *(__bf16*)(BuB + r * LSTRIDE + (k << 1)) = (__bf16)uv[i];
      }
    }
    __syncthreads();

    bf16x8v af[4], bg4[4], bu4[4];
#pragma unroll
    for (int i = 0; i < 4; ++i) {
      int r = wm + (i << 4) + lr;
      af[i] = *(const bf16x8v*)(AsB + r * LSTRIDE + (kh << 4));
    }
#pragma unroll
    for (int i = 0; i < 4; ++i) {
      int r = wn + (i << 4) + lr;
      bg4[i] = *(const bf16x8v*)(BgB + r * LSTRIDE + (kh << 4));
      bu4[i] = *(const bf16x8v*)(BuB + r * LSTRIDE + (kh << 4));
    }
#pragma unroll
    for (int mi = 0; mi < 4; ++mi)
#pragma unroll
      for (int ni = 0; ni < 4; ++ni) {
        accg[mi][ni] = MFMA(af[mi], bg4[ni], accg[mi][ni]);
        accu[mi][ni] = MFMA(af[mi], bu4[ni], accu[mi][ni]);
      }
  }

  const int cr0 = kh << 2;
#pragma unroll
  for (int mi = 0; mi < 4; ++mi)
#pragma unroll
    for (int ni = 0; ni < 4; ++ni)
#pragma unroll
      for (int r = 0; r < 4; ++r) {
        int row = bm * 128 + wm + (mi << 4) + cr0 + r;
        if (row < cnt) {
          int col = bn * 128 + wn + (ni << 4) + lr;
          int tok = list[e * SEQ + row];
          float w = W[tok * 8 + e];
          float gval = accg[mi][ni][r];
          float uval = accu[mi][ni][r];
          float a = gval / (1.f + __expf(-gval)) * uval * w;
          A2[(size_t)(base + row) * IDIM + col] = (__bf16)a;
        }
      }
}

__global__ __launch_bounds__(256) void gemm_moe_down2_kernel(
    const __bf16* __restrict__ A2, const float* __restrict__ MDall,
    float* __restrict__ Y2,
    const int* __restrict__ cnt8, const int* __restrict__ off8)
{
  const int e = blockIdx.z;
  const int cnt = cnt8[e];
  const int bm = blockIdx.y, bn = blockIdx.x;
  if (bm * 128 >= cnt) return;
  const float* __restrict__ MD = MDall + (size_t)e * IDIM * HID;
  const int base = off8[e];
  __shared__ __align__(16) char AsB[128 * LSTRIDE];
  __shared__ __align__(16) char BsB[128 * LSTRIDE];
  const int tid = threadIdx.x;
  const int wid = tid >> 6, lane = tid & 63;
  const int wm = (wid >> 1) << 6, wn = (wid & 1) << 6;
  const int lr = lane & 15, kh = lane >> 4;

  f32x4v acc[4][4];
  const f32x4v z4 = {0.f, 0.f, 0.f, 0.f};
#pragma unroll
  for (int i = 0; i < 4; ++i)
#pragma unroll
    for (int j = 0; j < 4; ++j) acc[i][j] = z4;

  for (int k0 = 0; k0 < IDIM; k0 += 32) {
    __syncthreads();
#pragma unroll
    for (int p = 0; p < 2; ++p) {
      int g = tid + (p << 8);
      int r = g >> 2;
      int c = g & 3;
      int rg = bm * 128 + r;
      *(bf16x8v*)(AsB + r * LSTRIDE + (c << 4)) =
          *(const bf16x8v*)(A2 + (size_t)(base + (rg < cnt ? rg : cnt - 1)) * IDIM + k0 + (c << 3));
    }
#pragma unroll
    for (int p = 0; p < 2; ++p) {
      int g = tid + (p << 8);
      int k = g >> 4;
      int n8 = (g & 15) << 3;
      const float* src = MD + (size_t)(k0 + k) * HID + bn * 128 + n8;
      float4 f0 = *(const float4*)src;
      float4 f1 = *(const float4*)(src + 4);
      float fv[8] = {f0.x, f0.y, f0.z, f0.w, f1.x, f1.y, f1.z, f1.w};
#pragma unroll
      for (int i = 0; i < 8; ++i) {
        int r = n8 + i;
        *(__bf16*)(BsB + r * LSTRIDE + (k << 1)) = (__bf16)fv[i];
      }
    }
    __syncthreads();

    bf16x8v af[4], bfv[4];
#pragma unroll
    for (int i = 0; i < 4; ++i) {
      int r = wm + (i << 4) + lr;
      af[i] = *(const bf16x8v*)(AsB + r * LSTRIDE + (kh << 4));
    }
#pragma unroll
    for (int i = 0; i < 4; ++i) {
      int r = wn + (i << 4) + lr;
      bfv[i] = *(const bf16x8v*)(BsB + r * LSTRIDE + (kh << 4));
    }
#pragma unroll
    for (int mi = 0; mi < 4; ++mi)
#pragma unroll
      for (int ni = 0; ni < 4; ++ni)
        acc[mi][ni] = MFMA(af[mi], bfv[ni], acc[mi][ni]);
  }

  const int cr0 = kh << 2;
#pragma unroll
  for (int mi = 0; mi < 4; ++mi)
#pragma unroll
    for (int ni = 0; ni < 4; ++ni)
#pragma unroll
      for (int r = 0; r < 4; ++r) {
        int row = bm * 128 + wm + (mi << 4) + cr0 + r;
        if (row < cnt) {
          int col = bn * 128 + wn + (ni << 4) + lr;
          Y2[(size_t)(base + row) * HID + col] = acc[mi][ni][r];
        }
      }
}

// h[t] += y(e_lo) + y(e_hi)  (ascending-e order == old serial order)
__global__ __launch_bounds__(256) void moe_scatter_kernel(
    const int* __restrict__ tokpair, const int* __restrict__ off8,
    const float* __restrict__ Y2, float* __restrict__ H)
{
  const int t = blockIdx.x;
  const int i = threadIdx.x;
  int p0 = tokpair[t * 2], p1 = tokpair[t * 2 + 1];
  size_t r0 = off8[p0 >> 16] + (p0 & 0xffff);
  size_t r1 = off8[p1 >> 16] + (p1 & 0xffff);
  float4 a = ((const float4*)(Y2 + r0 * HID))[i];
  float4 b = ((const float4*)(Y2 + r1 * HID))[i];
  float4 hv = ((float4*)(H + (size_t)t * HID))[i];
  hv.x = (hv.x + a.x) + b.x;
  hv.y = (hv.y + a.y) + b.y;
  hv.z = (hv.z + a.z) + b.z;
  hv.w = (hv.w + a.w) + b.w;
  ((float4*)(H + (size_t)t * HID))[i] = hv;
}

// ---------------------------------------------------------------------------
// Small kernels
// ---------------------------------------------------------------------------
__global__ void tables_kernel(float* __restrict__ CT, float* __restrict__ ST)
{
  int idx = blockIdx.x * 256 + threadIdx.x;
  int s = idx >> 5, i = idx & 31;
  double inv = exp(-log(10000.0) * (double)i / 32.0);
  double ang = (double)s * inv;
  CT[idx] = (float)cos(ang);
  ST[idx] = (float)sin(ang);
}

__global__ __launch_bounds__(256) void embed_kernel(
    const int* __restrict__ ids, const float* __restrict__ E, float* __restrict__ H)
{
  int t = blockIdx.x;
  int id = ids[t];
  ((float4*)(H + (size_t)t * HID))[threadIdx.x] =
      ((const float4*)(E + (size_t)id * HID))[threadIdx.x];
}

__global__ __launch_bounds__(256) void rmsnorm_kernel(
    const float* __restrict__ X, const float* __restrict__ W,
    float* __restrict__ O, __bf16* __restrict__ OHb, __bf16* __restrict__ OLb)
{
  int t = blockIdx.x;
  int tid = threadIdx.x;
  float4 v = ((const float4*)(X + (size_t)t * HID))[tid];
  float ss = v.x * v.x + v.y * v.y + v.z * v.z + v.w * v.w;
#pragma unroll
  for (int d = 1; d < 64; d <<= 1) ss += __shfl_xor(ss, d);
  __shared__ float red[4];
  if ((tid & 63) == 0) red[tid >> 6] = ss;
  __syncthreads();
  float tot = red[0] + red[1] + red[2] + red[3];
  float inv = 1.0f / sqrtf(tot * (1.0f / 1024.0f) + 1e-6f);
  float4 w = ((const float4*)W)[tid];
  float4 r;
  r.x = v.x * inv * w.x; r.y = v.y * inv * w.y;
  r.z = v.z * inv * w.z; r.w = v.w * inv * w.w;
  ((float4*)(O + (size_t)t * HID))[tid] = r;
  float f[4] = {r.x, r.y, r.z, r.w};
  bf16x4v hv, lv;
#pragma unroll
  for (int j = 0; j < 4; ++j) {
    __bf16 hb = (__bf16)f[j];
    hv[j] = hb; lv[j] = (__bf16)(f[j] - (float)hb);
  }
  *(bf16x4v*)(OHb + (size_t)t * HID + tid * 4) = hv;
  *(bf16x4v*)(OLb + (size_t)t * HID + tid * 4) = lv;
}

__global__ __launch_bounds__(256) void silu_kernel(
    const float* __restrict__ G, const float* __restrict__ U,
    __bf16* __restrict__ AH, __bf16* __restrict__ AL)
{
  int t = blockIdx.y;
  int i = blockIdx.x * 256 + threadIdx.x;
  size_t idx = (size_t)t * IDIM + i;
  float gv = G[idx], uv = U[idx];
  float a = gv / (1.f + __expf(-gv)) * uv;
  __bf16 hb = (__bf16)a;
  AH[idx] = hb;
  AL[idx] = (__bf16)(a - (float)hb);
}

__global__ __launch_bounds__(256) void router_kernel(
    const float* __restrict__ X, const float* __restrict__ RW, float* __restrict__ RL)
{
  int wid = threadIdx.x >> 6, lane = threadIdx.x & 63;
  int t = blockIdx.x * 4 + wid;
  const float* x = X + (size_t)t * HID;
  float a0 = 0, a1 = 0, a2 = 0, a3 = 0, a4 = 0, a5 = 0, a6 = 0, a7 = 0;
  for (int hh = lane; hh < HID; hh += 64) {
    float xv = x[hh];
    float4 f0 = *(const float4*)(RW + hh * 8);
    float4 f1 = *(const float4*)(RW + hh * 8 + 4);
    a0 += xv * f0.x; a1 += xv * f0.y; a2 += xv * f0.z; a3 += xv * f0.w;
    a4 += xv * f1.x; a5 += xv * f1.y; a6 += xv * f1.z; a7 += xv * f1.w;
  }
#pragma unroll
  for (int d = 1; d < 64; d <<= 1) {
    a0 += __shfl_xor(a0, d); a1 += __shfl_xor(a1, d);
    a2 += __shfl_xor(a2, d); a3 += __shfl_xor(a3, d);
    a4 += __shfl_xor(a4, d); a5 += __shfl_xor(a5, d);
    a6 += __shfl_xor(a6, d); a7 += __shfl_xor(a7, d);
  }
  if (lane == 0) {
    float* dst = RL + (size_t)t * 8;
    dst[0] = a0; dst[1] = a1; dst[2] = a2; dst[3] = a3;
    dst[4] = a4; dst[5] = a5; dst[6] = a6; dst[7] = a7;
  }
}

__global__ void zero_kernel(float* __restrict__ p, int n)
{
  int i = threadIdx.x;
  if (i < n) p[i] = 0.f;
}

__global__ void zeroi_kernel(int* __restrict__ p, int n)
{
  int i = threadIdx.x;
  if (i < n) p[i] = 0;
}

__global__ __launch_bounds__(256) void topk_kernel(
    const float* __restrict__ RL, float* __restrict__ W, float* __restrict__ AUX)
{
  int t = blockIdx.x * 256 + threadIdx.x;
  int lane = threadIdx.x & 63;
  float r[8];
#pragma unroll
  for (int e = 0; e < 8; ++e) r[e] = RL[t * 8 + e];
  float mx = r[0];
#pragma unroll
  for (int e = 1; e < 8; ++e) mx = fmaxf(mx, r[e]);
  float p[8];
  float se = 0.f;
#pragma unroll
  for (int e = 0; e < 8; ++e) { p[e] = __expf(r[e] - mx); se += p[e]; }
  float inv = 1.f / se;
#pragma unroll
  for (int e = 0; e < 8; ++e) p[e] *= inv;
  float lse = logf(se) + mx;
  int i1 = 0; float v1 = p[0];
#pragma unroll
  for (int e = 1; e < 8; ++e) if (p[e] > v1) { v1 = p[e]; i1 = e; }
  int i2 = -1; float v2 = -1.f;
#pragma unroll
  for (int e = 0; e < 8; ++e) if (e != i1 && p[e] > v2) { v2 = p[e]; i2 = e; }
  float s12 = v1 + v2;
#pragma unroll
  for (int e = 0; e < 8; ++e)
    W[t * 8 + e] = (e == i1) ? v1 / s12 : ((e == i2) ? v2 / s12 : 0.f);
#pragma unroll
  for (int e = 0; e < 8; ++e) {
    float fe = ((i1 == e) ? 1.f : 0.f) + ((i2 == e) ? 1.f : 0.f);
    float pe = p[e];
#pragma unroll
    for (int d = 1; d < 64; d <<= 1) { fe += __shfl_xor(fe, d); pe += __shfl_xor(pe, d); }
    if (lane == 0) { atomicAdd(&AUX[e], fe); atomicAdd(&AUX[8 + e], pe); }
  }
  float zz = lse * lse;
#pragma unroll
  for (int d = 1; d < 64; d <<= 1) zz += __shfl_xor(zz, d);
  if (lane == 0) atomicAdd(&AUX[16], zz);
}

__global__ void aux_kernel(const float* __restrict__ AUX, float* __restrict__ OUT)
{
  float s = 0.f;
#pragma unroll
  for (int e = 0; e < 8; ++e)
    s += (AUX[e] * (1.f / 2048.f)) * (AUX[8 + e] * (1.f / 2048.f));
  float auxv = 0.01f * 8.f * s;
  float z = 0.001f * (AUX[16] * (1.f / 2048.f));
  OUT[(size_t)SEQ * VOCAB] = auxv + z;
}

// records per-token (expert, pos) pairs in ascending-e order
__global__ __launch_bounds__(256) void build_list_kernel(
    const float* __restrict__ W, int* __restrict__ cnt, int* __restrict__ list,
    int* __restrict__ tokpair)
{
  int t = blockIdx.x * 256 + threadIdx.x;
  int j = 0;
#pragma unroll
  for (int e = 0; e < 8; ++e) {
    if (W[t * 8 + e] > 0.f) {
      int p = atomicAdd(&cnt[e], 1);
      list[e * SEQ + p] = t;
      tokpair[t * 2 + j] = (e << 16) | p;
      ++j;
    }
  }
}

__global__ void prefix_kernel(const int* __restrict__ cnt, int* __restrict__ off)
{
  if (threadIdx.x == 0) {
    int s = 0;
    for (int e = 0; e < 8; ++e) { off[e] = s; s += cnt[e]; }
  }
}

// ---------------------------------------------------------------------------
extern "C" void kernel_launch(void* const* d_in, const int* in_sizes, int n_in,
                              void* d_out, int out_size, void* d_ws, size_t ws_size,
                              hipStream_t stream)
{
  const int*   ids   = (const int*)d_in[0];
  const float* embed = (const float*)d_in[1];
  const float* ln1   = (const float*)d_in[2];
  const float* ln2   = (const float*)d_in[3];
  const float* wq    = (const float*)d_in[4];
  const float* wk    = (const float*)d_in[5];
  const float* wv    = (const float*)d_in[6];
  const float* wo    = (const float*)d_in[7];
  const float* dg    = (const float*)d_in[8];
  const float* du    = (const float*)d_in[9];
  const float* dd    = (const float*)d_in[10];
  const float* rw    = (const float*)d_in[11];
  const float* mg    = (const float*)d_in[12];
  const float* mu    = (const float*)d_in[13];
  const float* md    = (const float*)d_in[14];
  const float* fin   = (const float*)d_in[15];
  float* out = (float*)d_out;

  char* ws = (char*)d_ws;
  float* h    = (float*)(ws + 0);
  float* hn   = (float*)(ws + 8388608);
  float* q    = (float*)(ws + 16777216);
  float* k    = (float*)(ws + 25165824);
  float* v    = (float*)(ws + 33554432);
  __bf16* oh  = (__bf16*)(ws + 41943040);
  __bf16* ol  = (__bf16*)(ws + 46137344);
  float* g    = (float*)(ws + 50331648);     // 23.07MB (MLP scratch / MoE a2)
  float* u    = (float*)(ws + 73400320);     // 23.07MB (MLP scratch / MoE y2)
  float* ct   = (float*)(ws + 96468992);
  float* st   = (float*)(ws + 96731136);
  float* rl   = (float*)(ws + 96993280);
  float* wmoe = (float*)(ws + 97058816);
  float* aux  = (float*)(ws + 97124352);
  int*   cnt  = (int*)  (ws + 97124608);
  int*   list = (int*)  (ws + 97124864);     // 64KB
  int*   tokp = (int*)  (ws + 97190400);     // 16KB
  int*   off8 = (int*)  (ws + 97206784);     // 32B
  __bf16* wqh = (__bf16*)(ws + 97320960);
  __bf16* wql = (__bf16*)(ws + 105709568);
  __bf16* wkh = (__bf16*)(ws + 114098176);
  __bf16* wkl = (__bf16*)(ws + 122486784);
  __bf16* wvh = (__bf16*)(ws + 130875392);
  __bf16* wvl = (__bf16*)(ws + 139264000);
  __bf16* woh = (__bf16*)(ws + 147652608);
  __bf16* wol = (__bf16*)(ws + 156041216);
  __bf16* dgh = (__bf16*)(ws + 164429824);
  __bf16* dgl = (__bf16*)(ws + 181731328);
  __bf16* duh = (__bf16*)(ws + 199032832);
  __bf16* dul = (__bf16*)(ws + 216334336);
  __bf16* ddh = (__bf16*)(ws + 233635840);
  __bf16* ddl = (__bf16*)(ws + 250937344);
  __bf16* eh  = (__bf16*)(ws + 268238848);
  __bf16* hnh = (__bf16*)(ws + 333774848);
  __bf16* hnl = (__bf16*)(ws + 337969152);
  __bf16* gh  = (__bf16*)(ws + 342163456);
  __bf16* gl  = (__bf16*)(ws + 353697792);   // end 365,232,128
  __bf16* qh  = (__bf16*)g;
  __bf16* ql  = (__bf16*)((char*)g + 4194304);
  __bf16* kbh = (__bf16*)((char*)g + 8388608);
  __bf16* kbl = (__bf16*)((char*)g + 12582912);
  __bf16* vth = (__bf16*)u;
  __bf16* vtl = (__bf16*)((char*)u + 4194304);
  __bf16* a2  = (__bf16*)g;                  // [4096][IDIM] bf16 = 23.07MB exact
  float*  y2  = u;                           // [4096][HID] f32 = 16.8MB

  wsplit_t_kernel<<<dim3(16, 16, 4), 256, 0, stream>>>(wq, wqh, wql, HID, HID);
  wsplit_t_kernel<<<dim3(16, 16, 4), 256, 0, stream>>>(wk, wkh, wkl, HID, HID);
  wsplit_t_kernel<<<dim3(16, 16, 4), 256, 0, stream>>>(wv, wvh, wvl, HID, HID);
  wsplit_t_kernel<<<dim3(16, 16, 4), 256, 0, stream>>>(wo, woh, wol, HID, HID);
  wsplit_t_kernel<<<dim3(44, 16, 3), 256, 0, stream>>>(dg, dgh, dgl, HID, IDIM);
  wsplit_t_kernel<<<dim3(44, 16, 3), 256, 0, stream>>>(du, duh, dul, HID, IDIM);
  wsplit_t_kernel<<<dim3(16, 44, 3), 256, 0, stream>>>(dd, ddh, ddl, IDIM, HID);
  esplit_kernel<<<16000, 256, 0, stream>>>(embed, eh);

  tables_kernel<<<256, 256, 0, stream>>>(ct, st);
  embed_kernel<<<SEQ, 256, 0, stream>>>(ids, embed, h);

  for (int li = 0; li < 4; ++li) {
    const bool comp = (li <= 2);
    rmsnorm_kernel<<<SEQ, 256, 0, stream>>>(h, ln1 + li * HID, hn, hnh, hnl);
    size_t wofs = (size_t)li * HID * HID;
    if (comp)
      gemm_bt_kernel<true, false, false, 64><<<dim3(8, 32, 3), 256, 0, stream>>>(
          hnh, hnl, wqh + wofs, wql + wofs, wkh + wofs, wkl + wofs,
          wvh + wofs, wvl + wofs, q, k, v, SEQ, HID, HID);
    else
      gemm_bt_kernel<false, false, false, 64><<<dim3(8, 32, 3), 256, 0, stream>>>(
          hnh, hnh, wqh + wofs, wqh + wofs, wkh + wofs, wkh + wofs,
          wvh + wofs, wvh + wofs, q, k, v, SEQ, HID, HID);

    rope_split_kernel<<<4096, 256, 0, stream>>>(q, k, qh, ql, kbh, kbl, ct, st);
    vtsplit_kernel<<<dim3(32, 16), 256, 0, stream>>>(v, vth, vtl);

    attn_flash_kernel<<<dim3(32, 16), 256, 0, stream>>>(
        qh, ql, kbh, kbl, vth, vtl, oh, ol);

    if (comp)
      gemm_bt_kernel<true, true, false, 64><<<dim3(8, 32, 1), 256, 0, stream>>>(
          oh, ol, woh + wofs, wol + wofs, woh + wofs, wol + wofs,
          woh + wofs, wol + wofs, h, h, h, SEQ, HID, HID);
    else
      gemm_bt_kernel<false, true, false, 64><<<dim3(8, 32, 1), 256, 0, stream>>>(
          oh, oh, woh + wofs, woh + wofs, woh + wofs, woh + wofs,
          woh + wofs, woh + wofs, h, h, h, SEQ, HID, HID);

    rmsnorm_kernel<<<SEQ, 256, 0, stream>>>(h, ln2 + li * HID, hn, hnh, hnl);
    if (li == 2) {
      router_kernel<<<512, 256, 0, stream>>>(hn, rw, rl);
      zero_kernel<<<1, 32, 0, stream>>>(aux, 17);
      topk_kernel<<<8, 256, 0, stream>>>(rl, wmoe, aux);
      aux_kernel<<<1, 1, 0, stream>>>(aux, out);
      zeroi_kernel<<<1, 32, 0, stream>>>(cnt, 8);
      build_list_kernel<<<8, 256, 0, stream>>>(wmoe, cnt, list, tokp);
      prefix_kernel<<<1, 64, 0, stream>>>(cnt, off8);
      gemm_moe_guf_kernel<<<dim3(22, 16, 8), 256, 0, stream>>>(
          hnh, mg, mu, a2, wmoe, list, cnt, off8);
      gemm_moe_down2_kernel<<<dim3(8, 16, 8), 256, 0, stream>>>(
          a2, md, y2, cnt, off8);
      moe_scatter_kernel<<<SEQ, 256, 0, stream>>>(tokp, off8, y2, h);
    } else {
      int d = (li < 2) ? li : li - 1;
      size_t go = (size_t)d * HID * IDIM;
      if (comp) {
        gemm_bt_kernel<true, false, false, 128><<<dim3(22, 16, 2), 256, 0, stream>>>(
            hnh, hnl, dgh + go, dgl + go, duh + go, dul + go,
            duh + go, dul + go, g, u, u, SEQ, IDIM, HID);
        silu_kernel<<<dim3(11, SEQ), 256, 0, stream>>>(g, u, gh, gl);
        gemm_bt_kernel<true, true, false, 64><<<dim3(8, 32, 1), 256, 0, stream>>>(
            gh, gl, ddh + go, ddl + go, ddh + go, ddl + go,
            ddh + go, ddl + go, h, h, h, SEQ, HID, IDIM);
      } else {
        gemm_bt_kernel<false, false, false, 128><<<dim3(22, 16, 2), 256, 0, stream>>>(
            hnh, hnh, dgh + go, dgh + go, duh + go, duh + go,
            duh + go, duh + go, g, u, u, SEQ, IDIM, HID);
        silu_kernel<<<dim3(11, SEQ), 256, 0, stream>>>(g, u, gh, gl);
        gemm_bt_kernel<false, true, false, 64><<<dim3(8, 32, 1), 256, 0, stream>>>(
            gh, gh, ddh + go, ddh + go, ddh + go, ddh + go,
            ddh + go, ddh + go, h, h, h, SEQ, HID, IDIM);
      }
    }
  }
  rmsnorm_kernel<<<SEQ, 256, 0, stream>>>(h, fin, hn, hnh, hnl);
  gemm_bt_kernel<false, false, true, 128><<<dim3(16, 250, 1), 256, 0, stream>>>(
      hnh, hnh, eh, eh, eh, eh, eh, eh, out, out, out, SEQ, VOCAB, HID);
}

// Round 12
// 2134.707 us; speedup vs baseline: 13.0166x; 1.2483x over previous
//
#include <hip/hip_runtime.h>
#include <hip/hip_bf16.h>
#include <math.h>

#define SEQ 2048
#define HID 1024
#define NHEAD 16
#define HDIM 64
#define IDIM 2816
#define NEXP 8
#define VOCAB 32000

#define LSTRIDE 80   // padded rows (legacy; unused by DMA kernels)
#define ASTRIDE 144  // padded rows (attention)

typedef float f32x4v __attribute__((ext_vector_type(4)));
typedef __bf16 bf16x8v __attribute__((ext_vector_type(8)));
typedef __bf16 bf16x4v __attribute__((ext_vector_type(4)));

__device__ __forceinline__ bf16x8v cvt8(const float4& a, const float4& b) {
  bf16x8v r;
  r[0] = (__bf16)a.x; r[1] = (__bf16)a.y; r[2] = (__bf16)a.z; r[3] = (__bf16)a.w;
  r[4] = (__bf16)b.x; r[5] = (__bf16)b.y; r[6] = (__bf16)b.z; r[7] = (__bf16)b.w;
  return r;
}

#define MFMA(a, b, c) __builtin_amdgcn_mfma_f32_16x16x32_bf16(a, b, c, 0, 0, 0)

// async global->LDS DMA, 16B per lane; lds base must be wave-uniform
__device__ __forceinline__ void gld_lds16(const void* g, void* l) {
  __builtin_amdgcn_global_load_lds(
      (const __attribute__((address_space(1))) unsigned int*)(unsigned long long)g,
      (__attribute__((address_space(3))) unsigned int*)(unsigned int)(unsigned long long)l,
      16, 0, 0);
}

// ---------------------------------------------------------------------------
// Weight preprocessing: W[K,N] f32 -> WH,WL [N,K] bf16 (transposed hi/lo).
// ---------------------------------------------------------------------------
__global__ __launch_bounds__(256) void wsplit_t_kernel(
    const float* __restrict__ W, __bf16* __restrict__ WH, __bf16* __restrict__ WL,
    int K, int N)
{
  __shared__ float tile[64][65];
  const int tid = threadIdx.x;
  const size_t zofs = (size_t)blockIdx.z * K * N;
  const int n0 = blockIdx.x * 64, k0 = blockIdx.y * 64;
#pragma unroll
  for (int r = 0; r < 4; ++r) {
    int kk = (tid >> 4) + r * 16;
    int nn = (tid & 15) * 4;
    float4 v = *(const float4*)(W + zofs + (size_t)(k0 + kk) * N + n0 + nn);
    tile[kk][nn] = v.x; tile[kk][nn + 1] = v.y;
    tile[kk][nn + 2] = v.z; tile[kk][nn + 3] = v.w;
  }
  __syncthreads();
  const int nn = tid >> 2;
  const int kk = (tid & 3) * 16;
  __bf16* dh = WH + zofs + (size_t)(n0 + nn) * K + k0 + kk;
  __bf16* dl = WL + zofs + (size_t)(n0 + nn) * K + k0 + kk;
  bf16x8v h0, l0, h1, l1;
#pragma unroll
  for (int j = 0; j < 8; ++j) {
    float f = tile[kk + j][nn];
    __bf16 hb = (__bf16)f; h0[j] = hb; l0[j] = (__bf16)(f - (float)hb);
    f = tile[kk + 8 + j][nn];
    hb = (__bf16)f; h1[j] = hb; l1[j] = (__bf16)(f - (float)hb);
  }
  *(bf16x8v*)dh = h0; *(bf16x8v*)(dh + 8) = h1;
  *(bf16x8v*)dl = l0; *(bf16x8v*)(dl + 8) = l1;
}

// hi-only variant (MoE weights; plain-bf16 path needs no lo)
__global__ __launch_bounds__(256) void wsplit_th_kernel(
    const float* __restrict__ W, __bf16* __restrict__ WH, int K, int N)
{
  __shared__ float tile[64][65];
  const int tid = threadIdx.x;
  const size_t zofs = (size_t)blockIdx.z * K * N;
  const int n0 = blockIdx.x * 64, k0 = blockIdx.y * 64;
#pragma unroll
  for (int r = 0; r < 4; ++r) {
    int kk = (tid >> 4) + r * 16;
    int nn = (tid & 15) * 4;
    float4 v = *(const float4*)(W + zofs + (size_t)(k0 + kk) * N + n0 + nn);
    tile[kk][nn] = v.x; tile[kk][nn + 1] = v.y;
    tile[kk][nn + 2] = v.z; tile[kk][nn + 3] = v.w;
  }
  __syncthreads();
  const int nn = tid >> 2;
  const int kk = (tid & 3) * 16;
  __bf16* dh = WH + zofs + (size_t)(n0 + nn) * K + k0 + kk;
  bf16x8v h0, h1;
#pragma unroll
  for (int j = 0; j < 8; ++j) {
    h0[j] = (__bf16)tile[kk + j][nn];
    h1[j] = (__bf16)tile[kk + 8 + j][nn];
  }
  *(bf16x8v*)dh = h0; *(bf16x8v*)(dh + 8) = h1;
}

__global__ __launch_bounds__(256) void esplit_kernel(
    const float* __restrict__ E, __bf16* __restrict__ EH)
{
  size_t i = ((size_t)blockIdx.x * 256 + threadIdx.x) * 8;
  float4 a = *(const float4*)(E + i);
  float4 b = *(const float4*)(E + i + 4);
  *(bf16x8v*)(EH + i) = cvt8(a, b);
}

// ---------------------------------------------------------------------------
// Unified BT GEMM. A,B pre-split bf16. Staging = global_load_lds DMA (16B),
// LINEAR LDS rows (64B/row).
// ---------------------------------------------------------------------------
template<bool COMP, bool ACCUM, bool SWAP, int BM>
__global__ __launch_bounds__(256) void gemm_bt_kernel(
    const __bf16* __restrict__ Ah, const __bf16* __restrict__ Al,
    const __bf16* __restrict__ B0h, const __bf16* __restrict__ B0l,
    const __bf16* __restrict__ B1h, const __bf16* __restrict__ B1l,
    const __bf16* __restrict__ B2h, const __bf16* __restrict__ B2l,
    float* __restrict__ C0, float* __restrict__ C1, float* __restrict__ C2,
    int M, int N, int Kd)
{
  const __bf16* __restrict__ Bh = (blockIdx.z == 0) ? B0h : (blockIdx.z == 1 ? B1h : B2h);
  const __bf16* __restrict__ Bl = (blockIdx.z == 0) ? B0l : (blockIdx.z == 1 ? B1l : B2l);
  float* __restrict__ C         = (blockIdx.z == 0) ? C0 : (blockIdx.z == 1 ? C1 : C2);
  constexpr int ATILE = BM * 64;
  constexpr int BTILE = 128 * 64;
  constexpr int MFR = BM / 32;
  __shared__ __align__(16) char smem[COMP ? 2 * (ATILE + BTILE) : (ATILE + BTILE)];
  char* AsH = smem;
  char* BsH = smem + ATILE;
  char* AsL = COMP ? smem + ATILE + BTILE : smem;
  char* BsL = COMP ? smem + 2 * ATILE + BTILE : smem + ATILE;
  const int tid = threadIdx.x;
  const int bm = SWAP ? blockIdx.x : blockIdx.y;
  const int bn = SWAP ? blockIdx.y : blockIdx.x;
  const int wid = tid >> 6, lane = tid & 63;
  const int wm = (wid >> 1) * (BM / 2), wn = (wid & 1) << 6;
  const int lr = lane & 15, kh = lane >> 4;
  const int lrow = lane >> 2;
  const int lcol = (lane & 3) << 3;

  f32x4v acc[MFR][4];
  const f32x4v z4 = {0.f, 0.f, 0.f, 0.f};
#pragma unroll
  for (int i = 0; i < MFR; ++i)
#pragma unroll
    for (int j = 0; j < 4; ++j) acc[i][j] = z4;

  for (int k0 = 0; k0 < Kd; k0 += 32) {
    __syncthreads();
#pragma unroll
    for (int c = wid; c < BM / 16; c += 4) {
      size_t gofs = (size_t)(bm * BM + c * 16 + lrow) * Kd + k0 + lcol;
      gld_lds16(Ah + gofs, AsH + c * 1024);
      if (COMP) gld_lds16(Al + gofs, AsL + c * 1024);
    }
#pragma unroll
    for (int c = wid; c < 8; c += 4) {
      size_t gofs = (size_t)(bn * 128 + c * 16 + lrow) * Kd + k0 + lcol;
      gld_lds16(Bh + gofs, BsH + c * 1024);
      if (COMP) gld_lds16(Bl + gofs, BsL + c * 1024);
    }
    __syncthreads();

    bf16x8v ah[MFR], al[MFR], bh4[4], bl4[4];
#pragma unroll
    for (int i = 0; i < MFR; ++i) {
      int r = wm + (i << 4) + lr;
      int off = r * 64 + (kh << 4);
      ah[i] = *(const bf16x8v*)(AsH + off);
      if (COMP) al[i] = *(const bf16x8v*)(AsL + off);
    }
#pragma unroll
    for (int i = 0; i < 4; ++i) {
      int r = wn + (i << 4) + lr;
      int off = r * 64 + (kh << 4);
      bh4[i] = *(const bf16x8v*)(BsH + off);
      if (COMP) bl4[i] = *(const bf16x8v*)(BsL + off);
    }
#pragma unroll
    for (int mi = 0; mi < MFR; ++mi)
#pragma unroll
      for (int ni = 0; ni < 4; ++ni) {
        if (COMP) {
          acc[mi][ni] = MFMA(al[mi], bh4[ni], acc[mi][ni]);
          acc[mi][ni] = MFMA(ah[mi], bl4[ni], acc[mi][ni]);
        }
        acc[mi][ni] = MFMA(ah[mi], bh4[ni], acc[mi][ni]);
      }
  }

  const int cr0 = kh << 2;
#pragma unroll
  for (int mi = 0; mi < MFR; ++mi)
#pragma unroll
    for (int ni = 0; ni < 4; ++ni)
#pragma unroll
      for (int r = 0; r < 4; ++r) {
        int row = bm * BM + wm + (mi << 4) + cr0 + r;
        int col = bn * 128 + wn + (ni << 4) + lr;
        size_t idx = (size_t)row * N + col;
        if (ACCUM) C[idx] += acc[mi][ni][r];
        else       C[idx] = acc[mi][ni][r];
      }
}

// ---------------------------------------------------------------------------
// rope + hi/lo split for Q (scale 1/8) and K
// ---------------------------------------------------------------------------
__global__ __launch_bounds__(256) void rope_split_kernel(
    const float* __restrict__ Q, const float* __restrict__ K,
    __bf16* __restrict__ QH, __bf16* __restrict__ QL,
    __bf16* __restrict__ KH, __bf16* __restrict__ KL,
    const float* __restrict__ CT, const float* __restrict__ ST)
{
  int idx = blockIdx.x * 256 + threadIdx.x;
  int s = idx >> 9;
  int rr = idx & 511;
  int hd = rr >> 5;
  int i = rr & 31;
  float c = CT[(s << 5) + i], sn = ST[(s << 5) + i];
  size_t base = (size_t)s * HID + hd * 64 + i;
  {
    float x1 = Q[base], x2 = Q[base + 32];
    float o1 = (x1 * c - x2 * sn) * 0.125f;
    float o2 = (x2 * c + x1 * sn) * 0.125f;
    __bf16 h1 = (__bf16)o1, h2 = (__bf16)o2;
    QH[base] = h1;      QL[base] = (__bf16)(o1 - (float)h1);
    QH[base + 32] = h2; QL[base + 32] = (__bf16)(o2 - (float)h2);
  }
  {
    float x1 = K[base], x2 = K[base + 32];
    float o1 = x1 * c - x2 * sn;
    float o2 = x2 * c + x1 * sn;
    __bf16 h1 = (__bf16)o1, h2 = (__bf16)o2;
    KH[base] = h1;      KL[base] = (__bf16)(o1 - (float)h1);
    KH[base + 32] = h2; KL[base + 32] = (__bf16)(o2 - (float)h2);
  }
}

// V f32 [S][HID] -> per-head transposed hi/lo bf16 [NHEAD][HDIM][SEQ]
__global__ __launch_bounds__(256) void vtsplit_kernel(
    const float* __restrict__ V, __bf16* __restrict__ VTH, __bf16* __restrict__ VTL)
{
  __shared__ float tile[64][65];
  const int tid = threadIdx.x;
  const int s0 = blockIdx.x * 64;
  const int head = blockIdx.y;
#pragma unroll
  for (int r = 0; r < 4; ++r) {
    int ss = (tid >> 4) + r * 16;
    int dd = (tid & 15) * 4;
    float4 v = *(const float4*)(V + (size_t)(s0 + ss) * HID + head * 64 + dd);
    tile[ss][dd] = v.x; tile[ss][dd + 1] = v.y;
    tile[ss][dd + 2] = v.z; tile[ss][dd + 3] = v.w;
  }
  __syncthreads();
#pragma unroll
  for (int half = 0; half < 2; ++half) {
    const int d = (tid >> 3) + (half << 5);
    const int c = tid & 7;
    bf16x8v hv, lv;
#pragma unroll
    for (int j = 0; j < 8; ++j) {
      float f = tile[c * 8 + j][d];
      __bf16 hb = (__bf16)f;
      hv[j] = hb; lv[j] = (__bf16)(f - (float)hb);
    }
    size_t dst = (size_t)(head * 64 + d) * SEQ + s0 + c * 8;
    *(bf16x8v*)(VTH + dst) = hv;
    *(bf16x8v*)(VTL + dst) = lv;
  }
}

// ---------------------------------------------------------------------------
// Compensated flash attention; padded LDS; O -> bf16 hi/lo
// ---------------------------------------------------------------------------
__global__ __launch_bounds__(256) void attn_flash_kernel(
    const __bf16* __restrict__ QH, const __bf16* __restrict__ QL,
    const __bf16* __restrict__ KH, const __bf16* __restrict__ KL,
    const __bf16* __restrict__ VTH, const __bf16* __restrict__ VTL,
    __bf16* __restrict__ OH, __bf16* __restrict__ OL)
{
  const int qt = blockIdx.x;
  const int head = blockIdx.y;
  const int tid = threadIdx.x, wid = tid >> 6, lane = tid & 63;
  const int lr = lane & 15, kh = lane >> 4;
  __shared__ __align__(16) char KsH[64 * ASTRIDE], KsL[64 * ASTRIDE];
  __shared__ __align__(16) char VtH[64 * ASTRIDE], VtL[64 * ASTRIDE];
  __shared__ __align__(16) char PsH[4][16 * ASTRIDE], PsL[4][16 * ASTRIDE];

  const size_t qofs = (size_t)(qt * 64 + wid * 16 + lr) * HID + head * HDIM;
  const bf16x8v qfh0 = *(const bf16x8v*)(QH + qofs + (kh << 3));
  const bf16x8v qfh1 = *(const bf16x8v*)(QH + qofs + 32 + (kh << 3));
  const bf16x8v qfl0 = *(const bf16x8v*)(QL + qofs + (kh << 3));
  const bf16x8v qfl1 = *(const bf16x8v*)(QL + qofs + 32 + (kh << 3));

  float m_run[4], l_run[4];
  f32x4v oacc[4];
  const f32x4v z4 = {0.f, 0.f, 0.f, 0.f};
#pragma unroll
  for (int i = 0; i < 4; ++i) { m_run[i] = -1e30f; l_run[i] = 0.f; oacc[i] = z4; }

  for (int kt = 0; kt <= qt; ++kt) {
    __syncthreads();
#pragma unroll
    for (int p = 0; p < 2; ++p) {
      int g = tid + (p << 8);
      int r = g >> 3;
      int c = g & 7;
      int off = r * ASTRIDE + (c << 4);
      const size_t kofs = (size_t)(kt * 64 + r) * HID + head * HDIM + (c << 3);
      *(bf16x8v*)(KsH + off) = *(const bf16x8v*)(KH + kofs);
      *(bf16x8v*)(KsL + off) = *(const bf16x8v*)(KL + kofs);
      const size_t vofs = (size_t)(head * 64 + r) * SEQ + kt * 64 + (c << 3);
      *(bf16x8v*)(VtH + off) = *(const bf16x8v*)(VTH + vofs);
      *(bf16x8v*)(VtL + off) = *(const bf16x8v*)(VTL + vofs);
    }
    __syncthreads();

    float sv[4][4];
#pragma unroll
    for (int stt = 0; stt < 4; ++stt) {
      int r = (stt << 4) + lr;
      int off0 = r * ASTRIDE + (kh << 4);
      int off1 = off0 + 64;
      bf16x8v kfh0 = *(const bf16x8v*)(KsH + off0);
      bf16x8v kfl0 = *(const bf16x8v*)(KsL + off0);
      bf16x8v kfh1 = *(const bf16x8v*)(KsH + off1);
      bf16x8v kfl1 = *(const bf16x8v*)(KsL + off1);
      f32x4v s = z4;
      s = MFMA(qfl0, kfh0, s);
      s = MFMA(qfh0, kfl0, s);
      s = MFMA(qfh0, kfh0, s);
      s = MFMA(qfl1, kfh1, s);
      s = MFMA(qfh1, kfl1, s);
      s = MFMA(qfh1, kfh1, s);
      int key = kt * 64 + (stt << 4) + lr;
#pragma unroll
      for (int rr = 0; rr < 4; ++rr) {
        int qr = qt * 64 + wid * 16 + (kh << 2) + rr;
        sv[stt][rr] = (key <= qr) ? s[rr] : -1e30f;
      }
    }

#pragma unroll
    for (int rr = 0; rr < 4; ++rr) {
      float mx = fmaxf(fmaxf(sv[0][rr], sv[1][rr]), fmaxf(sv[2][rr], sv[3][rr]));
#pragma unroll
      for (int d = 1; d < 16; d <<= 1) mx = fmaxf(mx, __shfl_xor(mx, d));
      float mnew = fmaxf(m_run[rr], mx);
      float scl = __expf(m_run[rr] - mnew);
      float pv[4];
#pragma unroll
      for (int stt = 0; stt < 4; ++stt) pv[stt] = __expf(sv[stt][rr] - mnew);
      float rs = pv[0] + pv[1] + pv[2] + pv[3];
#pragma unroll
      for (int d = 1; d < 16; d <<= 1) rs += __shfl_xor(rs, d);
      l_run[rr] = l_run[rr] * scl + rs;
      m_run[rr] = mnew;
#pragma unroll
      for (int n = 0; n < 4; ++n) oacc[n][rr] *= scl;
      int qlr = (kh << 2) + rr;
#pragma unroll
      for (int stt = 0; stt < 4; ++stt) {
        __bf16 hb = (__bf16)pv[stt];
        __bf16 lb = (__bf16)(pv[stt] - (float)hb);
        int off = qlr * ASTRIDE + (((stt << 4) + lr) << 1);
        *(__bf16*)(PsH[wid] + off) = hb;
        *(__bf16*)(PsL[wid] + off) = lb;
      }
    }

    int poff0 = lr * ASTRIDE + (kh << 4);
    int poff1 = poff0 + 64;
    bf16x8v pah0 = *(const bf16x8v*)(PsH[wid] + poff0);
    bf16x8v pal0 = *(const bf16x8v*)(PsL[wid] + poff0);
    bf16x8v pah1 = *(const bf16x8v*)(PsH[wid] + poff1);
    bf16x8v pal1 = *(const bf16x8v*)(PsL[wid] + poff1);
#pragma unroll
    for (int n = 0; n < 4; ++n) {
      int vr = (n << 4) + lr;
      int voff0 = vr * ASTRIDE + (kh << 4);
      int voff1 = voff0 + 64;
      bf16x8v vfh0 = *(const bf16x8v*)(VtH + voff0);
      bf16x8v vfl0 = *(const bf16x8v*)(VtL + voff0);
      bf16x8v vfh1 = *(const bf16x8v*)(VtH + voff1);
      bf16x8v vfl1 = *(const bf16x8v*)(VtL + voff1);
      oacc[n] = MFMA(pal0, vfh0, oacc[n]);
      oacc[n] = MFMA(pah0, vfl0, oacc[n]);
      oacc[n] = MFMA(pah0, vfh0, oacc[n]);
      oacc[n] = MFMA(pal1, vfh1, oacc[n]);
      oacc[n] = MFMA(pah1, vfl1, oacc[n]);
      oacc[n] = MFMA(pah1, vfh1, oacc[n]);
    }
  }

#pragma unroll
  for (int n = 0; n < 4; ++n)
#pragma unroll
    for (int rr = 0; rr < 4; ++rr) {
      int qr = qt * 64 + wid * 16 + (kh << 2) + rr;
      size_t ofs = (size_t)qr * HID + head * HDIM + (n << 4) + lr;
      float val = oacc[n][rr] / l_run[rr];
      __bf16 hb = (__bf16)val;
      OH[ofs] = hb;
      OL[ofs] = (__bf16)(val - (float)hb);
    }
}

// ---------------------------------------------------------------------------
// MoE: fused gate+up+silu with DMA staging from pre-split bf16 weights.
// ---------------------------------------------------------------------------
__global__ __launch_bounds__(256) void gemm_moe_guf_kernel(
    const __bf16* __restrict__ Xh,
    const __bf16* __restrict__ MGH, const __bf16* __restrict__ MUH,
    __bf16* __restrict__ A2, const float* __restrict__ W,
    const int* __restrict__ list, const int* __restrict__ cnt8,
    const int* __restrict__ off8)
{
  const int e = blockIdx.z;
  const int cnt = cnt8[e];
  const int bm = blockIdx.y, bn = blockIdx.x;
  if (bm * 128 >= cnt) return;
  const int base = off8[e];
  __shared__ __align__(16) char AsB[8192];
  __shared__ __align__(16) char BgB[8192];
  __shared__ __align__(16) char BuB[8192];
  const int tid = threadIdx.x;
  const int wid = tid >> 6, lane = tid & 63;
  const int wm = (wid >> 1) << 6, wn = (wid & 1) << 6;
  const int lr = lane & 15, kh = lane >> 4;
  const int lrow = lane >> 2;
  const int lcol = (lane & 3) << 3;

  f32x4v accg[4][4], accu[4][4];
  const f32x4v z4 = {0.f, 0.f, 0.f, 0.f};
#pragma unroll
  for (int i = 0; i < 4; ++i)
#pragma unroll
    for (int j = 0; j < 4; ++j) { accg[i][j] = z4; accu[i][j] = z4; }

  for (int k0 = 0; k0 < HID; k0 += 32) {
    __syncthreads();
#pragma unroll
    for (int c = wid; c < 8; c += 4) {
      int rg = bm * 128 + c * 16 + lrow;
      int tok = list[e * SEQ + (rg < cnt ? rg : cnt - 1)];
      gld_lds16(Xh + (size_t)tok * HID + k0 + lcol, AsB + c * 1024);
      size_t wofs = (size_t)(e * IDIM + bn * 128 + c * 16 + lrow) * HID + k0 + lcol;
      gld_lds16(MGH + wofs, BgB + c * 1024);
      gld_lds16(MUH + wofs, BuB + c * 1024);
    }
    __syncthreads();

    bf16x8v af[4], bg4[4], bu4[4];
#pragma unroll
    for (int i = 0; i < 4; ++i) {
      int r = wm + (i << 4) + lr;
      af[i] = *(const bf16x8v*)(AsB + r * 64 + (kh << 4));
    }
#pragma unroll
    for (int i = 0; i < 4; ++i) {
      int r = wn + (i << 4) + lr;
      bg4[i] = *(const bf16x8v*)(BgB + r * 64 + (kh << 4));
      bu4[i] = *(const bf16x8v*)(BuB + r * 64 + (kh << 4));
    }
#pragma unroll
    for (int mi = 0; mi < 4; ++mi)
#pragma unroll
      for (int ni = 0; ni < 4; ++ni) {
        accg[mi][ni] = MFMA(af[mi], bg4[ni], accg[mi][ni]);
        accu[mi][ni] = MFMA(af[mi], bu4[ni], accu[mi][ni]);
      }
  }

  const int cr0 = kh << 2;
#pragma unroll
  for (int mi = 0; mi < 4; ++mi)
#pragma unroll
    for (int ni = 0; ni < 4; ++ni)
#pragma unroll
      for (int r = 0; r < 4; ++r) {
        int row = bm * 128 + wm + (mi << 4) + cr0 + r;
        if (row < cnt) {
          int col = bn * 128 + wn + (ni << 4) + lr;
          int tok = list[e * SEQ + row];
          float w = W[tok * 8 + e];
          float gval = accg[mi][ni][r];
          float uval = accu[mi][ni][r];
          float a = gval / (1.f + __expf(-gval)) * uval * w;
          A2[(size_t)(base + row) * IDIM + col] = (__bf16)a;
        }
      }
}

__global__ __launch_bounds__(256) void gemm_moe_down2_kernel(
    const __bf16* __restrict__ A2, const __bf16* __restrict__ MDH,
    float* __restrict__ Y2,
    const int* __restrict__ cnt8, const int* __restrict__ off8)
{
  const int e = blockIdx.z;
  const int cnt = cnt8[e];
  const int bm = blockIdx.y, bn = blockIdx.x;
  if (bm * 128 >= cnt) return;
  const int base = off8[e];
  __shared__ __align__(16) char AsB[8192];
  __shared__ __align__(16) char BsB[8192];
  const int tid = threadIdx.x;
  const int wid = tid >> 6, lane = tid & 63;
  const int wm = (wid >> 1) << 6, wn = (wid & 1) << 6;
  const int lr = lane & 15, kh = lane >> 4;
  const int lrow = lane >> 2;
  const int lcol = (lane & 3) << 3;

  f32x4v acc[4][4];
  const f32x4v z4 = {0.f, 0.f, 0.f, 0.f};
#pragma unroll
  for (int i = 0; i < 4; ++i)
#pragma unroll
    for (int j = 0; j < 4; ++j) acc[i][j] = z4;

  for (int k0 = 0; k0 < IDIM; k0 += 32) {
    __syncthreads();
#pragma unroll
    for (int c = wid; c < 8; c += 4) {
      int rg = bm * 128 + c * 16 + lrow;
      int row = (rg < cnt ? rg : cnt - 1);
      gld_lds16(A2 + (size_t)(base + row) * IDIM + k0 + lcol, AsB + c * 1024);
      gld_lds16(MDH + (size_t)(e * HID + bn * 128 + c * 16 + lrow) * IDIM + k0 + lcol,
                BsB + c * 1024);
    }
    __syncthreads();

    bf16x8v af[4], bfv[4];
#pragma unroll
    for (int i = 0; i < 4; ++i) {
      int r = wm + (i << 4) + lr;
      af[i] = *(const bf16x8v*)(AsB + r * 64 + (kh << 4));
    }
#pragma unroll
    for (int i = 0; i < 4; ++i) {
      int r = wn + (i << 4) + lr;
      bfv[i] = *(const bf16x8v*)(BsB + r * 64 + (kh << 4));
    }
#pragma unroll
    for (int mi = 0; mi < 4; ++mi)
#pragma unroll
      for (int ni = 0; ni < 4; ++ni)
        acc[mi][ni] = MFMA(af[mi], bfv[ni], acc[mi][ni]);
  }

  const int cr0 = kh << 2;
#pragma unroll
  for (int mi = 0; mi < 4; ++mi)
#pragma unroll
    for (int ni = 0; ni < 4; ++ni)
#pragma unroll
      for (int r = 0; r < 4; ++r) {
        int row = bm * 128 + wm + (mi << 4) + cr0 + r;
        if (row < cnt) {
          int col = bn * 128 + wn + (ni << 4) + lr;
          Y2[(size_t)(base + row) * HID + col] = acc[mi][ni][r];
        }
      }
}

// h[t] += y(e_lo) + y(e_hi)  (ascending-e order == old serial order)
__global__ __launch_bounds__(256) void moe_scatter_kernel(
    const int* __restrict__ tokpair, const int* __restrict__ off8,
    const float* __restrict__ Y2, float* __restrict__ H)
{
  const int t = blockIdx.x;
  const int i = threadIdx.x;
  int p0 = tokpair[t * 2], p1 = tokpair[t * 2 + 1];
  size_t r0 = off8[p0 >> 16] + (p0 & 0xffff);
  size_t r1 = off8[p1 >> 16] + (p1 & 0xffff);
  float4 a = ((const float4*)(Y2 + r0 * HID))[i];
  float4 b = ((const float4*)(Y2 + r1 * HID))[i];
  float4 hv = ((float4*)(H + (size_t)t * HID))[i];
  hv.x = (hv.x + a.x) + b.x;
  hv.y = (hv.y + a.y) + b.y;
  hv.z = (hv.z + a.z) + b.z;
  hv.w = (hv.w + a.w) + b.w;
  ((float4*)(H + (size_t)t * HID))[i] = hv;
}

// ---------------------------------------------------------------------------
// Small kernels
// ---------------------------------------------------------------------------
__global__ void tables_kernel(float* __restrict__ CT, float* __restrict__ ST)
{
  int idx = blockIdx.x * 256 + threadIdx.x;
  int s = idx >> 5, i = idx & 31;
  double inv = exp(-log(10000.0) * (double)i / 32.0);
  double ang = (double)s * inv;
  CT[idx] = (float)cos(ang);
  ST[idx] = (float)sin(ang);
}

__global__ __launch_bounds__(256) void embed_kernel(
    const int* __restrict__ ids, const float* __restrict__ E, float* __restrict__ H)
{
  int t = blockIdx.x;
  int id = ids[t];
  ((float4*)(H + (size_t)t * HID))[threadIdx.x] =
      ((const float4*)(E + (size_t)id * HID))[threadIdx.x];
}

__global__ __launch_bounds__(256) void rmsnorm_kernel(
    const float* __restrict__ X, const float* __restrict__ W,
    float* __restrict__ O, __bf16* __restrict__ OHb, __bf16* __restrict__ OLb)
{
  int t = blockIdx.x;
  int tid = threadIdx.x;
  float4 v = ((const float4*)(X + (size_t)t * HID))[tid];
  float ss = v.x * v.x + v.y * v.y + v.z * v.z + v.w * v.w;
#pragma unroll
  for (int d = 1; d < 64; d <<= 1) ss += __shfl_xor(ss, d);
  __shared__ float red[4];
  if ((tid & 63) == 0) red[tid >> 6] = ss;
  __syncthreads();
  float tot = red[0] + red[1] + red[2] + red[3];
  float inv = 1.0f / sqrtf(tot * (1.0f / 1024.0f) + 1e-6f);
  float4 w = ((const float4*)W)[tid];
  float4 r;
  r.x = v.x * inv * w.x; r.y = v.y * inv * w.y;
  r.z = v.z * inv * w.z; r.w = v.w * inv * w.w;
  ((float4*)(O + (size_t)t * HID))[tid] = r;
  float f[4] = {r.x, r.y, r.z, r.w};
  bf16x4v hv, lv;
#pragma unroll
  for (int j = 0; j < 4; ++j) {
    __bf16 hb = (__bf16)f[j];
    hv[j] = hb; lv[j] = (__bf16)(f[j] - (float)hb);
  }
  *(bf16x4v*)(OHb + (size_t)t * HID + tid * 4) = hv;
  *(bf16x4v*)(OLb + (size_t)t * HID + tid * 4) = lv;
}

__global__ __launch_bounds__(256) void silu_kernel(
    const float* __restrict__ G, const float* __restrict__ U,
    __bf16* __restrict__ AH, __bf16* __restrict__ AL)
{
  int t = blockIdx.y;
  int i = blockIdx.x * 256 + threadIdx.x;
  size_t idx = (size_t)t * IDIM + i;
  float gv = G[idx], uv = U[idx];
  float a = gv / (1.f + __expf(-gv)) * uv;
  __bf16 hb = (__bf16)a;
  AH[idx] = hb;
  AL[idx] = (__bf16)(a - (float)hb);
}

__global__ __launch_bounds__(256) void router_kernel(
    const float* __restrict__ X, const float* __restrict__ RW, float* __restrict__ RL)
{
  int wid = threadIdx.x >> 6, lane = threadIdx.x & 63;
  int t = blockIdx.x * 4 + wid;
  const float* x = X + (size_t)t * HID;
  float a0 = 0, a1 = 0, a2 = 0, a3 = 0, a4 = 0, a5 = 0, a6 = 0, a7 = 0;
  for (int hh = lane; hh < HID; hh += 64) {
    float xv = x[hh];
    float4 f0 = *(const float4*)(RW + hh * 8);
    float4 f1 = *(const float4*)(RW + hh * 8 + 4);
    a0 += xv * f0.x; a1 += xv * f0.y; a2 += xv * f0.z; a3 += xv * f0.w;
    a4 += xv * f1.x; a5 += xv * f1.y; a6 += xv * f1.z; a7 += xv * f1.w;
  }
#pragma unroll
  for (int d = 1; d < 64; d <<= 1) {
    a0 += __shfl_xor(a0, d); a1 += __shfl_xor(a1, d);
    a2 += __shfl_xor(a2, d); a3 += __shfl_xor(a3, d);
    a4 += __shfl_xor(a4, d); a5 += __shfl_xor(a5, d);
    a6 += __shfl_xor(a6, d); a7 += __shfl_xor(a7, d);
  }
  if (lane == 0) {
    float* dst = RL + (size_t)t * 8;
    dst[0] = a0; dst[1] = a1; dst[2] = a2; dst[3] = a3;
    dst[4] = a4; dst[5] = a5; dst[6] = a6; dst[7] = a7;
  }
}

__global__ void zero_kernel(float* __restrict__ p, int n)
{
  int i = threadIdx.x;
  if (i < n) p[i] = 0.f;
}

__global__ void zeroi_kernel(int* __restrict__ p, int n)
{
  int i = threadIdx.x;
  if (i < n) p[i] = 0;
}

__global__ __launch_bounds__(256) void topk_kernel(
    const float* __restrict__ RL, float* __restrict__ W, float* __restrict__ AUX)
{
  int t = blockIdx.x * 256 + threadIdx.x;
  int lane = threadIdx.x & 63;
  float r[8];
#pragma unroll
  for (int e = 0; e < 8; ++e) r[e] = RL[t * 8 + e];
  float mx = r[0];
#pragma unroll
  for (int e = 1; e < 8; ++e) mx = fmaxf(mx, r[e]);
  float p[8];
  float se = 0.f;
#pragma unroll
  for (int e = 0; e < 8; ++e) { p[e] = __expf(r[e] - mx); se += p[e]; }
  float inv = 1.f / se;
#pragma unroll
  for (int e = 0; e < 8; ++e) p[e] *= inv;
  float lse = logf(se) + mx;
  int i1 = 0; float v1 = p[0];
#pragma unroll
  for (int e = 1; e < 8; ++e) if (p[e] > v1) { v1 = p[e]; i1 = e; }
  int i2 = -1; float v2 = -1.f;
#pragma unroll
  for (int e = 0; e < 8; ++e) if (e != i1 && p[e] > v2) { v2 = p[e]; i2 = e; }
  float s12 = v1 + v2;
#pragma unroll
  for (int e = 0; e < 8; ++e)
    W[t * 8 + e] = (e == i1) ? v1 / s12 : ((e == i2) ? v2 / s12 : 0.f);
#pragma unroll
  for (int e = 0; e < 8; ++e) {
    float fe = ((i1 == e) ? 1.f : 0.f) + ((i2 == e) ? 1.f : 0.f);
    float pe = p[e];
#pragma unroll
    for (int d = 1; d < 64; d <<= 1) { fe += __shfl_xor(fe, d); pe += __shfl_xor(pe, d); }
    if (lane == 0) { atomicAdd(&AUX[e], fe); atomicAdd(&AUX[8 + e], pe); }
  }
  float zz = lse * lse;
#pragma unroll
  for (int d = 1; d < 64; d <<= 1) zz += __shfl_xor(zz, d);
  if (lane == 0) atomicAdd(&AUX[16], zz);
}

__global__ void aux_kernel(const float* __restrict__ AUX, float* __restrict__ OUT)
{
  float s = 0.f;
#pragma unroll
  for (int e = 0; e < 8; ++e)
    s += (AUX[e] * (1.f / 2048.f)) * (AUX[8 + e] * (1.f / 2048.f));
  float auxv = 0.01f * 8.f * s;
  float z = 0.001f * (AUX[16] * (1.f / 2048.f));
  OUT[(size_t)SEQ * VOCAB] = auxv + z;
}

// records per-token (expert, pos) pairs in ascending-e order
__global__ __launch_bounds__(256) void build_list_kernel(
    const float* __restrict__ W, int* __restrict__ cnt, int* __restrict__ list,
    int* __restrict__ tokpair)
{
  int t = blockIdx.x * 256 + threadIdx.x;
  int j = 0;
#pragma unroll
  for (int e = 0; e < 8; ++e) {
    if (W[t * 8 + e] > 0.f) {
      int p = atomicAdd(&cnt[e], 1);
      list[e * SEQ + p] = t;
      tokpair[t * 2 + j] = (e << 16) | p;
      ++j;
    }
  }
}

__global__ void prefix_kernel(const int* __restrict__ cnt, int* __restrict__ off)
{
  if (threadIdx.x == 0) {
    int s = 0;
    for (int e = 0; e < 8; ++e) { off[e] = s; s += cnt[e]; }
  }
}

// ---------------------------------------------------------------------------
extern "C" void kernel_launch(void* const* d_in, const int* in_sizes, int n_in,
                              void* d_out, int out_size, void* d_ws, size_t ws_size,
                              hipStream_t stream)
{
  const int*   ids   = (const int*)d_in[0];
  const float* embed = (const float*)d_in[1];
  const float* ln1   = (const float*)d_in[2];
  const float* ln2   = (const float*)d_in[3];
  const float* wq    = (const float*)d_in[4];
  const float* wk    = (const float*)d_in[5];
  const float* wv    = (const float*)d_in[6];
  const float* wo    = (const float*)d_in[7];
  const float* dg    = (const float*)d_in[8];
  const float* du    = (const float*)d_in[9];
  const float* dd    = (const float*)d_in[10];
  const float* rw    = (const float*)d_in[11];
  const float* mg    = (const float*)d_in[12];
  const float* mu    = (const float*)d_in[13];
  const float* md    = (const float*)d_in[14];
  const float* fin   = (const float*)d_in[15];
  float* out = (float*)d_out;

  char* ws = (char*)d_ws;
  float* h    = (float*)(ws + 0);
  float* hn   = (float*)(ws + 8388608);
  float* q    = (float*)(ws + 16777216);
  float* k    = (float*)(ws + 25165824);
  float* v    = (float*)(ws + 33554432);
  __bf16* oh  = (__bf16*)(ws + 41943040);
  __bf16* ol  = (__bf16*)(ws + 46137344);
  float* g    = (float*)(ws + 50331648);     // 23.07MB (MLP scratch / MoE a2)
  float* u    = (float*)(ws + 73400320);     // 23.07MB (MLP scratch / MoE y2)
  float* ct   = (float*)(ws + 96468992);
  float* st   = (float*)(ws + 96731136);
  float* rl   = (float*)(ws + 96993280);
  float* wmoe = (float*)(ws + 97058816);
  float* aux  = (float*)(ws + 97124352);
  int*   cnt  = (int*)  (ws + 97124608);
  int*   list = (int*)  (ws + 97124864);     // 64KB
  int*   tokp = (int*)  (ws + 97190400);     // 16KB
  int*   off8 = (int*)  (ws + 97206784);     // 32B
  __bf16* wqh = (__bf16*)(ws + 97320960);
  __bf16* wql = (__bf16*)(ws + 105709568);
  __bf16* wkh = (__bf16*)(ws + 114098176);
  __bf16* wkl = (__bf16*)(ws + 122486784);
  __bf16* wvh = (__bf16*)(ws + 130875392);
  __bf16* wvl = (__bf16*)(ws + 139264000);
  __bf16* woh = (__bf16*)(ws + 147652608);
  __bf16* wol = (__bf16*)(ws + 156041216);
  __bf16* dgh = (__bf16*)(ws + 164429824);
  __bf16* dgl = (__bf16*)(ws + 181731328);
  __bf16* duh = (__bf16*)(ws + 199032832);
  __bf16* dul = (__bf16*)(ws + 216334336);
  __bf16* ddh = (__bf16*)(ws + 233635840);
  __bf16* ddl = (__bf16*)(ws + 250937344);
  __bf16* eh  = (__bf16*)(ws + 268238848);
  __bf16* hnh = (__bf16*)(ws + 333774848);
  __bf16* hnl = (__bf16*)(ws + 337969152);
  __bf16* gh  = (__bf16*)(ws + 342163456);
  __bf16* gl  = (__bf16*)(ws + 353697792);
  __bf16* mgh = (__bf16*)(ws + 365232128);   // [8][IDIM][HID] bf16 = 46.1MB
  __bf16* muh = (__bf16*)(ws + 411369472);
  __bf16* mdh = (__bf16*)(ws + 457506816);   // [8][HID][IDIM]
  // end: 503,644,160 bytes
  __bf16* qh  = (__bf16*)g;
  __bf16* ql  = (__bf16*)((char*)g + 4194304);
  __bf16* kbh = (__bf16*)((char*)g + 8388608);
  __bf16* kbl = (__bf16*)((char*)g + 12582912);
  __bf16* vth = (__bf16*)u;
  __bf16* vtl = (__bf16*)((char*)u + 4194304);
  __bf16* a2  = (__bf16*)g;                  // [4096][IDIM] bf16 = 23.07MB
  float*  y2  = u;                           // [4096][HID] f32 = 16.8MB

  wsplit_t_kernel<<<dim3(16, 16, 4), 256, 0, stream>>>(wq, wqh, wql, HID, HID);
  wsplit_t_kernel<<<dim3(16, 16, 4), 256, 0, stream>>>(wk, wkh, wkl, HID, HID);
  wsplit_t_kernel<<<dim3(16, 16, 4), 256, 0, stream>>>(wv, wvh, wvl, HID, HID);
  wsplit_t_kernel<<<dim3(16, 16, 4), 256, 0, stream>>>(wo, woh, wol, HID, HID);
  wsplit_t_kernel<<<dim3(44, 16, 3), 256, 0, stream>>>(dg, dgh, dgl, HID, IDIM);
  wsplit_t_kernel<<<dim3(44, 16, 3), 256, 0, stream>>>(du, duh, dul, HID, IDIM);
  wsplit_t_kernel<<<dim3(16, 44, 3), 256, 0, stream>>>(dd, ddh, ddl, IDIM, HID);
  wsplit_th_kernel<<<dim3(44, 16, 8), 256, 0, stream>>>(mg, mgh, HID, IDIM);
  wsplit_th_kernel<<<dim3(44, 16, 8), 256, 0, stream>>>(mu, muh, HID, IDIM);
  wsplit_th_kernel<<<dim3(16, 44, 8), 256, 0, stream>>>(md, mdh, IDIM, HID);
  esplit_kernel<<<16000, 256, 0, stream>>>(embed, eh);

  tables_kernel<<<256, 256, 0, stream>>>(ct, st);
  embed_kernel<<<SEQ, 256, 0, stream>>>(ids, embed, h);

  for (int li = 0; li < 4; ++li) {
    const bool comp = (li <= 2);
    rmsnorm_kernel<<<SEQ, 256, 0, stream>>>(h, ln1 + li * HID, hn, hnh, hnl);
    size_t wofs = (size_t)li * HID * HID;
    if (comp)
      gemm_bt_kernel<true, false, false, 64><<<dim3(8, 32, 3), 256, 0, stream>>>(
          hnh, hnl, wqh + wofs, wql + wofs, wkh + wofs, wkl + wofs,
          wvh + wofs, wvl + wofs, q, k, v, SEQ, HID, HID);
    else
      gemm_bt_kernel<false, false, false, 64><<<dim3(8, 32, 3), 256, 0, stream>>>(
          hnh, hnh, wqh + wofs, wqh + wofs, wkh + wofs, wkh + wofs,
          wvh + wofs, wvh + wofs, q, k, v, SEQ, HID, HID);

    rope_split_kernel<<<4096, 256, 0, stream>>>(q, k, qh, ql, kbh, kbl, ct, st);
    vtsplit_kernel<<<dim3(32, 16), 256, 0, stream>>>(v, vth, vtl);

    attn_flash_kernel<<<dim3(32, 16), 256, 0, stream>>>(
        qh, ql, kbh, kbl, vth, vtl, oh, ol);

    if (comp)
      gemm_bt_kernel<true, true, false, 64><<<dim3(8, 32, 1), 256, 0, stream>>>(
          oh, ol, woh + wofs, wol + wofs, woh + wofs, wol + wofs,
          woh + wofs, wol + wofs, h, h, h, SEQ, HID, HID);
    else
      gemm_bt_kernel<false, true, false, 64><<<dim3(8, 32, 1), 256, 0, stream>>>(
          oh, oh, woh + wofs, woh + wofs, woh + wofs, woh + wofs,
          woh + wofs, woh + wofs, h, h, h, SEQ, HID, HID);

    rmsnorm_kernel<<<SEQ, 256, 0, stream>>>(h, ln2 + li * HID, hn, hnh, hnl);
    if (li == 2) {
      router_kernel<<<512, 256, 0, stream>>>(hn, rw, rl);
      zero_kernel<<<1, 32, 0, stream>>>(aux, 17);
      topk_kernel<<<8, 256, 0, stream>>>(rl, wmoe, aux);
      aux_kernel<<<1, 1, 0, stream>>>(aux, out);
      zeroi_kernel<<<1, 32, 0, stream>>>(cnt, 8);
      build_list_kernel<<<8, 256, 0, stream>>>(wmoe, cnt, list, tokp);
      prefix_kernel<<<1, 64, 0, stream>>>(cnt, off8);
      gemm_moe_guf_kernel<<<dim3(22, 16, 8), 256, 0, stream>>>(
          hnh, mgh, muh, a2, wmoe, list, cnt, off8);
      gemm_moe_down2_kernel<<<dim3(8, 16, 8), 256, 0, stream>>>(
          a2, mdh, y2, cnt, off8);
      moe_scatter_kernel<<<SEQ, 256, 0, stream>>>(tokp, off8, y2, h);
    } else {
      int d = (li < 2) ? li : li - 1;
      size_t go = (size_t)d * HID * IDIM;
      if (comp) {
        gemm_bt_kernel<true, false, false, 128><<<dim3(22, 16, 2), 256, 0, stream>>>(
            hnh, hnl, dgh + go, dgl + go, duh + go, dul + go,
            duh + go, dul + go, g, u, u, SEQ, IDIM, HID);
        silu_kernel<<<dim3(11, SEQ), 256, 0, stream>>>(g, u, gh, gl);
        gemm_bt_kernel<true, true, false, 64><<<dim3(8, 32, 1), 256, 0, stream>>>(
            gh, gl, ddh + go, ddl + go, ddh + go, ddl + go,
            ddh + go, ddl + go, h, h, h, SEQ, HID, IDIM);
      } else {
        gemm_bt_kernel<false, false, false, 128><<<dim3(22, 16, 2), 256, 0, stream>>>(
            hnh, hnh, dgh + go, dgh + go, duh + go, duh + go,
            duh + go, duh + go, g, u, u, SEQ, IDIM, HID);
        silu_kernel<<<dim3(11, SEQ), 256, 0, stream>>>(g, u, gh, gl);
        gemm_bt_kernel<false, true, false, 64><<<dim3(8, 32, 1), 256, 0, stream>>>(
            gh, gh, ddh + go, ddh + go, ddh + go, ddh + go,
            ddh + go, ddh + go, h, h, h, SEQ, HID, IDIM);
      }
    }
  }
  rmsnorm_kernel<<<SEQ, 256, 0, stream>>>(h, fin, hn, hnh, hnl);
  gemm_bt_kernel<false, false, true, 128><<<dim3(16, 250, 1), 256, 0, stream>>>(
      hnh, hnh, eh, eh, eh, eh, eh, eh, out, out, out, SEQ, VOCAB, HID);
}